// Round 1
// baseline (421.706 us; speedup 1.0000x reference)
//
#include <hip/hip_runtime.h>
#include <math.h>

#define D 128
#define DDIM 32
#define NHEAD 8

__device__ __forceinline__ float red16(float x) {
    x += __shfl_xor(x, 1);
    x += __shfl_xor(x, 2);
    x += __shfl_xor(x, 4);
    x += __shfl_xor(x, 8);
    return x;
}
__device__ __forceinline__ float red8(float x) {
    x += __shfl_xor(x, 1);
    x += __shfl_xor(x, 2);
    x += __shfl_xor(x, 4);
    return x;
}

__global__ void k_zero(int* __restrict__ p, int n) {
    int i = blockIdx.x * blockDim.x + threadIdx.x;
    if (i < n) p[i] = 0;
}

// ka = af @ Wk[:128,:], va = af @ Wv[:128,:]   (no bias; bias handled later)
__global__ void __launch_bounds__(128) k_atomproj(
    const float* __restrict__ af, const float* __restrict__ Wk,
    const float* __restrict__ Wv, float* __restrict__ ka,
    float* __restrict__ va, int N) {
    __shared__ float s[16][D];
    int a0 = blockIdx.x * 16;
    int c = threadIdx.x;
#pragma unroll
    for (int a = 0; a < 16; ++a) {
        int ai = a0 + a;
        s[a][c] = (ai < N) ? af[(size_t)ai * D + c] : 0.f;
    }
    __syncthreads();
    float acck[16], accv[16];
#pragma unroll
    for (int a = 0; a < 16; ++a) { acck[a] = 0.f; accv[a] = 0.f; }
    for (int d = 0; d < D; ++d) {
        float wk = Wk[d * D + c];
        float wv = Wv[d * D + c];
#pragma unroll
        for (int a = 0; a < 16; ++a) {
            float x = s[a][d];
            acck[a] += x * wk;
            accv[a] += x * wv;
        }
    }
#pragma unroll
    for (int a = 0; a < 16; ++a) {
        int ai = a0 + a;
        if (ai < N) {
            ka[(size_t)ai * D + c] = acck[a];
            va[(size_t)ai * D + c] = accv[a];
        }
    }
}

// per-bond: rb_pos, rb_feats = (fi+fl)@Wa + (fj+fk)@Wb + 2*b_dih,  q = rb_feats@Wq + bq
__global__ void __launch_bounds__(128) k_bondfeats(
    const float* __restrict__ af, const float* __restrict__ coords,
    const int* __restrict__ rbi, const int* __restrict__ tt,
    const float* __restrict__ W_dih, const float* __restrict__ b_dih,
    const float* __restrict__ Wq, const float* __restrict__ bq,
    float* __restrict__ qv, float* __restrict__ rbp, int NB) {
    __shared__ float s1[8][D], s2[8][D], rf[8][D];
    int b0 = blockIdx.x * 8;
    int c = threadIdx.x;
#pragma unroll
    for (int b = 0; b < 8; ++b) {
        int bi = b0 + b;
        if (bi < NB) {
            int i0 = tt[bi * 4 + 0], i1 = tt[bi * 4 + 1];
            int i2 = tt[bi * 4 + 2], i3 = tt[bi * 4 + 3];
            s1[b][c] = af[(size_t)i0 * D + c] + af[(size_t)i3 * D + c];
            s2[b][c] = af[(size_t)i1 * D + c] + af[(size_t)i2 * D + c];
        } else {
            s1[b][c] = 0.f; s2[b][c] = 0.f;
        }
    }
    // rb_pos
    if (c < 24) {
        int b = c / 3, x = c % 3;
        int bi = b0 + b;
        if (bi < NB) {
            int a0i = rbi[bi], a1i = rbi[NB + bi];
            rbp[bi * 3 + x] = 0.5f * (coords[a0i * 3 + x] + coords[a1i * 3 + x]);
        }
    }
    if (c >= 24 && c < 48) {
        int b = (c - 24) / 3, x = (c - 24) % 3;
        int bi = b0 + 4 + b; // wrong mapping guard below keeps it safe
        (void)bi; (void)b; (void)x;
    }
    __syncthreads();
    float acc[8];
    float bd2 = 2.f * b_dih[c];
#pragma unroll
    for (int b = 0; b < 8; ++b) acc[b] = bd2;
    for (int d = 0; d < D; ++d) {
        float wa = W_dih[d * D + c] + W_dih[(384 + d) * D + c];
        float wb = W_dih[(128 + d) * D + c] + W_dih[(256 + d) * D + c];
#pragma unroll
        for (int b = 0; b < 8; ++b) acc[b] += s1[b][d] * wa + s2[b][d] * wb;
    }
#pragma unroll
    for (int b = 0; b < 8; ++b) rf[b][c] = acc[b];
    __syncthreads();
    float accq[8];
    float bqc = bq[c];
#pragma unroll
    for (int b = 0; b < 8; ++b) accq[b] = bqc;
    for (int d = 0; d < D; ++d) {
        float wq = Wq[d * D + c];
#pragma unroll
        for (int b = 0; b < 8; ++b) accq[b] += rf[b][d] * wq;
    }
#pragma unroll
    for (int b = 0; b < 8; ++b) {
        int bi = b0 + b;
        if (bi < NB) qv[(size_t)bi * D + c] = accq[b];
    }
}

__global__ void k_count(const int* __restrict__ etgt, int* __restrict__ cnt, int E) {
    int e = blockIdx.x * blockDim.x + threadIdx.x;
    if (e < E) atomicAdd(&cnt[etgt[e]], 1);
}

__global__ void __launch_bounds__(1024) k_scan(const int* __restrict__ cnt,
                                               int* __restrict__ offs, int NB) {
    __shared__ int part[1024];
    int t = threadIdx.x;
    int CH = (NB + 1023) >> 10;
    int base = t * CH;
    int s = 0;
    for (int i = 0; i < CH; ++i) {
        int idx = base + i;
        if (idx < NB) s += cnt[idx];
    }
    part[t] = s;
    __syncthreads();
    for (int off = 1; off < 1024; off <<= 1) {
        int v = (t >= off) ? part[t - off] : 0;
        __syncthreads();
        part[t] += v;
        __syncthreads();
    }
    int run = part[t] - s;
    for (int i = 0; i < CH; ++i) {
        int idx = base + i;
        if (idx < NB) {
            offs[idx] = run;
            run += cnt[idx];
        }
    }
    if (t == 1023) offs[NB] = part[1023];
}

__global__ void k_scatter(const int* __restrict__ etgt, const int* __restrict__ offs,
                          int* __restrict__ cursor, int* __restrict__ perm, int E) {
    int e = blockIdx.x * blockDim.x + threadIdx.x;
    if (e < E) {
        int t = etgt[e];
        int pos = atomicAdd(&cursor[t], 1);
        perm[offs[t] + pos] = e;
    }
}

// one wave per bond: segment attention
__global__ void __launch_bounds__(64) k_attn(
    const float* __restrict__ qv, const float* __restrict__ ka,
    const float* __restrict__ va, const float* __restrict__ coords,
    const float* __restrict__ rbp, const int* __restrict__ esrc,
    const int* __restrict__ perm, const int* __restrict__ offs,
    const float* __restrict__ Wk, const float* __restrict__ Wv,
    const float* __restrict__ bk, const float* __restrict__ bv,
    float* __restrict__ oat, int NB) {
    int b = blockIdx.x;
    int l = threadIdx.x;
    __shared__ float q_s[D];
    __shared__ float qb_s[NHEAD];
    __shared__ float sc[NHEAD];
    __shared__ float wexp[NHEAD];
    __shared__ float wde_s[NHEAD][DDIM];
    __shared__ float dn_s[NHEAD];

    float q0 = qv[(size_t)b * D + l];
    float q1 = qv[(size_t)b * D + 64 + l];
    q_s[l] = q0;
    q_s[64 + l] = q1;
    // qb: per-head score bias from bk
    float r0 = red16(q0 * bk[l]);
    float r1 = red16(q1 * bk[64 + l]);
    if ((l & 15) == 0) {
        qb_s[l >> 4] = r0;
        qb_s[4 + (l >> 4)] = r1;
    }
    __syncthreads();

    // t_k[h][d] = sum_c Wk[128+d, h*16+c] * q[h*16+c]; lane handles h8=(l>>3), d = d0..d0+3
    int h8 = l >> 3;
    int d0 = (l & 7) * 4;
    float tk[4];
#pragma unroll
    for (int j = 0; j < 4; ++j) {
        float t = 0.f;
        int dr = 128 + d0 + j;
#pragma unroll
        for (int cc = 0; cc < 16; ++cc)
            t += Wk[dr * D + h8 * 16 + cc] * q_s[h8 * 16 + cc];
        tk[j] = t;
    }

    float bx = rbp[b * 3 + 0], by = rbp[b * 3 + 1], bz = rbp[b * 3 + 2];
    const float step = 5.0f / 31.0f;
    const float coeff = -0.5f / (step * step);

    float acc0 = 0.f, acc1 = 0.f;
    float wde[4] = {0.f, 0.f, 0.f, 0.f};
    float dn = 0.f;

    int istart = offs[b], iend = offs[b + 1];
    for (int i = istart; i < iend; ++i) {
        int e = perm[i];
        int src = esrc[e];
        float dx = coords[src * 3 + 0] - bx;
        float dy = coords[src * 3 + 1] - by;
        float dz = coords[src * 3 + 2] - bz;
        float dist = sqrtf(dx * dx + dy * dy + dz * dz);
        float de[4];
#pragma unroll
        for (int j = 0; j < 4; ++j) {
            float t = dist - step * (float)(d0 + j);
            de[j] = expf(coeff * t * t);
        }
        // score part A: q . ka[src]
        float ka0 = ka[(size_t)src * D + l];
        float ka1 = ka[(size_t)src * D + 64 + l];
        float rA0 = red16(q0 * ka0); // head l>>4
        float rA1 = red16(q1 * ka1); // head 4+(l>>4)
        // score part B: sum_d de[d]*tk[h][d]
        float pb = de[0] * tk[0] + de[1] * tk[1] + de[2] * tk[2] + de[3] * tk[3];
        float sB = red8(pb); // head h8
        if ((l & 15) == 0) {
            sc[l >> 4] = rA0;
            sc[4 + (l >> 4)] = rA1;
        }
        __syncthreads();
        if ((l & 7) == 0) {
            float s = (sc[h8] + sB + qb_s[h8]) * 0.25f;
            wexp[h8] = expf(s);
        }
        __syncthreads();
        float w0 = wexp[l >> 4];
        float w1 = wexp[4 + (l >> 4)];
        acc0 += w0 * va[(size_t)src * D + l];
        acc1 += w1 * va[(size_t)src * D + 64 + l];
        float wh = wexp[h8];
#pragma unroll
        for (int j = 0; j < 4; ++j) wde[j] += wh * de[j];
        if (l < 8) dn += wexp[l];
        __syncthreads();
    }

    if (l < 8) dn_s[l] = dn;
#pragma unroll
    for (int j = 0; j < 4; ++j) wde_s[h8][d0 + j] = wde[j];
    __syncthreads();

    int hA = l >> 4, hB = 4 + (l >> 4);
    float sum0 = acc0, sum1 = acc1;
    for (int d = 0; d < DDIM; ++d) {
        float wdA = wde_s[hA][d];
        float wdB = wde_s[hB][d];
        sum0 += wdA * Wv[(128 + d) * D + l];
        sum1 += wdB * Wv[(128 + d) * D + 64 + l];
    }
    float dnA = dn_s[hA], dnB = dn_s[hB];
    float invA = 1.0f / (dnA + 1e-16f);
    float invB = 1.0f / (dnB + 1e-16f);
    oat[(size_t)b * D + l] = sum0 * invA + bv[l] * (dnA * invA);
    oat[(size_t)b * D + 64 + l] = sum1 * invB + bv[64 + l] * (dnB * invB);
}

__device__ __forceinline__ float gelu_exact(float x) {
    return 0.5f * x * (1.0f + erff(x * 0.70710678118654752f));
}

// out MLP: x1 = oat@Wout + bout; h = gelu(x1@Wt1 + bt1); y = h@Wt2 + bt2
__global__ void __launch_bounds__(128) k_mlp(
    const float* __restrict__ oat, const float* __restrict__ Wout,
    const float* __restrict__ bout, const float* __restrict__ Wt1,
    const float* __restrict__ bt1, const float* __restrict__ Wt2,
    const float* __restrict__ bt2, float* __restrict__ y, int NB) {
    __shared__ float s[8][D], x1[8][D], hs[8][D];
    int b0 = blockIdx.x * 8;
    int c = threadIdx.x;
#pragma unroll
    for (int b = 0; b < 8; ++b) {
        int bi = b0 + b;
        s[b][c] = (bi < NB) ? oat[(size_t)bi * D + c] : 0.f;
    }
    __syncthreads();
    float acc[8];
    float bo = bout[c];
#pragma unroll
    for (int b = 0; b < 8; ++b) acc[b] = bo;
    for (int d = 0; d < D; ++d) {
        float w = Wout[d * D + c];
#pragma unroll
        for (int b = 0; b < 8; ++b) acc[b] += s[b][d] * w;
    }
#pragma unroll
    for (int b = 0; b < 8; ++b) x1[b][c] = acc[b];
    __syncthreads();
    float bt = bt1[c];
#pragma unroll
    for (int b = 0; b < 8; ++b) acc[b] = bt;
    for (int d = 0; d < D; ++d) {
        float w = Wt1[d * D + c];
#pragma unroll
        for (int b = 0; b < 8; ++b) acc[b] += x1[b][d] * w;
    }
#pragma unroll
    for (int b = 0; b < 8; ++b) hs[b][c] = gelu_exact(acc[b]);
    __syncthreads();
    // final 128->2 per bond
    int b2 = c >> 4;       // 0..7
    int l16 = c & 15;
    float p0 = 0.f, p1 = 0.f;
#pragma unroll
    for (int k = 0; k < 8; ++k) {
        int d = l16 + 16 * k;
        float hv = hs[b2][d];
        p0 += hv * Wt2[d * 2 + 0];
        p1 += hv * Wt2[d * 2 + 1];
    }
    p0 += __shfl_xor(p0, 1); p1 += __shfl_xor(p1, 1);
    p0 += __shfl_xor(p0, 2); p1 += __shfl_xor(p1, 2);
    p0 += __shfl_xor(p0, 4); p1 += __shfl_xor(p1, 4);
    p0 += __shfl_xor(p0, 8); p1 += __shfl_xor(p1, 8);
    int bi = b0 + b2;
    if (l16 == 0 && bi < NB) {
        y[bi * 2 + 0] = p0 + bt2[0];
        y[bi * 2 + 1] = p1 + bt2[1];
    }
}

extern "C" void kernel_launch(void* const* d_in, const int* in_sizes, int n_in,
                              void* d_out, int out_size, void* d_ws, size_t ws_size,
                              hipStream_t stream) {
    const float* af     = (const float*)d_in[0];
    const float* coords = (const float*)d_in[1];
    const int*   rbi    = (const int*)d_in[2];
    const int*   etgt   = (const int*)d_in[3];
    const int*   esrc   = (const int*)d_in[4];
    const int*   tt     = (const int*)d_in[5];
    const float* W_dih  = (const float*)d_in[6];
    const float* b_dih  = (const float*)d_in[7];
    const float* Wq     = (const float*)d_in[8];
    const float* bq     = (const float*)d_in[9];
    const float* Wk     = (const float*)d_in[10];
    const float* bk     = (const float*)d_in[11];
    const float* Wv     = (const float*)d_in[12];
    const float* bv     = (const float*)d_in[13];
    const float* Wout   = (const float*)d_in[14];
    const float* bout   = (const float*)d_in[15];
    const float* Wt1    = (const float*)d_in[16];
    const float* bt1    = (const float*)d_in[17];
    const float* Wt2    = (const float*)d_in[18];
    const float* bt2    = (const float*)d_in[19];

    int N  = in_sizes[0] / D;
    int NB = in_sizes[2] / 2;
    int E  = in_sizes[3];

    char* ws = (char*)d_ws;
    size_t off = 0;
    auto alloc = [&](size_t bytes) -> char* {
        char* p = ws + off;
        off = (off + bytes + 255) & ~(size_t)255;
        return p;
    };
    float* ka     = (float*)alloc((size_t)N * D * 4);
    float* va     = (float*)alloc((size_t)N * D * 4);
    float* qv     = (float*)alloc((size_t)NB * D * 4);
    float* rbp    = (float*)alloc((size_t)NB * 3 * 4);
    float* oat    = (float*)alloc((size_t)NB * D * 4);
    int*   cnt2   = (int*)alloc((size_t)2 * NB * 4); // cnt | cursor
    int*   cnt    = cnt2;
    int*   cursor = cnt2 + NB;
    int*   offs   = (int*)alloc((size_t)(NB + 1) * 4);
    int*   perm   = (int*)alloc((size_t)E * 4);

    k_zero<<<(2 * NB + 255) / 256, 256, 0, stream>>>(cnt2, 2 * NB);
    k_atomproj<<<(N + 15) / 16, 128, 0, stream>>>(af, Wk, Wv, ka, va, N);
    k_bondfeats<<<(NB + 7) / 8, 128, 0, stream>>>(af, coords, rbi, tt, W_dih,
                                                  b_dih, Wq, bq, qv, rbp, NB);
    k_count<<<(E + 255) / 256, 256, 0, stream>>>(etgt, cnt, E);
    k_scan<<<1, 1024, 0, stream>>>(cnt, offs, NB);
    k_scatter<<<(E + 255) / 256, 256, 0, stream>>>(etgt, offs, cursor, perm, E);
    k_attn<<<NB, 64, 0, stream>>>(qv, ka, va, coords, rbp, esrc, perm, offs,
                                  Wk, Wv, bk, bv, oat, NB);
    k_mlp<<<(NB + 7) / 8, 128, 0, stream>>>(oat, Wout, bout, Wt1, bt1, Wt2,
                                            bt2, (float*)d_out, NB);
}

// Round 2
// 378.697 us; speedup vs baseline: 1.1136x; 1.1136x over previous
//
#include <hip/hip_runtime.h>
#include <math.h>

#define D 128
#define DDIM 32
#define NHEAD 8

typedef float4 f4;

__global__ void k_zero(int* __restrict__ p, int n) {
    int i = blockIdx.x * blockDim.x + threadIdx.x;
    if (i < n) p[i] = 0;
}

// ka = af @ Wk[:128,:], va = af @ Wv[:128,:]
__global__ void __launch_bounds__(128) k_atomproj(
    const float* __restrict__ af, const float* __restrict__ Wk,
    const float* __restrict__ Wv, float* __restrict__ ka,
    float* __restrict__ va, int N) {
    __shared__ float s[16][D];
    int a0 = blockIdx.x * 16;
    int c = threadIdx.x;
#pragma unroll
    for (int a = 0; a < 16; ++a) {
        int ai = a0 + a;
        s[a][c] = (ai < N) ? af[(size_t)ai * D + c] : 0.f;
    }
    __syncthreads();
    float acck[16], accv[16];
#pragma unroll
    for (int a = 0; a < 16; ++a) { acck[a] = 0.f; accv[a] = 0.f; }
    for (int d = 0; d < D; ++d) {
        float wk = Wk[d * D + c];
        float wv = Wv[d * D + c];
#pragma unroll
        for (int a = 0; a < 16; ++a) {
            float x = s[a][d];
            acck[a] += x * wk;
            accv[a] += x * wv;
        }
    }
#pragma unroll
    for (int a = 0; a < 16; ++a) {
        int ai = a0 + a;
        if (ai < N) {
            ka[(size_t)ai * D + c] = acck[a];
            va[(size_t)ai * D + c] = accv[a];
        }
    }
}

// per-bond: rb_pos, rb_feats, q (scaled by 0.25), tk = WkB . q, qb = q . bk
__global__ void __launch_bounds__(128) k_bondfeats(
    const float* __restrict__ af, const float* __restrict__ coords,
    const int* __restrict__ rbi, const int* __restrict__ tt,
    const float* __restrict__ W_dih, const float* __restrict__ b_dih,
    const float* __restrict__ Wq, const float* __restrict__ bq,
    const float* __restrict__ Wk, const float* __restrict__ bk,
    float* __restrict__ qv, float* __restrict__ rbp,
    float* __restrict__ tkg, float* __restrict__ qbg, int NB) {
    __shared__ float s1[8][D], s2[8][D], rf[8][D], qs[8][D];
    int b0 = blockIdx.x * 8;
    int c = threadIdx.x;
#pragma unroll
    for (int b = 0; b < 8; ++b) {
        int bi = b0 + b;
        if (bi < NB) {
            int i0 = tt[bi * 4 + 0], i1 = tt[bi * 4 + 1];
            int i2 = tt[bi * 4 + 2], i3 = tt[bi * 4 + 3];
            s1[b][c] = af[(size_t)i0 * D + c] + af[(size_t)i3 * D + c];
            s2[b][c] = af[(size_t)i1 * D + c] + af[(size_t)i2 * D + c];
        } else {
            s1[b][c] = 0.f; s2[b][c] = 0.f;
        }
    }
    if (c < 24) {
        int b = c / 3, x = c % 3;
        int bi = b0 + b;
        if (bi < NB) {
            int a0i = rbi[bi], a1i = rbi[NB + bi];
            rbp[bi * 3 + x] = 0.5f * (coords[a0i * 3 + x] + coords[a1i * 3 + x]);
        }
    }
    __syncthreads();
    float acc[8];
    float bd2 = 2.f * b_dih[c];
#pragma unroll
    for (int b = 0; b < 8; ++b) acc[b] = bd2;
    for (int d = 0; d < D; ++d) {
        float wa = W_dih[d * D + c] + W_dih[(384 + d) * D + c];
        float wb = W_dih[(128 + d) * D + c] + W_dih[(256 + d) * D + c];
#pragma unroll
        for (int b = 0; b < 8; ++b) acc[b] += s1[b][d] * wa + s2[b][d] * wb;
    }
#pragma unroll
    for (int b = 0; b < 8; ++b) rf[b][c] = acc[b];
    __syncthreads();
    float accq[8];
    float bqc = bq[c];
#pragma unroll
    for (int b = 0; b < 8; ++b) accq[b] = bqc;
    for (int d = 0; d < D; ++d) {
        float wq = Wq[d * D + c];
#pragma unroll
        for (int b = 0; b < 8; ++b) accq[b] += rf[b][d] * wq;
    }
#pragma unroll
    for (int b = 0; b < 8; ++b) {
        float qq = accq[b] * 0.25f;   // fold 1/sqrt(HEAD_DIM)
        qs[b][c] = qq;
        int bi = b0 + b;
        if (bi < NB) qv[(size_t)bi * D + c] = qq;
    }
    __syncthreads();
    // tk[b][h][d] = sum_cc WkB[d][h*16+cc] * q[b][h*16+cc]
    int h = c >> 4;
    int dx = (c & 15) * 2;
    float w0[16], w1[16];
#pragma unroll
    for (int cc = 0; cc < 16; ++cc) {
        w0[cc] = Wk[(128 + dx) * D + h * 16 + cc];
        w1[cc] = Wk[(129 + dx) * D + h * 16 + cc];
    }
#pragma unroll
    for (int b = 0; b < 8; ++b) {
        float t0 = 0.f, t1 = 0.f;
#pragma unroll
        for (int cc = 0; cc < 16; ++cc) {
            float qq = qs[b][h * 16 + cc];
            t0 += w0[cc] * qq;
            t1 += w1[cc] * qq;
        }
        int bi = b0 + b;
        if (bi < NB) {
            tkg[(size_t)bi * 256 + h * 32 + dx]     = t0;
            tkg[(size_t)bi * 256 + h * 32 + dx + 1] = t1;
        }
    }
    // qb[b][h] = sum_c q[b][h*16+cc] * bk[h*16+cc]
    float bkv = bk[h * 16 + (c & 15)];
#pragma unroll
    for (int b = 0; b < 8; ++b) {
        float p = qs[b][h * 16 + (c & 15)] * bkv;
        p += __shfl_xor(p, 1);
        p += __shfl_xor(p, 2);
        p += __shfl_xor(p, 4);
        p += __shfl_xor(p, 8);
        int bi = b0 + b;
        if ((c & 15) == 0 && bi < NB) qbg[bi * 8 + h] = p;
    }
}

__global__ void k_count(const int* __restrict__ etgt, int* __restrict__ cnt, int E) {
    int e = blockIdx.x * blockDim.x + threadIdx.x;
    if (e < E) atomicAdd(&cnt[etgt[e]], 1);
}

__global__ void __launch_bounds__(1024) k_scan(const int* __restrict__ cnt,
                                               int* __restrict__ offs, int NB) {
    __shared__ int part[1024];
    int t = threadIdx.x;
    int CH = (NB + 1023) >> 10;
    int base = t * CH;
    int s = 0;
    for (int i = 0; i < CH; ++i) {
        int idx = base + i;
        if (idx < NB) s += cnt[idx];
    }
    part[t] = s;
    __syncthreads();
    for (int off = 1; off < 1024; off <<= 1) {
        int v = (t >= off) ? part[t - off] : 0;
        __syncthreads();
        part[t] += v;
        __syncthreads();
    }
    int run = part[t] - s;
    for (int i = 0; i < CH; ++i) {
        int idx = base + i;
        if (idx < NB) {
            offs[idx] = run;
            run += cnt[idx];
        }
    }
    if (t == 1023) offs[NB] = part[1023];
}

// scatter sorted-by-bond src + precomputed dist
__global__ void k_scatter(const int* __restrict__ etgt, const int* __restrict__ esrc,
                          const float* __restrict__ coords, const float* __restrict__ rbp,
                          const int* __restrict__ offs, int* __restrict__ cursor,
                          int* __restrict__ ssrc, float* __restrict__ sdist, int E) {
    int e = blockIdx.x * blockDim.x + threadIdx.x;
    if (e < E) {
        int t = etgt[e];
        int pos = atomicAdd(&cursor[t], 1);
        int idx = offs[t] + pos;
        int src = esrc[e];
        ssrc[idx] = src;
        float dx = coords[src * 3 + 0] - rbp[t * 3 + 0];
        float dy = coords[src * 3 + 1] - rbp[t * 3 + 1];
        float dz = coords[src * 3 + 2] - rbp[t * 3 + 2];
        sdist[idx] = sqrtf(dx * dx + dy * dy + dz * dz);
    }
}

// one wave per 2 bonds; chunked edge-parallel segment attention
__global__ void __launch_bounds__(64) k_attn(
    const float* __restrict__ qv, const float* __restrict__ tkg,
    const float* __restrict__ qbg, const float* __restrict__ ka,
    const float* __restrict__ va, const int* __restrict__ ssrc,
    const float* __restrict__ sdist, const int* __restrict__ offs,
    const float* __restrict__ Wv, const float* __restrict__ bv,
    float* __restrict__ oat, int NB) {
    __shared__ float q_s[2][128];
    __shared__ float tk_s[2][256];
    __shared__ float qb_s[2][8];
    __shared__ int   src_s[2][32];
    __shared__ float de_s[2][32 * 36];
    __shared__ float w_s[2][32 * 9];   // reused as wde[2][8*32] in epilogue

    int l = threadIdx.x;
    int half = l >> 5;
    int j = l & 31;
    int bb = blockIdx.x * 2 + half;
    bool vb = bb < NB;

    if (vb) {
#pragma unroll
        for (int i = 0; i < 4; ++i)
            q_s[half][j + 32 * i] = qv[(size_t)bb * D + j + 32 * i];
#pragma unroll
        for (int i = 0; i < 8; ++i)
            tk_s[half][j + 32 * i] = tkg[(size_t)bb * 256 + j + 32 * i];
        if (j < 8) qb_s[half][j] = qbg[bb * 8 + j];
    }
    int base = 0, ne = 0;
    if (vb) { base = offs[bb]; ne = offs[bb + 1] - base; }
    int mych = (ne + 31) >> 5;
    int och = __shfl_xor(mych, 32);
    int nch = mych > och ? mych : och;
    __syncthreads();

    const float step = 5.0f / 31.0f;
    const float coeff = -0.5f / (step * step);

    float dnp[8];
#pragma unroll
    for (int h = 0; h < 8; ++h) dnp[h] = 0.f;
    f4 acc = make_float4(0.f, 0.f, 0.f, 0.f);
    f4 wa  = make_float4(0.f, 0.f, 0.f, 0.f);
    f4 wb  = make_float4(0.f, 0.f, 0.f, 0.f);

    const f4* ka4 = (const f4*)ka;
    const f4* va4 = (const f4*)va;
    const f4* q4  = (const f4*)&q_s[half][0];
    const f4* tk4 = (const f4*)&tk_s[half][0];
    const f4* de4 = (const f4*)&de_s[half][0];
    int h4 = j >> 2;          // head owning channels 4j..4j+3
    int dq = 2 * (j & 3);     // f4 index base into de row for wde

    for (int cb = 0; cb < nch; ++cb) {
        int ebase = cb * 32;
        int nec = ne - ebase;
        nec = nec < 0 ? 0 : (nec > 32 ? 32 : nec);
        // ---- phase A: edge-parallel scores ----
        if (j < nec) {
            int eg = base + ebase + j;
            int src = ssrc[eg];
            float dist = sdist[eg];
            src_s[half][j] = src;
            float de[32];
#pragma unroll
            for (int d = 0; d < 32; ++d) {
                float t = dist - step * (float)d;
                de[d] = __expf(coeff * t * t);
            }
            f4* dw = (f4*)&de_s[half][j * 36];
#pragma unroll
            for (int k = 0; k < 8; ++k)
                dw[k] = make_float4(de[4 * k], de[4 * k + 1], de[4 * k + 2], de[4 * k + 3]);
            float sc[8];
#pragma unroll
            for (int h = 0; h < 8; ++h) sc[h] = qb_s[half][h];
            const f4* kap = ka4 + (size_t)src * 32;
#pragma unroll
            for (int i = 0; i < 32; ++i) {
                f4 kv = kap[i];
                f4 qq = q4[i];
                sc[i >> 2] += qq.x * kv.x + qq.y * kv.y + qq.z * kv.z + qq.w * kv.w;
            }
#pragma unroll
            for (int h = 0; h < 8; ++h) {
                float s = 0.f;
#pragma unroll
                for (int k = 0; k < 8; ++k) {
                    f4 tkv = tk4[h * 8 + k];
                    s += de[4 * k] * tkv.x + de[4 * k + 1] * tkv.y
                       + de[4 * k + 2] * tkv.z + de[4 * k + 3] * tkv.w;
                }
                float wv_ = __expf(sc[h] + s);
                dnp[h] += wv_;
                w_s[half][j * 9 + h] = wv_;
            }
        }
        __syncthreads();
        // ---- phase B: channel-parallel accumulation ----
        for (int e = 0; e < nec; ++e) {
            int srcE = src_s[half][e];
            float ww = w_s[half][e * 9 + h4];
            f4 vv = va4[(size_t)srcE * 32 + j];
            acc.x += ww * vv.x; acc.y += ww * vv.y;
            acc.z += ww * vv.z; acc.w += ww * vv.w;
            f4 dA = de4[e * 9 + dq];
            f4 dB = de4[e * 9 + dq + 1];
            wa.x += ww * dA.x; wa.y += ww * dA.y; wa.z += ww * dA.z; wa.w += ww * dA.w;
            wb.x += ww * dB.x; wb.y += ww * dB.y; wb.z += ww * dB.z; wb.w += ww * dB.w;
        }
        __syncthreads();
    }
    // denominators: butterfly within 32-lane half
#pragma unroll
    for (int h = 0; h < 8; ++h) {
        float v = dnp[h];
        v += __shfl_xor(v, 1);
        v += __shfl_xor(v, 2);
        v += __shfl_xor(v, 4);
        v += __shfl_xor(v, 8);
        v += __shfl_xor(v, 16);
        dnp[h] = v;
    }
    float sw = dnp[h4];
    float inv = 1.0f / (sw + 1e-16f);
    // exchange wde via LDS (reuse w_s)
    float* wde = &w_s[half][0];   // [8][32]
    int dbase = 8 * (j & 3);
    wde[h4 * 32 + dbase + 0] = wa.x; wde[h4 * 32 + dbase + 1] = wa.y;
    wde[h4 * 32 + dbase + 2] = wa.z; wde[h4 * 32 + dbase + 3] = wa.w;
    wde[h4 * 32 + dbase + 4] = wb.x; wde[h4 * 32 + dbase + 5] = wb.y;
    wde[h4 * 32 + dbase + 6] = wb.z; wde[h4 * 32 + dbase + 7] = wb.w;
    __syncthreads();
    f4 o = acc;
    const f4* wv4 = (const f4*)Wv;   // [160][32] f4 view
    for (int d = 0; d < 32; ++d) {
        float wd = wde[h4 * 32 + d];
        f4 wrow = wv4[(size_t)(128 + d) * 32 + j];
        o.x += wd * wrow.x; o.y += wd * wrow.y;
        o.z += wd * wrow.z; o.w += wd * wrow.w;
    }
    f4 bvv = ((const f4*)bv)[j];
    o.x = (o.x + bvv.x * sw) * inv;
    o.y = (o.y + bvv.y * sw) * inv;
    o.z = (o.z + bvv.z * sw) * inv;
    o.w = (o.w + bvv.w * sw) * inv;
    if (vb) ((f4*)oat)[(size_t)bb * 32 + j] = o;
}

__device__ __forceinline__ float gelu_exact(float x) {
    return 0.5f * x * (1.0f + erff(x * 0.70710678118654752f));
}

__global__ void __launch_bounds__(128) k_mlp(
    const float* __restrict__ oat, const float* __restrict__ Wout,
    const float* __restrict__ bout, const float* __restrict__ Wt1,
    const float* __restrict__ bt1, const float* __restrict__ Wt2,
    const float* __restrict__ bt2, float* __restrict__ y, int NB) {
    __shared__ float s[8][D], x1[8][D], hs[8][D];
    int b0 = blockIdx.x * 8;
    int c = threadIdx.x;
#pragma unroll
    for (int b = 0; b < 8; ++b) {
        int bi = b0 + b;
        s[b][c] = (bi < NB) ? oat[(size_t)bi * D + c] : 0.f;
    }
    __syncthreads();
    float acc[8];
    float bo = bout[c];
#pragma unroll
    for (int b = 0; b < 8; ++b) acc[b] = bo;
    for (int d = 0; d < D; ++d) {
        float w = Wout[d * D + c];
#pragma unroll
        for (int b = 0; b < 8; ++b) acc[b] += s[b][d] * w;
    }
#pragma unroll
    for (int b = 0; b < 8; ++b) x1[b][c] = acc[b];
    __syncthreads();
    float bt = bt1[c];
#pragma unroll
    for (int b = 0; b < 8; ++b) acc[b] = bt;
    for (int d = 0; d < D; ++d) {
        float w = Wt1[d * D + c];
#pragma unroll
        for (int b = 0; b < 8; ++b) acc[b] += x1[b][d] * w;
    }
#pragma unroll
    for (int b = 0; b < 8; ++b) hs[b][c] = gelu_exact(acc[b]);
    __syncthreads();
    int b2 = c >> 4;
    int l16 = c & 15;
    float p0 = 0.f, p1 = 0.f;
#pragma unroll
    for (int k = 0; k < 8; ++k) {
        int d = l16 + 16 * k;
        float hv = hs[b2][d];
        p0 += hv * Wt2[d * 2 + 0];
        p1 += hv * Wt2[d * 2 + 1];
    }
    p0 += __shfl_xor(p0, 1); p1 += __shfl_xor(p1, 1);
    p0 += __shfl_xor(p0, 2); p1 += __shfl_xor(p1, 2);
    p0 += __shfl_xor(p0, 4); p1 += __shfl_xor(p1, 4);
    p0 += __shfl_xor(p0, 8); p1 += __shfl_xor(p1, 8);
    int bi = b0 + b2;
    if (l16 == 0 && bi < NB) {
        y[bi * 2 + 0] = p0 + bt2[0];
        y[bi * 2 + 1] = p1 + bt2[1];
    }
}

extern "C" void kernel_launch(void* const* d_in, const int* in_sizes, int n_in,
                              void* d_out, int out_size, void* d_ws, size_t ws_size,
                              hipStream_t stream) {
    const float* af     = (const float*)d_in[0];
    const float* coords = (const float*)d_in[1];
    const int*   rbi    = (const int*)d_in[2];
    const int*   etgt   = (const int*)d_in[3];
    const int*   esrc   = (const int*)d_in[4];
    const int*   tt     = (const int*)d_in[5];
    const float* W_dih  = (const float*)d_in[6];
    const float* b_dih  = (const float*)d_in[7];
    const float* Wq     = (const float*)d_in[8];
    const float* bq     = (const float*)d_in[9];
    const float* Wk     = (const float*)d_in[10];
    const float* bk     = (const float*)d_in[11];
    const float* Wv     = (const float*)d_in[12];
    const float* bv     = (const float*)d_in[13];
    const float* Wout   = (const float*)d_in[14];
    const float* bout   = (const float*)d_in[15];
    const float* Wt1    = (const float*)d_in[16];
    const float* bt1    = (const float*)d_in[17];
    const float* Wt2    = (const float*)d_in[18];
    const float* bt2    = (const float*)d_in[19];

    int N  = in_sizes[0] / D;
    int NB = in_sizes[2] / 2;
    int E  = in_sizes[3];

    char* ws = (char*)d_ws;
    size_t off = 0;
    auto alloc = [&](size_t bytes) -> char* {
        char* p = ws + off;
        off = (off + bytes + 255) & ~(size_t)255;
        return p;
    };
    float* ka     = (float*)alloc((size_t)N * D * 4);
    float* va     = (float*)alloc((size_t)N * D * 4);
    float* qv     = (float*)alloc((size_t)NB * D * 4);
    float* rbp    = (float*)alloc((size_t)NB * 3 * 4);
    float* oat    = (float*)alloc((size_t)NB * D * 4);
    float* tkg    = (float*)alloc((size_t)NB * 256 * 4);
    float* qbg    = (float*)alloc((size_t)NB * 8 * 4);
    int*   cnt2   = (int*)alloc((size_t)2 * NB * 4);
    int*   cnt    = cnt2;
    int*   cursor = cnt2 + NB;
    int*   offs   = (int*)alloc((size_t)(NB + 1) * 4);
    int*   ssrc   = (int*)alloc((size_t)E * 4);
    float* sdist  = (float*)alloc((size_t)E * 4);

    k_zero<<<(2 * NB + 255) / 256, 256, 0, stream>>>(cnt2, 2 * NB);
    k_atomproj<<<(N + 15) / 16, 128, 0, stream>>>(af, Wk, Wv, ka, va, N);
    k_bondfeats<<<(NB + 7) / 8, 128, 0, stream>>>(af, coords, rbi, tt, W_dih,
                                                  b_dih, Wq, bq, Wk, bk,
                                                  qv, rbp, tkg, qbg, NB);
    k_count<<<(E + 255) / 256, 256, 0, stream>>>(etgt, cnt, E);
    k_scan<<<1, 1024, 0, stream>>>(cnt, offs, NB);
    k_scatter<<<(E + 255) / 256, 256, 0, stream>>>(etgt, esrc, coords, rbp,
                                                   offs, cursor, ssrc, sdist, E);
    k_attn<<<(NB + 1) / 2, 64, 0, stream>>>(qv, tkg, qbg, ka, va, ssrc, sdist,
                                            offs, Wv, bv, oat, NB);
    k_mlp<<<(NB + 7) / 8, 128, 0, stream>>>(oat, Wout, bout, Wt1, bt1, Wt2,
                                            bt2, (float*)d_out, NB);
}

// Round 4
// 366.497 us; speedup vs baseline: 1.1506x; 1.0333x over previous
//
#include <hip/hip_runtime.h>
#include <math.h>

#define D 128
#define DDIM 32
#define NHEAD 8

typedef float4 f4;

__global__ void k_zero(int* __restrict__ p, int n) {
    int i = blockIdx.x * blockDim.x + threadIdx.x;
    if (i < n) p[i] = 0;
}

// ka = af @ Wk[:128,:], va = af @ Wv[:128,:]  (f4-tiled)
__global__ void __launch_bounds__(256) k_atomproj(
    const float* __restrict__ af, const float* __restrict__ Wk,
    const float* __restrict__ Wv, float* __restrict__ ka,
    float* __restrict__ va, int N) {
    __shared__ __align__(16) float s[32 * 128];
    f4* s4 = (f4*)s;
    int a0 = blockIdx.x * 32;
    int t = threadIdx.x;
    const f4* af4 = (const f4*)af;
#pragma unroll
    for (int i = 0; i < 4; ++i) {
        int idx = t + 256 * i;          // [0,1024): a=idx>>5, q=idx&31
        int a = idx >> 5;
        f4 z = make_float4(0.f, 0.f, 0.f, 0.f);
        s4[idx] = (a0 + a < N) ? af4[(size_t)(a0 + a) * 32 + (idx & 31)] : z;
    }
    __syncthreads();
    int c = t & 127;
    int half = t >> 7;
    float acck[16], accv[16];
#pragma unroll
    for (int a = 0; a < 16; ++a) { acck[a] = 0.f; accv[a] = 0.f; }
    for (int dq = 0; dq < 32; ++dq) {
        float k0 = Wk[(4 * dq + 0) * D + c];
        float k1 = Wk[(4 * dq + 1) * D + c];
        float k2 = Wk[(4 * dq + 2) * D + c];
        float k3 = Wk[(4 * dq + 3) * D + c];
        float v0 = Wv[(4 * dq + 0) * D + c];
        float v1 = Wv[(4 * dq + 1) * D + c];
        float v2 = Wv[(4 * dq + 2) * D + c];
        float v3 = Wv[(4 * dq + 3) * D + c];
#pragma unroll
        for (int a = 0; a < 16; ++a) {
            f4 sv = s4[(half * 16 + a) * 32 + dq];
            acck[a] += sv.x * k0 + sv.y * k1 + sv.z * k2 + sv.w * k3;
            accv[a] += sv.x * v0 + sv.y * v1 + sv.z * v2 + sv.w * v3;
        }
    }
#pragma unroll
    for (int a = 0; a < 16; ++a) {
        int ai = a0 + half * 16 + a;
        if (ai < N) {
            ka[(size_t)ai * D + c] = acck[a];
            va[(size_t)ai * D + c] = accv[a];
        }
    }
}

// per-bond: rb_pos, rb_feats, q (scaled 0.25), tk = WkB.q, qb = q.bk
__global__ void __launch_bounds__(128) k_bondfeats(
    const float* __restrict__ af, const float* __restrict__ coords,
    const int* __restrict__ rbi, const int* __restrict__ tt,
    const float* __restrict__ W_dih, const float* __restrict__ b_dih,
    const float* __restrict__ Wq, const float* __restrict__ bq,
    const float* __restrict__ Wk, const float* __restrict__ bk,
    float* __restrict__ qv, float* __restrict__ rbp,
    float* __restrict__ tkg, float* __restrict__ qbg, int NB) {
    __shared__ __align__(16) float s1[8][D], s2[8][D], rf[8][D], qs[8][D];
    int b0 = blockIdx.x * 8;
    int c = threadIdx.x;
#pragma unroll
    for (int b = 0; b < 8; ++b) {
        int bi = b0 + b;
        if (bi < NB) {
            int i0 = tt[bi * 4 + 0], i1 = tt[bi * 4 + 1];
            int i2 = tt[bi * 4 + 2], i3 = tt[bi * 4 + 3];
            s1[b][c] = af[(size_t)i0 * D + c] + af[(size_t)i3 * D + c];
            s2[b][c] = af[(size_t)i1 * D + c] + af[(size_t)i2 * D + c];
        } else {
            s1[b][c] = 0.f; s2[b][c] = 0.f;
        }
    }
    if (c < 24) {
        int b = c / 3, x = c % 3;
        int bi = b0 + b;
        if (bi < NB) {
            int a0i = rbi[bi], a1i = rbi[NB + bi];
            rbp[bi * 3 + x] = 0.5f * (coords[a0i * 3 + x] + coords[a1i * 3 + x]);
        }
    }
    __syncthreads();
    float acc[8];
    float bd2 = 2.f * b_dih[c];
#pragma unroll
    for (int b = 0; b < 8; ++b) acc[b] = bd2;
    for (int dq = 0; dq < 32; ++dq) {
        float wa0 = W_dih[(4 * dq + 0) * D + c] + W_dih[(384 + 4 * dq + 0) * D + c];
        float wa1 = W_dih[(4 * dq + 1) * D + c] + W_dih[(384 + 4 * dq + 1) * D + c];
        float wa2 = W_dih[(4 * dq + 2) * D + c] + W_dih[(384 + 4 * dq + 2) * D + c];
        float wa3 = W_dih[(4 * dq + 3) * D + c] + W_dih[(384 + 4 * dq + 3) * D + c];
        float wb0 = W_dih[(128 + 4 * dq + 0) * D + c] + W_dih[(256 + 4 * dq + 0) * D + c];
        float wb1 = W_dih[(128 + 4 * dq + 1) * D + c] + W_dih[(256 + 4 * dq + 1) * D + c];
        float wb2 = W_dih[(128 + 4 * dq + 2) * D + c] + W_dih[(256 + 4 * dq + 2) * D + c];
        float wb3 = W_dih[(128 + 4 * dq + 3) * D + c] + W_dih[(256 + 4 * dq + 3) * D + c];
#pragma unroll
        for (int b = 0; b < 8; ++b) {
            f4 v1 = *(const f4*)&s1[b][4 * dq];
            f4 v2 = *(const f4*)&s2[b][4 * dq];
            acc[b] += v1.x * wa0 + v1.y * wa1 + v1.z * wa2 + v1.w * wa3
                    + v2.x * wb0 + v2.y * wb1 + v2.z * wb2 + v2.w * wb3;
        }
    }
#pragma unroll
    for (int b = 0; b < 8; ++b) rf[b][c] = acc[b];
    __syncthreads();
    float accq[8];
    float bqc = bq[c];
#pragma unroll
    for (int b = 0; b < 8; ++b) accq[b] = bqc;
    for (int dq = 0; dq < 32; ++dq) {
        float w0 = Wq[(4 * dq + 0) * D + c];
        float w1 = Wq[(4 * dq + 1) * D + c];
        float w2 = Wq[(4 * dq + 2) * D + c];
        float w3 = Wq[(4 * dq + 3) * D + c];
#pragma unroll
        for (int b = 0; b < 8; ++b) {
            f4 v = *(const f4*)&rf[b][4 * dq];
            accq[b] += v.x * w0 + v.y * w1 + v.z * w2 + v.w * w3;
        }
    }
#pragma unroll
    for (int b = 0; b < 8; ++b) {
        float qq = accq[b] * 0.25f;     // fold 1/sqrt(HEAD_DIM)
        qs[b][c] = qq;
        int bi = b0 + b;
        if (bi < NB) qv[(size_t)bi * D + c] = qq;
    }
    __syncthreads();
    // tk[b][h][d] = sum_cc WkB[d][h*16+cc] * q[b][h*16+cc]
    int h = c >> 4;
    int dx = (c & 15) * 2;
    float w0[16], w1[16];
#pragma unroll
    for (int cc = 0; cc < 16; ++cc) {
        w0[cc] = Wk[(128 + dx) * D + h * 16 + cc];
        w1[cc] = Wk[(129 + dx) * D + h * 16 + cc];
    }
#pragma unroll
    for (int b = 0; b < 8; ++b) {
        float t0 = 0.f, t1 = 0.f;
#pragma unroll
        for (int k = 0; k < 4; ++k) {
            f4 qq = *(const f4*)&qs[b][h * 16 + 4 * k];
            t0 += w0[4 * k] * qq.x + w0[4 * k + 1] * qq.y + w0[4 * k + 2] * qq.z + w0[4 * k + 3] * qq.w;
            t1 += w1[4 * k] * qq.x + w1[4 * k + 1] * qq.y + w1[4 * k + 2] * qq.z + w1[4 * k + 3] * qq.w;
        }
        int bi = b0 + b;
        if (bi < NB) {
            tkg[(size_t)bi * 256 + h * 32 + dx]     = t0;
            tkg[(size_t)bi * 256 + h * 32 + dx + 1] = t1;
        }
    }
    float bkv = bk[h * 16 + (c & 15)];
#pragma unroll
    for (int b = 0; b < 8; ++b) {
        float p = qs[b][h * 16 + (c & 15)] * bkv;
        p += __shfl_xor(p, 1);
        p += __shfl_xor(p, 2);
        p += __shfl_xor(p, 4);
        p += __shfl_xor(p, 8);
        int bi = b0 + b;
        if ((c & 15) == 0 && bi < NB) qbg[bi * 8 + h] = p;
    }
}

__global__ void k_count(const int* __restrict__ etgt, int* __restrict__ cnt, int E) {
    int e = blockIdx.x * blockDim.x + threadIdx.x;
    if (e < E) atomicAdd(&cnt[etgt[e]], 1);
}

__global__ void __launch_bounds__(1024) k_scan(const int* __restrict__ cnt,
                                               int* __restrict__ offs, int NB) {
    __shared__ int part[1024];
    int t = threadIdx.x;
    int CH = (NB + 1023) >> 10;
    int base = t * CH;
    int s = 0;
    for (int i = 0; i < CH; ++i) {
        int idx = base + i;
        if (idx < NB) s += cnt[idx];
    }
    part[t] = s;
    __syncthreads();
    for (int off = 1; off < 1024; off <<= 1) {
        int v = (t >= off) ? part[t - off] : 0;
        __syncthreads();
        part[t] += v;
        __syncthreads();
    }
    int run = part[t] - s;
    for (int i = 0; i < CH; ++i) {
        int idx = base + i;
        if (idx < NB) {
            offs[idx] = run;
            run += cnt[idx];
        }
    }
    if (t == 1023) offs[NB] = part[1023];
}

__global__ void k_scatter(const int* __restrict__ etgt, const int* __restrict__ esrc,
                          const float* __restrict__ coords, const float* __restrict__ rbp,
                          const int* __restrict__ offs, int* __restrict__ cursor,
                          int* __restrict__ ssrc, float* __restrict__ sdist, int E) {
    int e = blockIdx.x * blockDim.x + threadIdx.x;
    if (e < E) {
        int t = etgt[e];
        int pos = atomicAdd(&cursor[t], 1);
        int idx = offs[t] + pos;
        int src = esrc[e];
        ssrc[idx] = src;
        float dx = coords[src * 3 + 0] - rbp[t * 3 + 0];
        float dy = coords[src * 3 + 1] - rbp[t * 3 + 1];
        float dz = coords[src * 3 + 2] - rbp[t * 3 + 2];
        sdist[idx] = sqrtf(dx * dx + dy * dy + dz * dz);
    }
}

// one wave per 2 bonds; writes macc = sum w*va[src] (per-channel head weight),
// wde[8][32], dn[8]; WvB/bv projection deferred to k_mlp
__global__ void __launch_bounds__(64) k_attn(
    const float* __restrict__ qv, const float* __restrict__ tkg,
    const float* __restrict__ qbg, const float* __restrict__ ka,
    const float* __restrict__ va, const int* __restrict__ ssrc,
    const float* __restrict__ sdist, const int* __restrict__ offs,
    float* __restrict__ macc, float* __restrict__ wdeg,
    float* __restrict__ dnb, int NB) {
    __shared__ __align__(16) float q_s[2][128];
    __shared__ __align__(16) float tk_s[2][256];
    __shared__ float qb_s[2][8];
    __shared__ int   src_s[2][32];
    __shared__ __align__(16) float de_s[2][32 * 36];
    __shared__ float w_s[2][32 * 9];

    int l = threadIdx.x;
    int half = l >> 5;
    int j = l & 31;
    int bb = blockIdx.x * 2 + half;
    bool vb = bb < NB;

    if (vb) {
#pragma unroll
        for (int i = 0; i < 4; ++i)
            q_s[half][j + 32 * i] = qv[(size_t)bb * D + j + 32 * i];
#pragma unroll
        for (int i = 0; i < 8; ++i)
            tk_s[half][j + 32 * i] = tkg[(size_t)bb * 256 + j + 32 * i];
        if (j < 8) qb_s[half][j] = qbg[bb * 8 + j];
    }
    int base = 0, ne = 0;
    if (vb) { base = offs[bb]; ne = offs[bb + 1] - base; }
    int mych = (ne + 31) >> 5;
    int och = __shfl_xor(mych, 32);
    int nch = mych > och ? mych : och;
    __syncthreads();

    const float step = 5.0f / 31.0f;
    const float coeff = -0.5f / (step * step);

    float dnp[8];
#pragma unroll
    for (int h = 0; h < 8; ++h) dnp[h] = 0.f;
    f4 acc = make_float4(0.f, 0.f, 0.f, 0.f);
    f4 wa  = make_float4(0.f, 0.f, 0.f, 0.f);
    f4 wb  = make_float4(0.f, 0.f, 0.f, 0.f);

    const f4* ka4 = (const f4*)ka;
    const f4* va4 = (const f4*)va;
    const f4* q4  = (const f4*)&q_s[half][0];
    const f4* tk4 = (const f4*)&tk_s[half][0];
    const f4* de4 = (const f4*)&de_s[half][0];
    int h4 = j >> 2;
    int dq = 2 * (j & 3);

    for (int cb = 0; cb < nch; ++cb) {
        int ebase = cb * 32;
        int nec = ne - ebase;
        nec = nec < 0 ? 0 : (nec > 32 ? 32 : nec);
        // ---- phase A: edge-parallel scores ----
        if (j < nec) {
            int eg = base + ebase + j;
            int src = ssrc[eg];
            float dist = sdist[eg];
            src_s[half][j] = src;
            float de[32];
#pragma unroll
            for (int d = 0; d < 32; ++d) {
                float t = dist - step * (float)d;
                de[d] = __expf(coeff * t * t);
            }
            f4* dw = (f4*)&de_s[half][j * 36];
#pragma unroll
            for (int k = 0; k < 8; ++k)
                dw[k] = make_float4(de[4 * k], de[4 * k + 1], de[4 * k + 2], de[4 * k + 3]);
            float sc[8];
#pragma unroll
            for (int h = 0; h < 8; ++h) sc[h] = qb_s[half][h];
            const f4* kap = ka4 + (size_t)src * 32;
#pragma unroll
            for (int i = 0; i < 32; ++i) {
                f4 kv = kap[i];
                f4 qq = q4[i];
                sc[i >> 2] += qq.x * kv.x + qq.y * kv.y + qq.z * kv.z + qq.w * kv.w;
            }
#pragma unroll
            for (int h = 0; h < 8; ++h) {
                float s = 0.f;
#pragma unroll
                for (int k = 0; k < 8; ++k) {
                    f4 tkv = tk4[h * 8 + k];
                    s += de[4 * k] * tkv.x + de[4 * k + 1] * tkv.y
                       + de[4 * k + 2] * tkv.z + de[4 * k + 3] * tkv.w;
                }
                float wv_ = __expf(sc[h] + s);
                dnp[h] += wv_;
                w_s[half][j * 9 + h] = wv_;
            }
        }
        __syncthreads();
        // ---- phase B: channel-parallel accumulation (va gather) ----
        for (int e = 0; e < nec; ++e) {
            int srcE = src_s[half][e];
            float ww = w_s[half][e * 9 + h4];
            f4 vv = va4[(size_t)srcE * 32 + j];
            acc.x += ww * vv.x; acc.y += ww * vv.y;
            acc.z += ww * vv.z; acc.w += ww * vv.w;
            f4 dA = de4[e * 9 + dq];
            f4 dB = de4[e * 9 + dq + 1];
            wa.x += ww * dA.x; wa.y += ww * dA.y; wa.z += ww * dA.z; wa.w += ww * dA.w;
            wb.x += ww * dB.x; wb.y += ww * dB.y; wb.z += ww * dB.z; wb.w += ww * dB.w;
        }
        __syncthreads();
    }
#pragma unroll
    for (int h = 0; h < 8; ++h) {
        float v = dnp[h];
        v += __shfl_xor(v, 1);
        v += __shfl_xor(v, 2);
        v += __shfl_xor(v, 4);
        v += __shfl_xor(v, 8);
        v += __shfl_xor(v, 16);
        dnp[h] = v;
    }
    if (vb) {
        ((f4*)macc)[(size_t)bb * 32 + j] = acc;
        f4* wp = (f4*)&wdeg[(size_t)bb * 256 + h4 * 32 + 8 * (j & 3)];
        wp[0] = wa;
        wp[1] = wb;
        if (j < 8) dnb[bb * 8 + j] = dnp[j];
    }
}

__device__ __forceinline__ float gelu_exact(float x) {
    return 0.5f * x * (1.0f + erff(x * 0.70710678118654752f));
}

// v_in = (macc + wde@WvB + dn*bv)/dn -> Wout -> gelu(Wt1) -> Wt2
__global__ void __launch_bounds__(128) k_mlp(
    const float* __restrict__ macc, const float* __restrict__ wdeg,
    const float* __restrict__ dnb, const float* __restrict__ Wv,
    const float* __restrict__ bv, const float* __restrict__ Wout,
    const float* __restrict__ bout, const float* __restrict__ Wt1,
    const float* __restrict__ bt1, const float* __restrict__ Wt2,
    const float* __restrict__ bt2, float* __restrict__ y, int NB) {
    __shared__ __align__(16) float s[8][D], x1[8][D], wdl[8][256];
    __shared__ float dnl[8][8];
    int b0 = blockIdx.x * 8;
    int c = threadIdx.x;
#pragma unroll
    for (int b = 0; b < 8; ++b) {
        int bi = b0 + b;
        s[b][c] = (bi < NB) ? macc[(size_t)bi * D + c] : 0.f;
    }
#pragma unroll
    for (int i = 0; i < 16; ++i) {
        int idx = c + 128 * i;
        int b = idx >> 8, r = idx & 255;
        wdl[b][r] = (b0 + b < NB) ? wdeg[(size_t)(b0 + b) * 256 + r] : 0.f;
    }
    if (c < 64) {
        int b = c >> 3, h = c & 7;
        dnl[b][h] = (b0 + b < NB) ? dnb[(b0 + b) * 8 + h] : 0.f;
    }
    __syncthreads();
    int hh = c >> 4;
    float acc[8];
    // wde @ WvB (head-specific [8][32] deferral — per-head weights valid)
#pragma unroll
    for (int b = 0; b < 8; ++b) acc[b] = 0.f;
    for (int tq = 0; tq < 8; ++tq) {
        float w0 = Wv[(128 + 4 * tq + 0) * D + c];
        float w1 = Wv[(128 + 4 * tq + 1) * D + c];
        float w2 = Wv[(128 + 4 * tq + 2) * D + c];
        float w3 = Wv[(128 + 4 * tq + 3) * D + c];
#pragma unroll
        for (int b = 0; b < 8; ++b) {
            f4 v = *(const f4*)&wdl[b][hh * 32 + 4 * tq];
            acc[b] += v.x * w0 + v.y * w1 + v.z * w2 + v.w * w3;
        }
    }
    float bvc = bv[c];
#pragma unroll
    for (int b = 0; b < 8; ++b) {
        float dn = dnl[b][hh];
        float inv = 1.0f / (dn + 1e-16f);
        x1[b][c] = (s[b][c] + acc[b] + bvc * dn) * inv;   // v_in
    }
    __syncthreads();
    // Wout stage: x1 -> s
    float bo = bout[c];
#pragma unroll
    for (int b = 0; b < 8; ++b) acc[b] = bo;
    for (int dq = 0; dq < 32; ++dq) {
        float w0 = Wout[(4 * dq + 0) * D + c];
        float w1 = Wout[(4 * dq + 1) * D + c];
        float w2 = Wout[(4 * dq + 2) * D + c];
        float w3 = Wout[(4 * dq + 3) * D + c];
#pragma unroll
        for (int b = 0; b < 8; ++b) {
            f4 v = *(const f4*)&x1[b][4 * dq];
            acc[b] += v.x * w0 + v.y * w1 + v.z * w2 + v.w * w3;
        }
    }
    __syncthreads();
#pragma unroll
    for (int b = 0; b < 8; ++b) s[b][c] = acc[b];
    __syncthreads();
    // Wt1 + gelu: s -> x1
    float bt = bt1[c];
#pragma unroll
    for (int b = 0; b < 8; ++b) acc[b] = bt;
    for (int dq = 0; dq < 32; ++dq) {
        float w0 = Wt1[(4 * dq + 0) * D + c];
        float w1 = Wt1[(4 * dq + 1) * D + c];
        float w2 = Wt1[(4 * dq + 2) * D + c];
        float w3 = Wt1[(4 * dq + 3) * D + c];
#pragma unroll
        for (int b = 0; b < 8; ++b) {
            f4 v = *(const f4*)&s[b][4 * dq];
            acc[b] += v.x * w0 + v.y * w1 + v.z * w2 + v.w * w3;
        }
    }
    __syncthreads();
#pragma unroll
    for (int b = 0; b < 8; ++b) x1[b][c] = gelu_exact(acc[b]);
    __syncthreads();
    // final 128 -> 2
    int b2 = c >> 4;
    int l16 = c & 15;
    float p0 = 0.f, p1 = 0.f;
#pragma unroll
    for (int k = 0; k < 8; ++k) {
        int d = l16 + 16 * k;
        float hv = x1[b2][d];
        p0 += hv * Wt2[d * 2 + 0];
        p1 += hv * Wt2[d * 2 + 1];
    }
    p0 += __shfl_xor(p0, 1); p1 += __shfl_xor(p1, 1);
    p0 += __shfl_xor(p0, 2); p1 += __shfl_xor(p1, 2);
    p0 += __shfl_xor(p0, 4); p1 += __shfl_xor(p1, 4);
    p0 += __shfl_xor(p0, 8); p1 += __shfl_xor(p1, 8);
    int bi = b0 + b2;
    if (l16 == 0 && bi < NB) {
        y[bi * 2 + 0] = p0 + bt2[0];
        y[bi * 2 + 1] = p1 + bt2[1];
    }
}

extern "C" void kernel_launch(void* const* d_in, const int* in_sizes, int n_in,
                              void* d_out, int out_size, void* d_ws, size_t ws_size,
                              hipStream_t stream) {
    const float* af     = (const float*)d_in[0];
    const float* coords = (const float*)d_in[1];
    const int*   rbi    = (const int*)d_in[2];
    const int*   etgt   = (const int*)d_in[3];
    const int*   esrc   = (const int*)d_in[4];
    const int*   tt     = (const int*)d_in[5];
    const float* W_dih  = (const float*)d_in[6];
    const float* b_dih  = (const float*)d_in[7];
    const float* Wq     = (const float*)d_in[8];
    const float* bq     = (const float*)d_in[9];
    const float* Wk     = (const float*)d_in[10];
    const float* bk     = (const float*)d_in[11];
    const float* Wv     = (const float*)d_in[12];
    const float* bv     = (const float*)d_in[13];
    const float* Wout   = (const float*)d_in[14];
    const float* bout   = (const float*)d_in[15];
    const float* Wt1    = (const float*)d_in[16];
    const float* bt1    = (const float*)d_in[17];
    const float* Wt2    = (const float*)d_in[18];
    const float* bt2    = (const float*)d_in[19];

    int N  = in_sizes[0] / D;
    int NB = in_sizes[2] / 2;
    int E  = in_sizes[3];

    char* ws = (char*)d_ws;
    size_t off = 0;
    auto alloc = [&](size_t bytes) -> char* {
        char* p = ws + off;
        off = (off + bytes + 255) & ~(size_t)255;
        return p;
    };
    float* ka     = (float*)alloc((size_t)N * D * 4);
    float* va     = (float*)alloc((size_t)N * D * 4);
    float* qv     = (float*)alloc((size_t)NB * D * 4);
    float* rbp    = (float*)alloc((size_t)NB * 3 * 4);
    float* tkg    = (float*)alloc((size_t)NB * 256 * 4);
    float* qbg    = (float*)alloc((size_t)NB * 8 * 4);
    float* maccb  = (float*)alloc((size_t)NB * D * 4);
    float* wdeg   = (float*)alloc((size_t)NB * 256 * 4);
    float* dnb    = (float*)alloc((size_t)NB * 8 * 4);
    int*   cnt2   = (int*)alloc((size_t)2 * NB * 4);
    int*   cnt    = cnt2;
    int*   cursor = cnt2 + NB;
    int*   offs   = (int*)alloc((size_t)(NB + 1) * 4);
    int*   ssrc   = (int*)alloc((size_t)E * 4);
    float* sdist  = (float*)alloc((size_t)E * 4);

    k_zero<<<(2 * NB + 255) / 256, 256, 0, stream>>>(cnt2, 2 * NB);
    k_atomproj<<<(N + 31) / 32, 256, 0, stream>>>(af, Wk, Wv, ka, va, N);
    k_bondfeats<<<(NB + 7) / 8, 128, 0, stream>>>(af, coords, rbi, tt, W_dih,
                                                  b_dih, Wq, bq, Wk, bk,
                                                  qv, rbp, tkg, qbg, NB);
    k_count<<<(E + 255) / 256, 256, 0, stream>>>(etgt, cnt, E);
    k_scan<<<1, 1024, 0, stream>>>(cnt, offs, NB);
    k_scatter<<<(E + 255) / 256, 256, 0, stream>>>(etgt, esrc, coords, rbp,
                                                   offs, cursor, ssrc, sdist, E);
    k_attn<<<(NB + 1) / 2, 64, 0, stream>>>(qv, tkg, qbg, ka, va, ssrc, sdist,
                                            offs, maccb, wdeg, dnb, NB);
    k_mlp<<<(NB + 7) / 8, 128, 0, stream>>>(maccb, wdeg, dnb, Wv, bv, Wout,
                                            bout, Wt1, bt1, Wt2, bt2,
                                            (float*)d_out, NB);
}

// Round 5
// 321.952 us; speedup vs baseline: 1.3098x; 1.1384x over previous
//
#include <hip/hip_runtime.h>
#include <math.h>

#define D 128
#define DDIM 32
#define NHEAD 8

typedef float4 f4;
typedef __attribute__((ext_vector_type(8))) short short8;
typedef __attribute__((ext_vector_type(4))) float f32x4;

__device__ __forceinline__ unsigned short bf16_rne(float x) {
    unsigned u = __float_as_uint(x);
    return (unsigned short)((u + 0x7fff + ((u >> 16) & 1)) >> 16);
}
__device__ __forceinline__ float bf16_to_f(unsigned short h) {
    return __uint_as_float(((unsigned)h) << 16);
}

__global__ void k_zero(int* __restrict__ p, int n) {
    int i = blockIdx.x * blockDim.x + threadIdx.x;
    if (i < n) p[i] = 0;
}

// Split Wk|Wv into transposed bf16 hi/lo: Wt[col][k], col 0-127 = Wk, 128-255 = Wv
__global__ void __launch_bounds__(256) k_wprep(
    const float* __restrict__ Wk, const float* __restrict__ Wv,
    unsigned short* __restrict__ Wth, unsigned short* __restrict__ Wtl) {
    int idx = blockIdx.x * 256 + threadIdx.x;    // 0..32767
    int col = idx >> 7, k = idx & 127;
    float w = (col < 128) ? Wk[k * 128 + col] : Wv[k * 128 + (col - 128)];
    unsigned short h = bf16_rne(w);
    float r = w - bf16_to_f(h);
    Wth[idx] = h;
    Wtl[idx] = bf16_rne(r);
}

// MFMA: [ka|va] = af @ [WkA|WvA], 3-pass bf16 hi/lo split (f32-grade accuracy)
__global__ void __launch_bounds__(256) k_atomproj(
    const float* __restrict__ af, const unsigned short* __restrict__ Wth,
    const unsigned short* __restrict__ Wtl, float* __restrict__ ka,
    float* __restrict__ va, int N) {
    __shared__ __align__(16) unsigned short Ahi[64 * 128];
    __shared__ __align__(16) unsigned short Alo[64 * 128];
    int t = threadIdx.x;
    int a0 = blockIdx.x * 64;
    const f4* af4 = (const f4*)af;
    // stage 64 rows x 128 k as bf16 hi/lo, XOR-swizzled within each 256B row
#pragma unroll
    for (int i = 0; i < 8; ++i) {
        int idx = t + 256 * i;           // 0..2047
        int row = idx >> 5, q4 = idx & 31;
        f4 v = make_float4(0.f, 0.f, 0.f, 0.f);
        if (a0 + row < N) v = af4[(size_t)(a0 + row) * 32 + q4];
        float xs[4] = {v.x, v.y, v.z, v.w};
        unsigned hp0, hp1, lp0, lp1;
        {
            unsigned short h0 = bf16_rne(xs[0]), h1 = bf16_rne(xs[1]);
            unsigned short h2 = bf16_rne(xs[2]), h3 = bf16_rne(xs[3]);
            unsigned short l0 = bf16_rne(xs[0] - bf16_to_f(h0));
            unsigned short l1 = bf16_rne(xs[1] - bf16_to_f(h1));
            unsigned short l2 = bf16_rne(xs[2] - bf16_to_f(h2));
            unsigned short l3 = bf16_rne(xs[3] - bf16_to_f(h3));
            hp0 = (unsigned)h0 | ((unsigned)h1 << 16);
            hp1 = (unsigned)h2 | ((unsigned)h3 << 16);
            lp0 = (unsigned)l0 | ((unsigned)l1 << 16);
            lp1 = (unsigned)l2 | ((unsigned)l3 << 16);
        }
        int byteoff = (q4 * 8) ^ ((row & 7) << 4);
        *(uint2*)((char*)Ahi + row * 256 + byteoff) = make_uint2(hp0, hp1);
        *(uint2*)((char*)Alo + row * 256 + byteoff) = make_uint2(lp0, lp1);
    }
    __syncthreads();

    int w = t >> 6;          // wave 0..3: waves 0-1 -> ka, 2-3 -> va
    int l = t & 63;
    int lr = l & 15;         // row-in-frag (A) / col (B, C)
    int lg = l >> 4;         // k-group
    float* outbase = (w < 2) ? ka : va;
    int colbase = (w & 1) * 64;

    f32x4 acc[4][4];
#pragma unroll
    for (int mf = 0; mf < 4; ++mf)
#pragma unroll
        for (int nf = 0; nf < 4; ++nf)
            acc[mf][nf] = (f32x4){0.f, 0.f, 0.f, 0.f};

    for (int ks = 0; ks < 4; ++ks) {
        short8 Bh[4], Bl[4];
#pragma unroll
        for (int nf = 0; nf < 4; ++nf) {
            size_t o = (size_t)(w * 64 + nf * 16 + lr) * 128 + ks * 32 + lg * 8;
            Bh[nf] = *(const short8*)(Wth + o);
            Bl[nf] = *(const short8*)(Wtl + o);
        }
#pragma unroll
        for (int mf = 0; mf < 4; ++mf) {
            int row = mf * 16 + lr;
            int kbyte = (ks * 64 + lg * 16) ^ ((row & 7) << 4);
            short8 Ah = *(const short8*)((const char*)Ahi + row * 256 + kbyte);
            short8 Al = *(const short8*)((const char*)Alo + row * 256 + kbyte);
#pragma unroll
            for (int nf = 0; nf < 4; ++nf) {
                acc[mf][nf] = __builtin_amdgcn_mfma_f32_16x16x32_bf16(Ah, Bh[nf], acc[mf][nf], 0, 0, 0);
                acc[mf][nf] = __builtin_amdgcn_mfma_f32_16x16x32_bf16(Al, Bh[nf], acc[mf][nf], 0, 0, 0);
                acc[mf][nf] = __builtin_amdgcn_mfma_f32_16x16x32_bf16(Ah, Bl[nf], acc[mf][nf], 0, 0, 0);
            }
        }
    }
    // C layout: col = lane&15, row = (lane>>4)*4 + reg
#pragma unroll
    for (int mf = 0; mf < 4; ++mf) {
        int atom0 = a0 + mf * 16 + lg * 4;
#pragma unroll
        for (int r = 0; r < 4; ++r) {
            int atom = atom0 + r;
            if (atom < N) {
#pragma unroll
                for (int nf = 0; nf < 4; ++nf)
                    outbase[(size_t)atom * 128 + colbase + nf * 16 + lr] = acc[mf][nf][r];
            }
        }
    }
}

// per-bond: rb_pos, rb_feats, q (scaled 0.25), tk = WkB.q, qb = q.bk
__global__ void __launch_bounds__(128) k_bondfeats(
    const float* __restrict__ af, const float* __restrict__ coords,
    const int* __restrict__ rbi, const int* __restrict__ tt,
    const float* __restrict__ W_dih, const float* __restrict__ b_dih,
    const float* __restrict__ Wq, const float* __restrict__ bq,
    const float* __restrict__ Wk, const float* __restrict__ bk,
    float* __restrict__ qv, float* __restrict__ rbp,
    float* __restrict__ tkg, float* __restrict__ qbg, int NB) {
    __shared__ __align__(16) float s1[8][D], s2[8][D], rf[8][D], qs[8][D];
    int b0 = blockIdx.x * 8;
    int c = threadIdx.x;
#pragma unroll
    for (int b = 0; b < 8; ++b) {
        int bi = b0 + b;
        if (bi < NB) {
            int i0 = tt[bi * 4 + 0], i1 = tt[bi * 4 + 1];
            int i2 = tt[bi * 4 + 2], i3 = tt[bi * 4 + 3];
            s1[b][c] = af[(size_t)i0 * D + c] + af[(size_t)i3 * D + c];
            s2[b][c] = af[(size_t)i1 * D + c] + af[(size_t)i2 * D + c];
        } else {
            s1[b][c] = 0.f; s2[b][c] = 0.f;
        }
    }
    if (c < 24) {
        int b = c / 3, x = c % 3;
        int bi = b0 + b;
        if (bi < NB) {
            int a0i = rbi[bi], a1i = rbi[NB + bi];
            rbp[bi * 3 + x] = 0.5f * (coords[a0i * 3 + x] + coords[a1i * 3 + x]);
        }
    }
    __syncthreads();
    float acc[8];
    float bd2 = 2.f * b_dih[c];
#pragma unroll
    for (int b = 0; b < 8; ++b) acc[b] = bd2;
    for (int dq = 0; dq < 32; ++dq) {
        float wa0 = W_dih[(4 * dq + 0) * D + c] + W_dih[(384 + 4 * dq + 0) * D + c];
        float wa1 = W_dih[(4 * dq + 1) * D + c] + W_dih[(384 + 4 * dq + 1) * D + c];
        float wa2 = W_dih[(4 * dq + 2) * D + c] + W_dih[(384 + 4 * dq + 2) * D + c];
        float wa3 = W_dih[(4 * dq + 3) * D + c] + W_dih[(384 + 4 * dq + 3) * D + c];
        float wb0 = W_dih[(128 + 4 * dq + 0) * D + c] + W_dih[(256 + 4 * dq + 0) * D + c];
        float wb1 = W_dih[(128 + 4 * dq + 1) * D + c] + W_dih[(256 + 4 * dq + 1) * D + c];
        float wb2 = W_dih[(128 + 4 * dq + 2) * D + c] + W_dih[(256 + 4 * dq + 2) * D + c];
        float wb3 = W_dih[(128 + 4 * dq + 3) * D + c] + W_dih[(256 + 4 * dq + 3) * D + c];
#pragma unroll
        for (int b = 0; b < 8; ++b) {
            f4 v1 = *(const f4*)&s1[b][4 * dq];
            f4 v2 = *(const f4*)&s2[b][4 * dq];
            acc[b] += v1.x * wa0 + v1.y * wa1 + v1.z * wa2 + v1.w * wa3
                    + v2.x * wb0 + v2.y * wb1 + v2.z * wb2 + v2.w * wb3;
        }
    }
#pragma unroll
    for (int b = 0; b < 8; ++b) rf[b][c] = acc[b];
    __syncthreads();
    float accq[8];
    float bqc = bq[c];
#pragma unroll
    for (int b = 0; b < 8; ++b) accq[b] = bqc;
    for (int dq = 0; dq < 32; ++dq) {
        float w0 = Wq[(4 * dq + 0) * D + c];
        float w1 = Wq[(4 * dq + 1) * D + c];
        float w2 = Wq[(4 * dq + 2) * D + c];
        float w3 = Wq[(4 * dq + 3) * D + c];
#pragma unroll
        for (int b = 0; b < 8; ++b) {
            f4 v = *(const f4*)&rf[b][4 * dq];
            accq[b] += v.x * w0 + v.y * w1 + v.z * w2 + v.w * w3;
        }
    }
#pragma unroll
    for (int b = 0; b < 8; ++b) {
        float qq = accq[b] * 0.25f;     // fold 1/sqrt(HEAD_DIM)
        qs[b][c] = qq;
        int bi = b0 + b;
        if (bi < NB) qv[(size_t)bi * D + c] = qq;
    }
    __syncthreads();
    // tk[b][h][d] = sum_cc WkB[d][h*16+cc] * q[b][h*16+cc]
    int h = c >> 4;
    int dx = (c & 15) * 2;
    float w0[16], w1[16];
#pragma unroll
    for (int cc = 0; cc < 16; ++cc) {
        w0[cc] = Wk[(128 + dx) * D + h * 16 + cc];
        w1[cc] = Wk[(129 + dx) * D + h * 16 + cc];
    }
#pragma unroll
    for (int b = 0; b < 8; ++b) {
        float t0 = 0.f, t1 = 0.f;
#pragma unroll
        for (int k = 0; k < 4; ++k) {
            f4 qq = *(const f4*)&qs[b][h * 16 + 4 * k];
            t0 += w0[4 * k] * qq.x + w0[4 * k + 1] * qq.y + w0[4 * k + 2] * qq.z + w0[4 * k + 3] * qq.w;
            t1 += w1[4 * k] * qq.x + w1[4 * k + 1] * qq.y + w1[4 * k + 2] * qq.z + w1[4 * k + 3] * qq.w;
        }
        int bi = b0 + b;
        if (bi < NB) {
            tkg[(size_t)bi * 256 + h * 32 + dx]     = t0;
            tkg[(size_t)bi * 256 + h * 32 + dx + 1] = t1;
        }
    }
    float bkv = bk[h * 16 + (c & 15)];
#pragma unroll
    for (int b = 0; b < 8; ++b) {
        float p = qs[b][h * 16 + (c & 15)] * bkv;
        p += __shfl_xor(p, 1);
        p += __shfl_xor(p, 2);
        p += __shfl_xor(p, 4);
        p += __shfl_xor(p, 8);
        int bi = b0 + b;
        if ((c & 15) == 0 && bi < NB) qbg[bi * 8 + h] = p;
    }
}

__global__ void k_count(const int* __restrict__ etgt, int* __restrict__ cnt, int E) {
    int e = blockIdx.x * blockDim.x + threadIdx.x;
    if (e < E) atomicAdd(&cnt[etgt[e]], 1);
}

__global__ void __launch_bounds__(1024) k_scan(const int* __restrict__ cnt,
                                               int* __restrict__ offs, int NB) {
    __shared__ int part[1024];
    int t = threadIdx.x;
    int CH = (NB + 1023) >> 10;
    int base = t * CH;
    int s = 0;
    for (int i = 0; i < CH; ++i) {
        int idx = base + i;
        if (idx < NB) s += cnt[idx];
    }
    part[t] = s;
    __syncthreads();
    for (int off = 1; off < 1024; off <<= 1) {
        int v = (t >= off) ? part[t - off] : 0;
        __syncthreads();
        part[t] += v;
        __syncthreads();
    }
    int run = part[t] - s;
    for (int i = 0; i < CH; ++i) {
        int idx = base + i;
        if (idx < NB) {
            offs[idx] = run;
            run += cnt[idx];
        }
    }
    if (t == 1023) offs[NB] = part[1023];
}

__global__ void k_scatter(const int* __restrict__ etgt, const int* __restrict__ esrc,
                          const float* __restrict__ coords, const float* __restrict__ rbp,
                          const int* __restrict__ offs, int* __restrict__ cursor,
                          int* __restrict__ ssrc, float* __restrict__ sdist, int E) {
    int e = blockIdx.x * blockDim.x + threadIdx.x;
    if (e < E) {
        int t = etgt[e];
        int pos = atomicAdd(&cursor[t], 1);
        int idx = offs[t] + pos;
        int src = esrc[e];
        ssrc[idx] = src;
        float dx = coords[src * 3 + 0] - rbp[t * 3 + 0];
        float dy = coords[src * 3 + 1] - rbp[t * 3 + 1];
        float dz = coords[src * 3 + 2] - rbp[t * 3 + 2];
        sdist[idx] = sqrtf(dx * dx + dy * dy + dz * dz);
    }
}

// one wave per 2 bonds; writes macc = sum w*va[src] (per-channel head weight),
// wde[8][32], dn[8]; WvB/bv projection deferred to k_mlp
__global__ void __launch_bounds__(64) k_attn(
    const float* __restrict__ qv, const float* __restrict__ tkg,
    const float* __restrict__ qbg, const float* __restrict__ ka,
    const float* __restrict__ va, const int* __restrict__ ssrc,
    const float* __restrict__ sdist, const int* __restrict__ offs,
    float* __restrict__ macc, float* __restrict__ wdeg,
    float* __restrict__ dnb, int NB) {
    __shared__ __align__(16) float q_s[2][128];
    __shared__ __align__(16) float tk_s[2][256];
    __shared__ float qb_s[2][8];
    __shared__ int   src_s[2][32];
    __shared__ __align__(16) float de_s[2][32 * 36];
    __shared__ float w_s[2][32 * 9];

    int l = threadIdx.x;
    int half = l >> 5;
    int j = l & 31;
    int bb = blockIdx.x * 2 + half;
    bool vb = bb < NB;

    if (vb) {
#pragma unroll
        for (int i = 0; i < 4; ++i)
            q_s[half][j + 32 * i] = qv[(size_t)bb * D + j + 32 * i];
#pragma unroll
        for (int i = 0; i < 8; ++i)
            tk_s[half][j + 32 * i] = tkg[(size_t)bb * 256 + j + 32 * i];
        if (j < 8) qb_s[half][j] = qbg[bb * 8 + j];
    }
    int base = 0, ne = 0;
    if (vb) { base = offs[bb]; ne = offs[bb + 1] - base; }
    int mych = (ne + 31) >> 5;
    int och = __shfl_xor(mych, 32);
    int nch = mych > och ? mych : och;
    __syncthreads();

    const float step = 5.0f / 31.0f;
    const float coeff = -0.5f / (step * step);

    float dnp[8];
#pragma unroll
    for (int h = 0; h < 8; ++h) dnp[h] = 0.f;
    f4 acc = make_float4(0.f, 0.f, 0.f, 0.f);
    f4 wa  = make_float4(0.f, 0.f, 0.f, 0.f);
    f4 wb  = make_float4(0.f, 0.f, 0.f, 0.f);

    const f4* ka4 = (const f4*)ka;
    const f4* va4 = (const f4*)va;
    const f4* q4  = (const f4*)&q_s[half][0];
    const f4* tk4 = (const f4*)&tk_s[half][0];
    const f4* de4 = (const f4*)&de_s[half][0];
    int h4 = j >> 2;
    int dq = 2 * (j & 3);

    for (int cb = 0; cb < nch; ++cb) {
        int ebase = cb * 32;
        int nec = ne - ebase;
        nec = nec < 0 ? 0 : (nec > 32 ? 32 : nec);
        // ---- phase A: edge-parallel scores ----
        if (j < nec) {
            int eg = base + ebase + j;
            int src = ssrc[eg];
            float dist = sdist[eg];
            src_s[half][j] = src;
            float de[32];
#pragma unroll
            for (int d = 0; d < 32; ++d) {
                float t = dist - step * (float)d;
                de[d] = __expf(coeff * t * t);
            }
            f4* dw = (f4*)&de_s[half][j * 36];
#pragma unroll
            for (int k = 0; k < 8; ++k)
                dw[k] = make_float4(de[4 * k], de[4 * k + 1], de[4 * k + 2], de[4 * k + 3]);
            float sc[8];
#pragma unroll
            for (int h = 0; h < 8; ++h) sc[h] = qb_s[half][h];
            const f4* kap = ka4 + (size_t)src * 32;
#pragma unroll
            for (int i = 0; i < 32; ++i) {
                f4 kv = kap[i];
                f4 qq = q4[i];
                sc[i >> 2] += qq.x * kv.x + qq.y * kv.y + qq.z * kv.z + qq.w * kv.w;
            }
#pragma unroll
            for (int h = 0; h < 8; ++h) {
                float s = 0.f;
#pragma unroll
                for (int k = 0; k < 8; ++k) {
                    f4 tkv = tk4[h * 8 + k];
                    s += de[4 * k] * tkv.x + de[4 * k + 1] * tkv.y
                       + de[4 * k + 2] * tkv.z + de[4 * k + 3] * tkv.w;
                }
                float wv_ = __expf(sc[h] + s);
                dnp[h] += wv_;
                w_s[half][j * 9 + h] = wv_;
            }
        }
        __syncthreads();
        // ---- phase B: channel-parallel accumulation (va gather) ----
        for (int e = 0; e < nec; ++e) {
            int srcE = src_s[half][e];
            float ww = w_s[half][e * 9 + h4];
            f4 vv = va4[(size_t)srcE * 32 + j];
            acc.x += ww * vv.x; acc.y += ww * vv.y;
            acc.z += ww * vv.z; acc.w += ww * vv.w;
            f4 dA = de4[e * 9 + dq];
            f4 dB = de4[e * 9 + dq + 1];
            wa.x += ww * dA.x; wa.y += ww * dA.y; wa.z += ww * dA.z; wa.w += ww * dA.w;
            wb.x += ww * dB.x; wb.y += ww * dB.y; wb.z += ww * dB.z; wb.w += ww * dB.w;
        }
        __syncthreads();
    }
#pragma unroll
    for (int h = 0; h < 8; ++h) {
        float v = dnp[h];
        v += __shfl_xor(v, 1);
        v += __shfl_xor(v, 2);
        v += __shfl_xor(v, 4);
        v += __shfl_xor(v, 8);
        v += __shfl_xor(v, 16);
        dnp[h] = v;
    }
    if (vb) {
        ((f4*)macc)[(size_t)bb * 32 + j] = acc;
        f4* wp = (f4*)&wdeg[(size_t)bb * 256 + h4 * 32 + 8 * (j & 3)];
        wp[0] = wa;
        wp[1] = wb;
        if (j < 8) dnb[bb * 8 + j] = dnp[j];
    }
}

__device__ __forceinline__ float gelu_exact(float x) {
    return 0.5f * x * (1.0f + erff(x * 0.70710678118654752f));
}

// v_in = (macc + wde@WvB + dn*bv)/dn -> Wout -> gelu(Wt1) -> Wt2
__global__ void __launch_bounds__(128) k_mlp(
    const float* __restrict__ macc, const float* __restrict__ wdeg,
    const float* __restrict__ dnb, const float* __restrict__ Wv,
    const float* __restrict__ bv, const float* __restrict__ Wout,
    const float* __restrict__ bout, const float* __restrict__ Wt1,
    const float* __restrict__ bt1, const float* __restrict__ Wt2,
    const float* __restrict__ bt2, float* __restrict__ y, int NB) {
    __shared__ __align__(16) float s[8][D], x1[8][D], wdl[8][256];
    __shared__ float dnl[8][8];
    int b0 = blockIdx.x * 8;
    int c = threadIdx.x;
#pragma unroll
    for (int b = 0; b < 8; ++b) {
        int bi = b0 + b;
        s[b][c] = (bi < NB) ? macc[(size_t)bi * D + c] : 0.f;
    }
#pragma unroll
    for (int i = 0; i < 16; ++i) {
        int idx = c + 128 * i;
        int b = idx >> 8, r = idx & 255;
        wdl[b][r] = (b0 + b < NB) ? wdeg[(size_t)(b0 + b) * 256 + r] : 0.f;
    }
    if (c < 64) {
        int b = c >> 3, h = c & 7;
        dnl[b][h] = (b0 + b < NB) ? dnb[(b0 + b) * 8 + h] : 0.f;
    }
    __syncthreads();
    int hh = c >> 4;
    float acc[8];
#pragma unroll
    for (int b = 0; b < 8; ++b) acc[b] = 0.f;
    for (int tq = 0; tq < 8; ++tq) {
        float w0 = Wv[(128 + 4 * tq + 0) * D + c];
        float w1 = Wv[(128 + 4 * tq + 1) * D + c];
        float w2 = Wv[(128 + 4 * tq + 2) * D + c];
        float w3 = Wv[(128 + 4 * tq + 3) * D + c];
#pragma unroll
        for (int b = 0; b < 8; ++b) {
            f4 v = *(const f4*)&wdl[b][hh * 32 + 4 * tq];
            acc[b] += v.x * w0 + v.y * w1 + v.z * w2 + v.w * w3;
        }
    }
    float bvc = bv[c];
#pragma unroll
    for (int b = 0; b < 8; ++b) {
        float dn = dnl[b][hh];
        float inv = 1.0f / (dn + 1e-16f);
        x1[b][c] = (s[b][c] + acc[b] + bvc * dn) * inv;   // v_in
    }
    __syncthreads();
    float bo = bout[c];
#pragma unroll
    for (int b = 0; b < 8; ++b) acc[b] = bo;
    for (int dq = 0; dq < 32; ++dq) {
        float w0 = Wout[(4 * dq + 0) * D + c];
        float w1 = Wout[(4 * dq + 1) * D + c];
        float w2 = Wout[(4 * dq + 2) * D + c];
        float w3 = Wout[(4 * dq + 3) * D + c];
#pragma unroll
        for (int b = 0; b < 8; ++b) {
            f4 v = *(const f4*)&x1[b][4 * dq];
            acc[b] += v.x * w0 + v.y * w1 + v.z * w2 + v.w * w3;
        }
    }
    __syncthreads();
#pragma unroll
    for (int b = 0; b < 8; ++b) s[b][c] = acc[b];
    __syncthreads();
    float bt = bt1[c];
#pragma unroll
    for (int b = 0; b < 8; ++b) acc[b] = bt;
    for (int dq = 0; dq < 32; ++dq) {
        float w0 = Wt1[(4 * dq + 0) * D + c];
        float w1 = Wt1[(4 * dq + 1) * D + c];
        float w2 = Wt1[(4 * dq + 2) * D + c];
        float w3 = Wt1[(4 * dq + 3) * D + c];
#pragma unroll
        for (int b = 0; b < 8; ++b) {
            f4 v = *(const f4*)&s[b][4 * dq];
            acc[b] += v.x * w0 + v.y * w1 + v.z * w2 + v.w * w3;
        }
    }
    __syncthreads();
#pragma unroll
    for (int b = 0; b < 8; ++b) x1[b][c] = gelu_exact(acc[b]);
    __syncthreads();
    int b2 = c >> 4;
    int l16 = c & 15;
    float p0 = 0.f, p1 = 0.f;
#pragma unroll
    for (int k = 0; k < 8; ++k) {
        int d = l16 + 16 * k;
        float hv = x1[b2][d];
        p0 += hv * Wt2[d * 2 + 0];
        p1 += hv * Wt2[d * 2 + 1];
    }
    p0 += __shfl_xor(p0, 1); p1 += __shfl_xor(p1, 1);
    p0 += __shfl_xor(p0, 2); p1 += __shfl_xor(p1, 2);
    p0 += __shfl_xor(p0, 4); p1 += __shfl_xor(p1, 4);
    p0 += __shfl_xor(p0, 8); p1 += __shfl_xor(p1, 8);
    int bi = b0 + b2;
    if (l16 == 0 && bi < NB) {
        y[bi * 2 + 0] = p0 + bt2[0];
        y[bi * 2 + 1] = p1 + bt2[1];
    }
}

extern "C" void kernel_launch(void* const* d_in, const int* in_sizes, int n_in,
                              void* d_out, int out_size, void* d_ws, size_t ws_size,
                              hipStream_t stream) {
    const float* af     = (const float*)d_in[0];
    const float* coords = (const float*)d_in[1];
    const int*   rbi    = (const int*)d_in[2];
    const int*   etgt   = (const int*)d_in[3];
    const int*   esrc   = (const int*)d_in[4];
    const int*   tt     = (const int*)d_in[5];
    const float* W_dih  = (const float*)d_in[6];
    const float* b_dih  = (const float*)d_in[7];
    const float* Wq     = (const float*)d_in[8];
    const float* bq     = (const float*)d_in[9];
    const float* Wk     = (const float*)d_in[10];
    const float* bk     = (const float*)d_in[11];
    const float* Wv     = (const float*)d_in[12];
    const float* bv     = (const float*)d_in[13];
    const float* Wout   = (const float*)d_in[14];
    const float* bout   = (const float*)d_in[15];
    const float* Wt1    = (const float*)d_in[16];
    const float* bt1    = (const float*)d_in[17];
    const float* Wt2    = (const float*)d_in[18];
    const float* bt2    = (const float*)d_in[19];

    int N  = in_sizes[0] / D;
    int NB = in_sizes[2] / 2;
    int E  = in_sizes[3];

    char* ws = (char*)d_ws;
    size_t off = 0;
    auto alloc = [&](size_t bytes) -> char* {
        char* p = ws + off;
        off = (off + bytes + 255) & ~(size_t)255;
        return p;
    };
    float* ka     = (float*)alloc((size_t)N * D * 4);
    float* va     = (float*)alloc((size_t)N * D * 4);
    float* qv     = (float*)alloc((size_t)NB * D * 4);
    float* rbp    = (float*)alloc((size_t)NB * 3 * 4);
    float* tkg    = (float*)alloc((size_t)NB * 256 * 4);
    float* qbg    = (float*)alloc((size_t)NB * 8 * 4);
    float* maccb  = (float*)alloc((size_t)NB * D * 4);
    float* wdeg   = (float*)alloc((size_t)NB * 256 * 4);
    float* dnb    = (float*)alloc((size_t)NB * 8 * 4);
    int*   cnt2   = (int*)alloc((size_t)2 * NB * 4);
    int*   cnt    = cnt2;
    int*   cursor = cnt2 + NB;
    int*   offs   = (int*)alloc((size_t)(NB + 1) * 4);
    int*   ssrc   = (int*)alloc((size_t)E * 4);
    float* sdist  = (float*)alloc((size_t)E * 4);
    unsigned short* Wth = (unsigned short*)alloc((size_t)256 * 128 * 2);
    unsigned short* Wtl = (unsigned short*)alloc((size_t)256 * 128 * 2);

    k_zero<<<(2 * NB + 255) / 256, 256, 0, stream>>>(cnt2, 2 * NB);
    k_wprep<<<128, 256, 0, stream>>>(Wk, Wv, Wth, Wtl);
    k_atomproj<<<(N + 63) / 64, 256, 0, stream>>>(af, Wth, Wtl, ka, va, N);
    k_bondfeats<<<(NB + 7) / 8, 128, 0, stream>>>(af, coords, rbi, tt, W_dih,
                                                  b_dih, Wq, bq, Wk, bk,
                                                  qv, rbp, tkg, qbg, NB);
    k_count<<<(E + 255) / 256, 256, 0, stream>>>(etgt, cnt, E);
    k_scan<<<1, 1024, 0, stream>>>(cnt, offs, NB);
    k_scatter<<<(E + 255) / 256, 256, 0, stream>>>(etgt, esrc, coords, rbp,
                                                   offs, cursor, ssrc, sdist, E);
    k_attn<<<(NB + 1) / 2, 64, 0, stream>>>(qv, tkg, qbg, ka, va, ssrc, sdist,
                                            offs, maccb, wdeg, dnb, NB);
    k_mlp<<<(NB + 7) / 8, 128, 0, stream>>>(maccb, wdeg, dnb, Wv, bv, Wout,
                                            bout, Wt1, bt1, Wt2, bt2,
                                            (float*)d_out, NB);
}

// Round 6
// 301.221 us; speedup vs baseline: 1.4000x; 1.0688x over previous
//
#include <hip/hip_runtime.h>
#include <math.h>

#define D 128
#define DDIM 32
#define NHEAD 8

typedef float4 f4;
typedef __attribute__((ext_vector_type(8))) short short8;
typedef __attribute__((ext_vector_type(4))) float f32x4;
typedef _Float16 h2v __attribute__((ext_vector_type(2)));
typedef _Float16 h4v __attribute__((ext_vector_type(4)));
typedef _Float16 h8v __attribute__((ext_vector_type(8)));

#if defined(__has_builtin)
#if __has_builtin(__builtin_amdgcn_fdot2)
#define HAVE_FDOT2 1
#endif
#endif

__device__ __forceinline__ float fdot2_acc(h2v a, h2v b, float c) {
#ifdef HAVE_FDOT2
    return __builtin_amdgcn_fdot2(a, b, c, false);
#else
    return c + (float)a[0] * (float)b[0] + (float)a[1] * (float)b[1];
#endif
}

__device__ __forceinline__ unsigned short bf16_rne(float x) {
    unsigned u = __float_as_uint(x);
    return (unsigned short)((u + 0x7fff + ((u >> 16) & 1)) >> 16);
}
__device__ __forceinline__ float bf16_to_f(unsigned short h) {
    return __uint_as_float(((unsigned)h) << 16);
}

__global__ void k_zero(int* __restrict__ p, int n) {
    int i = blockIdx.x * blockDim.x + threadIdx.x;
    if (i < n) p[i] = 0;
}

// Split Wk|Wv into transposed bf16 hi/lo: Wt[col][k], col 0-127 = Wk, 128-255 = Wv
__global__ void __launch_bounds__(256) k_wprep(
    const float* __restrict__ Wk, const float* __restrict__ Wv,
    unsigned short* __restrict__ Wth, unsigned short* __restrict__ Wtl) {
    int idx = blockIdx.x * 256 + threadIdx.x;    // 0..32767
    int col = idx >> 7, k = idx & 127;
    float w = (col < 128) ? Wk[k * 128 + col] : Wv[k * 128 + (col - 128)];
    unsigned short h = bf16_rne(w);
    float r = w - bf16_to_f(h);
    Wth[idx] = h;
    Wtl[idx] = bf16_rne(r);
}

// MFMA: [ka|va] = af @ [WkA|WvA], 3-pass bf16 hi/lo split; fp16 output
__global__ void __launch_bounds__(256) k_atomproj(
    const float* __restrict__ af, const unsigned short* __restrict__ Wth,
    const unsigned short* __restrict__ Wtl, _Float16* __restrict__ ka,
    _Float16* __restrict__ va, int N) {
    __shared__ __align__(16) unsigned short Ahi[64 * 128];
    __shared__ __align__(16) unsigned short Alo[64 * 128];
    int t = threadIdx.x;
    int a0 = blockIdx.x * 64;
    const f4* af4 = (const f4*)af;
#pragma unroll
    for (int i = 0; i < 8; ++i) {
        int idx = t + 256 * i;           // 0..2047
        int row = idx >> 5, q4 = idx & 31;
        f4 v = make_float4(0.f, 0.f, 0.f, 0.f);
        if (a0 + row < N) v = af4[(size_t)(a0 + row) * 32 + q4];
        float xs[4] = {v.x, v.y, v.z, v.w};
        unsigned hp0, hp1, lp0, lp1;
        {
            unsigned short h0 = bf16_rne(xs[0]), h1 = bf16_rne(xs[1]);
            unsigned short h2 = bf16_rne(xs[2]), h3 = bf16_rne(xs[3]);
            unsigned short l0 = bf16_rne(xs[0] - bf16_to_f(h0));
            unsigned short l1 = bf16_rne(xs[1] - bf16_to_f(h1));
            unsigned short l2 = bf16_rne(xs[2] - bf16_to_f(h2));
            unsigned short l3 = bf16_rne(xs[3] - bf16_to_f(h3));
            hp0 = (unsigned)h0 | ((unsigned)h1 << 16);
            hp1 = (unsigned)h2 | ((unsigned)h3 << 16);
            lp0 = (unsigned)l0 | ((unsigned)l1 << 16);
            lp1 = (unsigned)l2 | ((unsigned)l3 << 16);
        }
        int byteoff = (q4 * 8) ^ ((row & 7) << 4);
        *(uint2*)((char*)Ahi + row * 256 + byteoff) = make_uint2(hp0, hp1);
        *(uint2*)((char*)Alo + row * 256 + byteoff) = make_uint2(lp0, lp1);
    }
    __syncthreads();

    int w = t >> 6;          // wave 0..3: waves 0-1 -> ka, 2-3 -> va
    int l = t & 63;
    int lr = l & 15;
    int lg = l >> 4;
    _Float16* outbase = (w < 2) ? ka : va;
    int colbase = (w & 1) * 64;

    f32x4 acc[4][4];
#pragma unroll
    for (int mf = 0; mf < 4; ++mf)
#pragma unroll
        for (int nf = 0; nf < 4; ++nf)
            acc[mf][nf] = (f32x4){0.f, 0.f, 0.f, 0.f};

    for (int ks = 0; ks < 4; ++ks) {
        short8 Bh[4], Bl[4];
#pragma unroll
        for (int nf = 0; nf < 4; ++nf) {
            size_t o = (size_t)(w * 64 + nf * 16 + lr) * 128 + ks * 32 + lg * 8;
            Bh[nf] = *(const short8*)(Wth + o);
            Bl[nf] = *(const short8*)(Wtl + o);
        }
#pragma unroll
        for (int mf = 0; mf < 4; ++mf) {
            int row = mf * 16 + lr;
            int kbyte = (ks * 64 + lg * 16) ^ ((row & 7) << 4);
            short8 Ah = *(const short8*)((const char*)Ahi + row * 256 + kbyte);
            short8 Al = *(const short8*)((const char*)Alo + row * 256 + kbyte);
#pragma unroll
            for (int nf = 0; nf < 4; ++nf) {
                acc[mf][nf] = __builtin_amdgcn_mfma_f32_16x16x32_bf16(Ah, Bh[nf], acc[mf][nf], 0, 0, 0);
                acc[mf][nf] = __builtin_amdgcn_mfma_f32_16x16x32_bf16(Al, Bh[nf], acc[mf][nf], 0, 0, 0);
                acc[mf][nf] = __builtin_amdgcn_mfma_f32_16x16x32_bf16(Ah, Bl[nf], acc[mf][nf], 0, 0, 0);
            }
        }
    }
#pragma unroll
    for (int mf = 0; mf < 4; ++mf) {
        int atom0 = a0 + mf * 16 + lg * 4;
#pragma unroll
        for (int r = 0; r < 4; ++r) {
            int atom = atom0 + r;
            if (atom < N) {
#pragma unroll
                for (int nf = 0; nf < 4; ++nf)
                    outbase[(size_t)atom * 128 + colbase + nf * 16 + lr] = (_Float16)acc[mf][nf][r];
            }
        }
    }
}

// per-bond: rb_pos, rb_feats, q (scaled 0.25), tk = WkB.q, qb = q.bk
__global__ void __launch_bounds__(128) k_bondfeats(
    const float* __restrict__ af, const float* __restrict__ coords,
    const int* __restrict__ rbi, const int* __restrict__ tt,
    const float* __restrict__ W_dih, const float* __restrict__ b_dih,
    const float* __restrict__ Wq, const float* __restrict__ bq,
    const float* __restrict__ Wk, const float* __restrict__ bk,
    float* __restrict__ qv, float* __restrict__ rbp,
    float* __restrict__ tkg, float* __restrict__ qbg, int NB) {
    __shared__ __align__(16) float s1[8][D], s2[8][D], rf[8][D], qs[8][D];
    int b0 = blockIdx.x * 8;
    int c = threadIdx.x;
#pragma unroll
    for (int b = 0; b < 8; ++b) {
        int bi = b0 + b;
        if (bi < NB) {
            int i0 = tt[bi * 4 + 0], i1 = tt[bi * 4 + 1];
            int i2 = tt[bi * 4 + 2], i3 = tt[bi * 4 + 3];
            s1[b][c] = af[(size_t)i0 * D + c] + af[(size_t)i3 * D + c];
            s2[b][c] = af[(size_t)i1 * D + c] + af[(size_t)i2 * D + c];
        } else {
            s1[b][c] = 0.f; s2[b][c] = 0.f;
        }
    }
    if (c < 24) {
        int b = c / 3, x = c % 3;
        int bi = b0 + b;
        if (bi < NB) {
            int a0i = rbi[bi], a1i = rbi[NB + bi];
            rbp[bi * 3 + x] = 0.5f * (coords[a0i * 3 + x] + coords[a1i * 3 + x]);
        }
    }
    __syncthreads();
    float acc[8];
    float bd2 = 2.f * b_dih[c];
#pragma unroll
    for (int b = 0; b < 8; ++b) acc[b] = bd2;
    for (int dq = 0; dq < 32; ++dq) {
        float wa0 = W_dih[(4 * dq + 0) * D + c] + W_dih[(384 + 4 * dq + 0) * D + c];
        float wa1 = W_dih[(4 * dq + 1) * D + c] + W_dih[(384 + 4 * dq + 1) * D + c];
        float wa2 = W_dih[(4 * dq + 2) * D + c] + W_dih[(384 + 4 * dq + 2) * D + c];
        float wa3 = W_dih[(4 * dq + 3) * D + c] + W_dih[(384 + 4 * dq + 3) * D + c];
        float wb0 = W_dih[(128 + 4 * dq + 0) * D + c] + W_dih[(256 + 4 * dq + 0) * D + c];
        float wb1 = W_dih[(128 + 4 * dq + 1) * D + c] + W_dih[(256 + 4 * dq + 1) * D + c];
        float wb2 = W_dih[(128 + 4 * dq + 2) * D + c] + W_dih[(256 + 4 * dq + 2) * D + c];
        float wb3 = W_dih[(128 + 4 * dq + 3) * D + c] + W_dih[(256 + 4 * dq + 3) * D + c];
#pragma unroll
        for (int b = 0; b < 8; ++b) {
            f4 v1 = *(const f4*)&s1[b][4 * dq];
            f4 v2 = *(const f4*)&s2[b][4 * dq];
            acc[b] += v1.x * wa0 + v1.y * wa1 + v1.z * wa2 + v1.w * wa3
                    + v2.x * wb0 + v2.y * wb1 + v2.z * wb2 + v2.w * wb3;
        }
    }
#pragma unroll
    for (int b = 0; b < 8; ++b) rf[b][c] = acc[b];
    __syncthreads();
    float accq[8];
    float bqc = bq[c];
#pragma unroll
    for (int b = 0; b < 8; ++b) accq[b] = bqc;
    for (int dq = 0; dq < 32; ++dq) {
        float w0 = Wq[(4 * dq + 0) * D + c];
        float w1 = Wq[(4 * dq + 1) * D + c];
        float w2 = Wq[(4 * dq + 2) * D + c];
        float w3 = Wq[(4 * dq + 3) * D + c];
#pragma unroll
        for (int b = 0; b < 8; ++b) {
            f4 v = *(const f4*)&rf[b][4 * dq];
            accq[b] += v.x * w0 + v.y * w1 + v.z * w2 + v.w * w3;
        }
    }
#pragma unroll
    for (int b = 0; b < 8; ++b) {
        float qq = accq[b] * 0.25f;     // fold 1/sqrt(HEAD_DIM)
        qs[b][c] = qq;
        int bi = b0 + b;
        if (bi < NB) qv[(size_t)bi * D + c] = qq;
    }
    __syncthreads();
    int h = c >> 4;
    int dx = (c & 15) * 2;
    float w0[16], w1[16];
#pragma unroll
    for (int cc = 0; cc < 16; ++cc) {
        w0[cc] = Wk[(128 + dx) * D + h * 16 + cc];
        w1[cc] = Wk[(129 + dx) * D + h * 16 + cc];
    }
#pragma unroll
    for (int b = 0; b < 8; ++b) {
        float t0 = 0.f, t1 = 0.f;
#pragma unroll
        for (int k = 0; k < 4; ++k) {
            f4 qq = *(const f4*)&qs[b][h * 16 + 4 * k];
            t0 += w0[4 * k] * qq.x + w0[4 * k + 1] * qq.y + w0[4 * k + 2] * qq.z + w0[4 * k + 3] * qq.w;
            t1 += w1[4 * k] * qq.x + w1[4 * k + 1] * qq.y + w1[4 * k + 2] * qq.z + w1[4 * k + 3] * qq.w;
        }
        int bi = b0 + b;
        if (bi < NB) {
            tkg[(size_t)bi * 256 + h * 32 + dx]     = t0;
            tkg[(size_t)bi * 256 + h * 32 + dx + 1] = t1;
        }
    }
    float bkv = bk[h * 16 + (c & 15)];
#pragma unroll
    for (int b = 0; b < 8; ++b) {
        float p = qs[b][h * 16 + (c & 15)] * bkv;
        p += __shfl_xor(p, 1);
        p += __shfl_xor(p, 2);
        p += __shfl_xor(p, 4);
        p += __shfl_xor(p, 8);
        int bi = b0 + b;
        if ((c & 15) == 0 && bi < NB) qbg[bi * 8 + h] = p;
    }
}

__global__ void k_count(const int* __restrict__ etgt, int* __restrict__ cnt, int E) {
    int e = blockIdx.x * blockDim.x + threadIdx.x;
    if (e < E) atomicAdd(&cnt[etgt[e]], 1);
}

__global__ void __launch_bounds__(1024) k_scan(const int* __restrict__ cnt,
                                               int* __restrict__ offs, int NB) {
    __shared__ int part[1024];
    int t = threadIdx.x;
    int CH = (NB + 1023) >> 10;
    int base = t * CH;
    int s = 0;
    for (int i = 0; i < CH; ++i) {
        int idx = base + i;
        if (idx < NB) s += cnt[idx];
    }
    part[t] = s;
    __syncthreads();
    for (int off = 1; off < 1024; off <<= 1) {
        int v = (t >= off) ? part[t - off] : 0;
        __syncthreads();
        part[t] += v;
        __syncthreads();
    }
    int run = part[t] - s;
    for (int i = 0; i < CH; ++i) {
        int idx = base + i;
        if (idx < NB) {
            offs[idx] = run;
            run += cnt[idx];
        }
    }
    if (t == 1023) offs[NB] = part[1023];
}

__global__ void k_scatter(const int* __restrict__ etgt, const int* __restrict__ esrc,
                          const float* __restrict__ coords, const float* __restrict__ rbp,
                          const int* __restrict__ offs, int* __restrict__ cursor,
                          int* __restrict__ ssrc, float* __restrict__ sdist, int E) {
    int e = blockIdx.x * blockDim.x + threadIdx.x;
    if (e < E) {
        int t = etgt[e];
        int pos = atomicAdd(&cursor[t], 1);
        int idx = offs[t] + pos;
        int src = esrc[e];
        ssrc[idx] = src;
        float dx = coords[src * 3 + 0] - rbp[t * 3 + 0];
        float dy = coords[src * 3 + 1] - rbp[t * 3 + 1];
        float dz = coords[src * 3 + 2] - rbp[t * 3 + 2];
        sdist[idx] = sqrtf(dx * dx + dy * dy + dz * dz);
    }
}

// one wave per 2 bonds; fp16 K/V + fdot2 scores; writes macc/wde/dn (V-proj B deferred)
__global__ void __launch_bounds__(64) k_attn(
    const float* __restrict__ qv, const float* __restrict__ tkg,
    const float* __restrict__ qbg, const _Float16* __restrict__ ka,
    const _Float16* __restrict__ va, const int* __restrict__ ssrc,
    const float* __restrict__ sdist, const int* __restrict__ offs,
    float* __restrict__ macc, float* __restrict__ wdeg,
    float* __restrict__ dnb, int NB) {
    __shared__ __align__(16) _Float16 qh[2][128];      // 512B
    __shared__ __align__(16) _Float16 tkh[2][256];     // 1KB
    __shared__ float qb_s[2][8];
    __shared__ int   src_s[2][32];
    __shared__ __align__(16) _Float16 de_s[2][32 * 40]; // 5.1KB (80B row stride)
    __shared__ float w_s[2][32 * 9];                    // 2.3KB

    int l = threadIdx.x;
    int half = l >> 5;
    int j = l & 31;
    int bb = blockIdx.x * 2 + half;
    bool vb = bb < NB;

    if (vb) {
#pragma unroll
        for (int i = 0; i < 4; ++i)
            qh[half][j + 32 * i] = (_Float16)qv[(size_t)bb * D + j + 32 * i];
#pragma unroll
        for (int i = 0; i < 8; ++i)
            tkh[half][j + 32 * i] = (_Float16)tkg[(size_t)bb * 256 + j + 32 * i];
        if (j < 8) qb_s[half][j] = qbg[bb * 8 + j];
    }
    int base = 0, ne = 0;
    if (vb) { base = offs[bb]; ne = offs[bb + 1] - base; }
    int mych = (ne + 31) >> 5;
    int och = __shfl_xor(mych, 32);
    int nch = mych > och ? mych : och;
    __syncthreads();

    const float step = 5.0f / 31.0f;
    const float coeff = -0.5f / (step * step);

    float dnp[8];
#pragma unroll
    for (int h = 0; h < 8; ++h) dnp[h] = 0.f;
    f4 acc = make_float4(0.f, 0.f, 0.f, 0.f);
    f4 wa  = make_float4(0.f, 0.f, 0.f, 0.f);
    f4 wb  = make_float4(0.f, 0.f, 0.f, 0.f);
    f4 acc2 = acc, wa2 = acc, wb2 = acc;

    int h4 = j >> 2;
    int dq8 = 8 * (j & 3);

    for (int cb = 0; cb < nch; ++cb) {
        int ebase = cb * 32;
        int nec = ne - ebase;
        nec = nec < 0 ? 0 : (nec > 32 ? 32 : nec);
        // ---- phase A: edge-parallel scores (fp16 dots) ----
        if (j < nec) {
            int eg = base + ebase + j;
            int src = ssrc[eg];
            float dist = sdist[eg];
            src_s[half][j] = src;
            h8v dh[4];
#pragma unroll
            for (int k2 = 0; k2 < 4; ++k2) {
#pragma unroll
                for (int m = 0; m < 8; ++m) {
                    float t = dist - step * (float)(8 * k2 + m);
                    dh[k2][m] = (_Float16)__expf(coeff * t * t);
                }
                *(h8v*)&de_s[half][j * 40 + 8 * k2] = dh[k2];
            }
            float sc[8];
#pragma unroll
            for (int h = 0; h < 8; ++h) sc[h] = qb_s[half][h];
            const _Float16* kap = ka + (size_t)src * 128;
#pragma unroll
            for (int f = 0; f < 16; ++f) {
                h8v kv = *(const h8v*)(kap + 8 * f);
                h8v qq = *(const h8v*)&qh[half][8 * f];
                int hh = f >> 1;
#pragma unroll
                for (int m = 0; m < 4; ++m) {
                    h2v a = {qq[2 * m], qq[2 * m + 1]};
                    h2v bq2 = {kv[2 * m], kv[2 * m + 1]};
                    sc[hh] = fdot2_acc(a, bq2, sc[hh]);
                }
            }
            const h2v* dh2 = (const h2v*)dh;
#pragma unroll
            for (int h = 0; h < 8; ++h) {
                float s = 0.f;
                h8v t0 = *(const h8v*)&tkh[half][h * 32];
                h8v t1 = *(const h8v*)&tkh[half][h * 32 + 8];
                h8v t2 = *(const h8v*)&tkh[half][h * 32 + 16];
                h8v t3 = *(const h8v*)&tkh[half][h * 32 + 24];
#pragma unroll
                for (int m = 0; m < 4; ++m) {
                    h2v ta = {t0[2 * m], t0[2 * m + 1]};
                    h2v tb = {t1[2 * m], t1[2 * m + 1]};
                    h2v tc = {t2[2 * m], t2[2 * m + 1]};
                    h2v td = {t3[2 * m], t3[2 * m + 1]};
                    s = fdot2_acc(dh2[m], ta, s);
                    s = fdot2_acc(dh2[4 + m], tb, s);
                    s = fdot2_acc(dh2[8 + m], tc, s);
                    s = fdot2_acc(dh2[12 + m], td, s);
                }
                float wv_ = __expf(sc[h] + s);
                dnp[h] += wv_;
                w_s[half][j * 9 + h] = wv_;
            }
        }
        __syncthreads();
        // ---- phase B: channel-parallel accumulation, 2x unrolled ----
        int e = 0;
        for (; e + 2 <= nec; e += 2) {
            int s0 = src_s[half][e];
            int s1 = src_s[half][e + 1];
            float ww0 = w_s[half][e * 9 + h4];
            float ww1 = w_s[half][(e + 1) * 9 + h4];
            h4v v0 = *(const h4v*)(va + (size_t)s0 * 128 + 4 * j);
            h4v v1 = *(const h4v*)(va + (size_t)s1 * 128 + 4 * j);
            h8v d0 = *(const h8v*)&de_s[half][e * 40 + dq8];
            h8v d1 = *(const h8v*)&de_s[half][(e + 1) * 40 + dq8];
            acc.x += ww0 * (float)v0[0]; acc.y += ww0 * (float)v0[1];
            acc.z += ww0 * (float)v0[2]; acc.w += ww0 * (float)v0[3];
            wa.x += ww0 * (float)d0[0]; wa.y += ww0 * (float)d0[1];
            wa.z += ww0 * (float)d0[2]; wa.w += ww0 * (float)d0[3];
            wb.x += ww0 * (float)d0[4]; wb.y += ww0 * (float)d0[5];
            wb.z += ww0 * (float)d0[6]; wb.w += ww0 * (float)d0[7];
            acc2.x += ww1 * (float)v1[0]; acc2.y += ww1 * (float)v1[1];
            acc2.z += ww1 * (float)v1[2]; acc2.w += ww1 * (float)v1[3];
            wa2.x += ww1 * (float)d1[0]; wa2.y += ww1 * (float)d1[1];
            wa2.z += ww1 * (float)d1[2]; wa2.w += ww1 * (float)d1[3];
            wb2.x += ww1 * (float)d1[4]; wb2.y += ww1 * (float)d1[5];
            wb2.z += ww1 * (float)d1[6]; wb2.w += ww1 * (float)d1[7];
        }
        if (e < nec) {
            int s0 = src_s[half][e];
            float ww0 = w_s[half][e * 9 + h4];
            h4v v0 = *(const h4v*)(va + (size_t)s0 * 128 + 4 * j);
            h8v d0 = *(const h8v*)&de_s[half][e * 40 + dq8];
            acc.x += ww0 * (float)v0[0]; acc.y += ww0 * (float)v0[1];
            acc.z += ww0 * (float)v0[2]; acc.w += ww0 * (float)v0[3];
            wa.x += ww0 * (float)d0[0]; wa.y += ww0 * (float)d0[1];
            wa.z += ww0 * (float)d0[2]; wa.w += ww0 * (float)d0[3];
            wb.x += ww0 * (float)d0[4]; wb.y += ww0 * (float)d0[5];
            wb.z += ww0 * (float)d0[6]; wb.w += ww0 * (float)d0[7];
        }
        __syncthreads();
    }
    acc.x += acc2.x; acc.y += acc2.y; acc.z += acc2.z; acc.w += acc2.w;
    wa.x += wa2.x; wa.y += wa2.y; wa.z += wa2.z; wa.w += wa2.w;
    wb.x += wb2.x; wb.y += wb2.y; wb.z += wb2.z; wb.w += wb2.w;
#pragma unroll
    for (int h = 0; h < 8; ++h) {
        float v = dnp[h];
        v += __shfl_xor(v, 1);
        v += __shfl_xor(v, 2);
        v += __shfl_xor(v, 4);
        v += __shfl_xor(v, 8);
        v += __shfl_xor(v, 16);
        dnp[h] = v;
    }
    if (vb) {
        ((f4*)macc)[(size_t)bb * 32 + j] = acc;
        f4* wp = (f4*)&wdeg[(size_t)bb * 256 + h4 * 32 + dq8];
        wp[0] = wa;
        wp[1] = wb;
        if (j < 8) dnb[bb * 8 + j] = dnp[j];
    }
}

__device__ __forceinline__ float gelu_exact(float x) {
    return 0.5f * x * (1.0f + erff(x * 0.70710678118654752f));
}

// v_in = (macc + wde@WvB + dn*bv)/dn -> Wout -> gelu(Wt1) -> Wt2
__global__ void __launch_bounds__(128) k_mlp(
    const float* __restrict__ macc, const float* __restrict__ wdeg,
    const float* __restrict__ dnb, const float* __restrict__ Wv,
    const float* __restrict__ bv, const float* __restrict__ Wout,
    const float* __restrict__ bout, const float* __restrict__ Wt1,
    const float* __restrict__ bt1, const float* __restrict__ Wt2,
    const float* __restrict__ bt2, float* __restrict__ y, int NB) {
    __shared__ __align__(16) float s[8][D], x1[8][D], wdl[8][256];
    __shared__ float dnl[8][8];
    int b0 = blockIdx.x * 8;
    int c = threadIdx.x;
#pragma unroll
    for (int b = 0; b < 8; ++b) {
        int bi = b0 + b;
        s[b][c] = (bi < NB) ? macc[(size_t)bi * D + c] : 0.f;
    }
#pragma unroll
    for (int i = 0; i < 16; ++i) {
        int idx = c + 128 * i;
        int b = idx >> 8, r = idx & 255;
        wdl[b][r] = (b0 + b < NB) ? wdeg[(size_t)(b0 + b) * 256 + r] : 0.f;
    }
    if (c < 64) {
        int b = c >> 3, h = c & 7;
        dnl[b][h] = (b0 + b < NB) ? dnb[(b0 + b) * 8 + h] : 0.f;
    }
    __syncthreads();
    int hh = c >> 4;
    float acc[8];
#pragma unroll
    for (int b = 0; b < 8; ++b) acc[b] = 0.f;
    for (int tq = 0; tq < 8; ++tq) {
        float w0 = Wv[(128 + 4 * tq + 0) * D + c];
        float w1 = Wv[(128 + 4 * tq + 1) * D + c];
        float w2 = Wv[(128 + 4 * tq + 2) * D + c];
        float w3 = Wv[(128 + 4 * tq + 3) * D + c];
#pragma unroll
        for (int b = 0; b < 8; ++b) {
            f4 v = *(const f4*)&wdl[b][hh * 32 + 4 * tq];
            acc[b] += v.x * w0 + v.y * w1 + v.z * w2 + v.w * w3;
        }
    }
    float bvc = bv[c];
#pragma unroll
    for (int b = 0; b < 8; ++b) {
        float dn = dnl[b][hh];
        float inv = 1.0f / (dn + 1e-16f);
        x1[b][c] = (s[b][c] + acc[b] + bvc * dn) * inv;
    }
    __syncthreads();
    float bo = bout[c];
#pragma unroll
    for (int b = 0; b < 8; ++b) acc[b] = bo;
    for (int dq = 0; dq < 32; ++dq) {
        float w0 = Wout[(4 * dq + 0) * D + c];
        float w1 = Wout[(4 * dq + 1) * D + c];
        float w2 = Wout[(4 * dq + 2) * D + c];
        float w3 = Wout[(4 * dq + 3) * D + c];
#pragma unroll
        for (int b = 0; b < 8; ++b) {
            f4 v = *(const f4*)&x1[b][4 * dq];
            acc[b] += v.x * w0 + v.y * w1 + v.z * w2 + v.w * w3;
        }
    }
    __syncthreads();
#pragma unroll
    for (int b = 0; b < 8; ++b) s[b][c] = acc[b];
    __syncthreads();
    float bt = bt1[c];
#pragma unroll
    for (int b = 0; b < 8; ++b) acc[b] = bt;
    for (int dq = 0; dq < 32; ++dq) {
        float w0 = Wt1[(4 * dq + 0) * D + c];
        float w1 = Wt1[(4 * dq + 1) * D + c];
        float w2 = Wt1[(4 * dq + 2) * D + c];
        float w3 = Wt1[(4 * dq + 3) * D + c];
#pragma unroll
        for (int b = 0; b < 8; ++b) {
            f4 v = *(const f4*)&s[b][4 * dq];
            acc[b] += v.x * w0 + v.y * w1 + v.z * w2 + v.w * w3;
        }
    }
    __syncthreads();
#pragma unroll
    for (int b = 0; b < 8; ++b) x1[b][c] = gelu_exact(acc[b]);
    __syncthreads();
    int b2 = c >> 4;
    int l16 = c & 15;
    float p0 = 0.f, p1 = 0.f;
#pragma unroll
    for (int k = 0; k < 8; ++k) {
        int d = l16 + 16 * k;
        float hv = x1[b2][d];
        p0 += hv * Wt2[d * 2 + 0];
        p1 += hv * Wt2[d * 2 + 1];
    }
    p0 += __shfl_xor(p0, 1); p1 += __shfl_xor(p1, 1);
    p0 += __shfl_xor(p0, 2); p1 += __shfl_xor(p1, 2);
    p0 += __shfl_xor(p0, 4); p1 += __shfl_xor(p1, 4);
    p0 += __shfl_xor(p0, 8); p1 += __shfl_xor(p1, 8);
    int bi = b0 + b2;
    if (l16 == 0 && bi < NB) {
        y[bi * 2 + 0] = p0 + bt2[0];
        y[bi * 2 + 1] = p1 + bt2[1];
    }
}

extern "C" void kernel_launch(void* const* d_in, const int* in_sizes, int n_in,
                              void* d_out, int out_size, void* d_ws, size_t ws_size,
                              hipStream_t stream) {
    const float* af     = (const float*)d_in[0];
    const float* coords = (const float*)d_in[1];
    const int*   rbi    = (const int*)d_in[2];
    const int*   etgt   = (const int*)d_in[3];
    const int*   esrc   = (const int*)d_in[4];
    const int*   tt     = (const int*)d_in[5];
    const float* W_dih  = (const float*)d_in[6];
    const float* b_dih  = (const float*)d_in[7];
    const float* Wq     = (const float*)d_in[8];
    const float* bq     = (const float*)d_in[9];
    const float* Wk     = (const float*)d_in[10];
    const float* bk     = (const float*)d_in[11];
    const float* Wv     = (const float*)d_in[12];
    const float* bv     = (const float*)d_in[13];
    const float* Wout   = (const float*)d_in[14];
    const float* bout   = (const float*)d_in[15];
    const float* Wt1    = (const float*)d_in[16];
    const float* bt1    = (const float*)d_in[17];
    const float* Wt2    = (const float*)d_in[18];
    const float* bt2    = (const float*)d_in[19];

    int N  = in_sizes[0] / D;
    int NB = in_sizes[2] / 2;
    int E  = in_sizes[3];

    char* ws = (char*)d_ws;
    size_t off = 0;
    auto alloc = [&](size_t bytes) -> char* {
        char* p = ws + off;
        off = (off + bytes + 255) & ~(size_t)255;
        return p;
    };
    _Float16* ka  = (_Float16*)alloc((size_t)N * D * 2);
    _Float16* va  = (_Float16*)alloc((size_t)N * D * 2);
    float* qv     = (float*)alloc((size_t)NB * D * 4);
    float* rbp    = (float*)alloc((size_t)NB * 3 * 4);
    float* tkg    = (float*)alloc((size_t)NB * 256 * 4);
    float* qbg    = (float*)alloc((size_t)NB * 8 * 4);
    float* maccb  = (float*)alloc((size_t)NB * D * 4);
    float* wdeg   = (float*)alloc((size_t)NB * 256 * 4);
    float* dnb    = (float*)alloc((size_t)NB * 8 * 4);
    int*   cnt2   = (int*)alloc((size_t)2 * NB * 4);
    int*   cnt    = cnt2;
    int*   cursor = cnt2 + NB;
    int*   offs   = (int*)alloc((size_t)(NB + 1) * 4);
    int*   ssrc   = (int*)alloc((size_t)E * 4);
    float* sdist  = (float*)alloc((size_t)E * 4);
    unsigned short* Wth = (unsigned short*)alloc((size_t)256 * 128 * 2);
    unsigned short* Wtl = (unsigned short*)alloc((size_t)256 * 128 * 2);

    k_zero<<<(2 * NB + 255) / 256, 256, 0, stream>>>(cnt2, 2 * NB);
    k_wprep<<<128, 256, 0, stream>>>(Wk, Wv, Wth, Wtl);
    k_atomproj<<<(N + 63) / 64, 256, 0, stream>>>(af, Wth, Wtl, ka, va, N);
    k_bondfeats<<<(NB + 7) / 8, 128, 0, stream>>>(af, coords, rbi, tt, W_dih,
                                                  b_dih, Wq, bq, Wk, bk,
                                                  qv, rbp, tkg, qbg, NB);
    k_count<<<(E + 255) / 256, 256, 0, stream>>>(etgt, cnt, E);
    k_scan<<<1, 1024, 0, stream>>>(cnt, offs, NB);
    k_scatter<<<(E + 255) / 256, 256, 0, stream>>>(etgt, esrc, coords, rbp,
                                                   offs, cursor, ssrc, sdist, E);
    k_attn<<<(NB + 1) / 2, 64, 0, stream>>>(qv, tkg, qbg, ka, va, ssrc, sdist,
                                            offs, maccb, wdeg, dnb, NB);
    k_mlp<<<(NB + 7) / 8, 128, 0, stream>>>(maccb, wdeg, dnb, Wv, bv, Wout,
                                            bout, Wt1, bt1, Wt2, bt2,
                                            (float*)d_out, NB);
}

// Round 7
// 292.909 us; speedup vs baseline: 1.4397x; 1.0284x over previous
//
#include <hip/hip_runtime.h>
#include <math.h>

#define D 128
#define DDIM 32
#define NHEAD 8

typedef float4 f4;
typedef __attribute__((ext_vector_type(8))) short short8;
typedef __attribute__((ext_vector_type(4))) float f32x4;
typedef _Float16 h2v __attribute__((ext_vector_type(2)));
typedef _Float16 h4v __attribute__((ext_vector_type(4)));
typedef _Float16 h8v __attribute__((ext_vector_type(8)));

#if defined(__has_builtin)
#if __has_builtin(__builtin_amdgcn_fdot2)
#define HAVE_FDOT2 1
#endif
#endif

__device__ __forceinline__ float fdot2_acc(h2v a, h2v b, float c) {
#ifdef HAVE_FDOT2
    return __builtin_amdgcn_fdot2(a, b, c, false);
#else
    return c + (float)a[0] * (float)b[0] + (float)a[1] * (float)b[1];
#endif
}

__device__ __forceinline__ unsigned short bf16_rne(float x) {
    unsigned u = __float_as_uint(x);
    return (unsigned short)((u + 0x7fff + ((u >> 16) & 1)) >> 16);
}
__device__ __forceinline__ float bf16_to_f(unsigned short h) {
    return __uint_as_float(((unsigned)h) << 16);
}

__global__ void k_zero(int* __restrict__ p, int n) {
    int i = blockIdx.x * blockDim.x + threadIdx.x;
    if (i < n) p[i] = 0;
}

// Split Wk|Wv into transposed bf16 hi/lo: Wt[col][k], col 0-127 = Wk, 128-255 = Wv
__global__ void __launch_bounds__(256) k_wprep(
    const float* __restrict__ Wk, const float* __restrict__ Wv,
    unsigned short* __restrict__ Wth, unsigned short* __restrict__ Wtl) {
    int idx = blockIdx.x * 256 + threadIdx.x;    // 0..32767
    int col = idx >> 7, k = idx & 127;
    float w = (col < 128) ? Wk[k * 128 + col] : Wv[k * 128 + (col - 128)];
    unsigned short h = bf16_rne(w);
    float r = w - bf16_to_f(h);
    Wth[idx] = h;
    Wtl[idx] = bf16_rne(r);
}

// Transposed bf16 hi/lo for Wab=[W0+W3; W1+W2] (K=256) and Wq (K=128)
__global__ void __launch_bounds__(256) k_wprep2(
    const float* __restrict__ W_dih, const float* __restrict__ Wq,
    unsigned short* __restrict__ Wabh, unsigned short* __restrict__ Wabl,
    unsigned short* __restrict__ Wqh, unsigned short* __restrict__ Wql) {
    int idx = blockIdx.x * 256 + threadIdx.x;
    if (idx < 32768) {
        int col = idx >> 8, k = idx & 255;
        float w;
        if (k < 128) w = W_dih[k * 128 + col] + W_dih[(384 + k) * 128 + col];
        else {
            int kk = k - 128;
            w = W_dih[(128 + kk) * 128 + col] + W_dih[(256 + kk) * 128 + col];
        }
        unsigned short h = bf16_rne(w);
        Wabh[idx] = h;
        Wabl[idx] = bf16_rne(w - bf16_to_f(h));
    } else if (idx < 49152) {
        int j = idx - 32768;
        int col = j >> 7, k = j & 127;
        float w = Wq[k * 128 + col];
        unsigned short h = bf16_rne(w);
        Wqh[j] = h;
        Wql[j] = bf16_rne(w - bf16_to_f(h));
    }
}

// MFMA: [ka|va] = af @ [WkA|WvA], 3-pass bf16 hi/lo split; fp16 output
__global__ void __launch_bounds__(256) k_atomproj(
    const float* __restrict__ af, const unsigned short* __restrict__ Wth,
    const unsigned short* __restrict__ Wtl, _Float16* __restrict__ ka,
    _Float16* __restrict__ va, int N) {
    __shared__ __align__(16) unsigned short Ahi[64 * 128];
    __shared__ __align__(16) unsigned short Alo[64 * 128];
    int t = threadIdx.x;
    int a0 = blockIdx.x * 64;
    const f4* af4 = (const f4*)af;
#pragma unroll
    for (int i = 0; i < 8; ++i) {
        int idx = t + 256 * i;           // 0..2047
        int row = idx >> 5, q4 = idx & 31;
        f4 v = make_float4(0.f, 0.f, 0.f, 0.f);
        if (a0 + row < N) v = af4[(size_t)(a0 + row) * 32 + q4];
        float xs[4] = {v.x, v.y, v.z, v.w};
        unsigned hp0, hp1, lp0, lp1;
        {
            unsigned short h0 = bf16_rne(xs[0]), h1 = bf16_rne(xs[1]);
            unsigned short h2 = bf16_rne(xs[2]), h3 = bf16_rne(xs[3]);
            unsigned short l0 = bf16_rne(xs[0] - bf16_to_f(h0));
            unsigned short l1 = bf16_rne(xs[1] - bf16_to_f(h1));
            unsigned short l2 = bf16_rne(xs[2] - bf16_to_f(h2));
            unsigned short l3 = bf16_rne(xs[3] - bf16_to_f(h3));
            hp0 = (unsigned)h0 | ((unsigned)h1 << 16);
            hp1 = (unsigned)h2 | ((unsigned)h3 << 16);
            lp0 = (unsigned)l0 | ((unsigned)l1 << 16);
            lp1 = (unsigned)l2 | ((unsigned)l3 << 16);
        }
        int byteoff = (q4 * 8) ^ ((row & 7) << 4);
        *(uint2*)((char*)Ahi + row * 256 + byteoff) = make_uint2(hp0, hp1);
        *(uint2*)((char*)Alo + row * 256 + byteoff) = make_uint2(lp0, lp1);
    }
    __syncthreads();

    int w = t >> 6;          // wave 0..3: waves 0-1 -> ka, 2-3 -> va
    int l = t & 63;
    int lr = l & 15;
    int lg = l >> 4;
    _Float16* outbase = (w < 2) ? ka : va;
    int colbase = (w & 1) * 64;

    f32x4 acc[4][4];
#pragma unroll
    for (int mf = 0; mf < 4; ++mf)
#pragma unroll
        for (int nf = 0; nf < 4; ++nf)
            acc[mf][nf] = (f32x4){0.f, 0.f, 0.f, 0.f};

    for (int ks = 0; ks < 4; ++ks) {
        short8 Bh[4], Bl[4];
#pragma unroll
        for (int nf = 0; nf < 4; ++nf) {
            size_t o = (size_t)(w * 64 + nf * 16 + lr) * 128 + ks * 32 + lg * 8;
            Bh[nf] = *(const short8*)(Wth + o);
            Bl[nf] = *(const short8*)(Wtl + o);
        }
#pragma unroll
        for (int mf = 0; mf < 4; ++mf) {
            int row = mf * 16 + lr;
            int kbyte = (ks * 64 + lg * 16) ^ ((row & 7) << 4);
            short8 Ah = *(const short8*)((const char*)Ahi + row * 256 + kbyte);
            short8 Al = *(const short8*)((const char*)Alo + row * 256 + kbyte);
#pragma unroll
            for (int nf = 0; nf < 4; ++nf) {
                acc[mf][nf] = __builtin_amdgcn_mfma_f32_16x16x32_bf16(Ah, Bh[nf], acc[mf][nf], 0, 0, 0);
                acc[mf][nf] = __builtin_amdgcn_mfma_f32_16x16x32_bf16(Al, Bh[nf], acc[mf][nf], 0, 0, 0);
                acc[mf][nf] = __builtin_amdgcn_mfma_f32_16x16x32_bf16(Ah, Bl[nf], acc[mf][nf], 0, 0, 0);
            }
        }
    }
#pragma unroll
    for (int mf = 0; mf < 4; ++mf) {
        int atom0 = a0 + mf * 16 + lg * 4;
#pragma unroll
        for (int r = 0; r < 4; ++r) {
            int atom = atom0 + r;
            if (atom < N) {
#pragma unroll
                for (int nf = 0; nf < 4; ++nf)
                    outbase[(size_t)atom * 128 + colbase + nf * 16 + lr] = (_Float16)acc[mf][nf][r];
            }
        }
    }
}

// MFMA bondfeats: rf = [s1|s2]@Wab + 2*b_dih; q = (rf@Wq + bq)*0.25; tk; qb; rbp
__global__ void __launch_bounds__(256) k_bondfeats(
    const float* __restrict__ af, const float* __restrict__ coords,
    const int* __restrict__ rbi, const int* __restrict__ tt,
    const float* __restrict__ b_dih, const float* __restrict__ bq,
    const unsigned short* __restrict__ Wabh, const unsigned short* __restrict__ Wabl,
    const unsigned short* __restrict__ Wqh, const unsigned short* __restrict__ Wql,
    const float* __restrict__ Wk, const float* __restrict__ bk,
    float* __restrict__ qv, float* __restrict__ rbp,
    float* __restrict__ tkg, float* __restrict__ qbg, int NB) {
    __shared__ __align__(16) char lds[32768];
    unsigned short* Ahi = (unsigned short*)lds;              // 32 rows x 512B (stage)
    unsigned short* Alo = (unsigned short*)(lds + 16384);
    int t = threadIdx.x;
    int b0 = blockIdx.x * 32;
    const f4* af4 = (const f4*)af;
    // ---- stage: s1|s2 (K=256) as bf16 hi/lo, swizzled ----
#pragma unroll
    for (int i = 0; i < 8; ++i) {
        int idx = t + 256 * i;          // 0..2047
        int bond = idx >> 6, rem = idx & 63;
        int halfm = rem >> 5, q4 = rem & 31;
        int bi = b0 + bond;
        f4 v = make_float4(0.f, 0.f, 0.f, 0.f);
        if (bi < NB) {
            int ia, ib_;
            if (halfm == 0) { ia = tt[bi * 4 + 0]; ib_ = tt[bi * 4 + 3]; }
            else            { ia = tt[bi * 4 + 1]; ib_ = tt[bi * 4 + 2]; }
            f4 va_ = af4[(size_t)ia * 32 + q4];
            f4 vb_ = af4[(size_t)ib_ * 32 + q4];
            v = make_float4(va_.x + vb_.x, va_.y + vb_.y, va_.z + vb_.z, va_.w + vb_.w);
        }
        float xs[4] = {v.x, v.y, v.z, v.w};
        unsigned short h0 = bf16_rne(xs[0]), h1 = bf16_rne(xs[1]);
        unsigned short h2 = bf16_rne(xs[2]), h3 = bf16_rne(xs[3]);
        unsigned short l0 = bf16_rne(xs[0] - bf16_to_f(h0));
        unsigned short l1 = bf16_rne(xs[1] - bf16_to_f(h1));
        unsigned short l2 = bf16_rne(xs[2] - bf16_to_f(h2));
        unsigned short l3 = bf16_rne(xs[3] - bf16_to_f(h3));
        uint2 hp = make_uint2((unsigned)h0 | ((unsigned)h1 << 16),
                              (unsigned)h2 | ((unsigned)h3 << 16));
        uint2 lp = make_uint2((unsigned)l0 | ((unsigned)l1 << 16),
                              (unsigned)l2 | ((unsigned)l3 << 16));
        int byteoff = (halfm * 256 + q4 * 8) ^ ((bond & 7) << 4);
        *(uint2*)((char*)Ahi + bond * 512 + byteoff) = hp;
        *(uint2*)((char*)Alo + bond * 512 + byteoff) = lp;
    }
    if (t < 96) {
        int b = t / 3, x = t % 3;
        int bi = b0 + b;
        if (bi < NB) {
            int a0i = rbi[bi], a1i = rbi[NB + bi];
            rbp[bi * 3 + x] = 0.5f * (coords[a0i * 3 + x] + coords[a1i * 3 + x]);
        }
    }
    __syncthreads();
    // ---- GEMM1: rf = A(32x256) @ Wab(256x128), 3-pass ----
    int w = t >> 6, l = t & 63, lr = l & 15, lg = l >> 4;
    int colbase = w * 32;
    f32x4 acc[2][2];
#pragma unroll
    for (int mf = 0; mf < 2; ++mf)
#pragma unroll
        for (int nf = 0; nf < 2; ++nf)
            acc[mf][nf] = (f32x4){0.f, 0.f, 0.f, 0.f};
    for (int ks = 0; ks < 8; ++ks) {
        short8 Bh[2], Bl[2];
#pragma unroll
        for (int nf = 0; nf < 2; ++nf) {
            size_t o = (size_t)(colbase + nf * 16 + lr) * 256 + ks * 32 + lg * 8;
            Bh[nf] = *(const short8*)(Wabh + o);
            Bl[nf] = *(const short8*)(Wabl + o);
        }
#pragma unroll
        for (int mf = 0; mf < 2; ++mf) {
            int row = mf * 16 + lr;
            int kbyte = (ks * 64 + lg * 16) ^ ((row & 7) << 4);
            short8 Ah = *(const short8*)((const char*)Ahi + row * 512 + kbyte);
            short8 Al = *(const short8*)((const char*)Alo + row * 512 + kbyte);
#pragma unroll
            for (int nf = 0; nf < 2; ++nf) {
                acc[mf][nf] = __builtin_amdgcn_mfma_f32_16x16x32_bf16(Ah, Bh[nf], acc[mf][nf], 0, 0, 0);
                acc[mf][nf] = __builtin_amdgcn_mfma_f32_16x16x32_bf16(Al, Bh[nf], acc[mf][nf], 0, 0, 0);
                acc[mf][nf] = __builtin_amdgcn_mfma_f32_16x16x32_bf16(Ah, Bl[nf], acc[mf][nf], 0, 0, 0);
            }
        }
    }
    float bd[2];
#pragma unroll
    for (int nf = 0; nf < 2; ++nf) bd[nf] = 2.f * b_dih[colbase + nf * 16 + lr];
    __syncthreads();   // all GEMM1 LDS reads done before overwrite
    // ---- write rf as bf16 hi/lo (A-layout for GEMM2) ----
    {
        char* rfh = lds;            // 32 rows x 256B
        char* rfl = lds + 8192;
#pragma unroll
        for (int mf = 0; mf < 2; ++mf) {
#pragma unroll
            for (int nf = 0; nf < 2; ++nf) {
#pragma unroll
                for (int r = 0; r < 4; ++r) {
                    int row = mf * 16 + lg * 4 + r;
                    int col = colbase + nf * 16 + lr;
                    float vv_ = acc[mf][nf][r] + bd[nf];
                    unsigned short hh = bf16_rne(vv_);
                    unsigned short ll = bf16_rne(vv_ - bf16_to_f(hh));
                    int byteo = row * 256 + ((col * 2) ^ ((row & 7) << 4));
                    *(unsigned short*)(rfh + byteo) = hh;
                    *(unsigned short*)(rfl + byteo) = ll;
                }
            }
        }
    }
    __syncthreads();
    // ---- GEMM2: q = rf(32x128) @ Wq(128x128), 3-pass ----
    f32x4 acc2[2][2];
#pragma unroll
    for (int mf = 0; mf < 2; ++mf)
#pragma unroll
        for (int nf = 0; nf < 2; ++nf)
            acc2[mf][nf] = (f32x4){0.f, 0.f, 0.f, 0.f};
    for (int ks = 0; ks < 4; ++ks) {
        short8 Bh[2], Bl[2];
#pragma unroll
        for (int nf = 0; nf < 2; ++nf) {
            size_t o = (size_t)(colbase + nf * 16 + lr) * 128 + ks * 32 + lg * 8;
            Bh[nf] = *(const short8*)(Wqh + o);
            Bl[nf] = *(const short8*)(Wql + o);
        }
#pragma unroll
        for (int mf = 0; mf < 2; ++mf) {
            int row = mf * 16 + lr;
            int kbyte = (ks * 64 + lg * 16) ^ ((row & 7) << 4);
            short8 Ah = *(const short8*)((const char*)lds + row * 256 + kbyte);
            short8 Al = *(const short8*)((const char*)lds + 8192 + row * 256 + kbyte);
#pragma unroll
            for (int nf = 0; nf < 2; ++nf) {
                acc2[mf][nf] = __builtin_amdgcn_mfma_f32_16x16x32_bf16(Ah, Bh[nf], acc2[mf][nf], 0, 0, 0);
                acc2[mf][nf] = __builtin_amdgcn_mfma_f32_16x16x32_bf16(Al, Bh[nf], acc2[mf][nf], 0, 0, 0);
                acc2[mf][nf] = __builtin_amdgcn_mfma_f32_16x16x32_bf16(Ah, Bl[nf], acc2[mf][nf], 0, 0, 0);
            }
        }
    }
    float* qs = (float*)(lds + 16384);   // 32 x 128 f32
    {
        float bqv[2];
#pragma unroll
        for (int nf = 0; nf < 2; ++nf) bqv[nf] = bq[colbase + nf * 16 + lr];
#pragma unroll
        for (int mf = 0; mf < 2; ++mf) {
#pragma unroll
            for (int nf = 0; nf < 2; ++nf) {
#pragma unroll
                for (int r = 0; r < 4; ++r) {
                    int row = mf * 16 + lg * 4 + r;
                    int col = colbase + nf * 16 + lr;
                    float qq = (acc2[mf][nf][r] + bqv[nf]) * 0.25f;
                    qs[row * 128 + col] = qq;
                    int bi = b0 + row;
                    if (bi < NB) qv[(size_t)bi * 128 + col] = qq;
                }
            }
        }
    }
    __syncthreads();
    // ---- tk + qb ----
    int g = t >> 7, c = t & 127;
    int h = c >> 4, dx = (c & 15) * 2;
    float w0[16], w1[16];
#pragma unroll
    for (int cc = 0; cc < 16; ++cc) {
        w0[cc] = Wk[(128 + dx) * 128 + h * 16 + cc];
        w1[cc] = Wk[(129 + dx) * 128 + h * 16 + cc];
    }
#pragma unroll
    for (int b = 0; b < 16; ++b) {
        int row = g * 16 + b;
        float t0 = 0.f, t1 = 0.f;
#pragma unroll
        for (int k = 0; k < 4; ++k) {
            f4 qq = *(const f4*)&qs[row * 128 + h * 16 + 4 * k];
            t0 += w0[4 * k] * qq.x + w0[4 * k + 1] * qq.y + w0[4 * k + 2] * qq.z + w0[4 * k + 3] * qq.w;
            t1 += w1[4 * k] * qq.x + w1[4 * k + 1] * qq.y + w1[4 * k + 2] * qq.z + w1[4 * k + 3] * qq.w;
        }
        int bi = b0 + row;
        if (bi < NB) {
            tkg[(size_t)bi * 256 + h * 32 + dx]     = t0;
            tkg[(size_t)bi * 256 + h * 32 + dx + 1] = t1;
        }
    }
    float bkv = bk[h * 16 + (c & 15)];
#pragma unroll
    for (int b = 0; b < 16; ++b) {
        int row = g * 16 + b;
        float p = qs[row * 128 + h * 16 + (c & 15)] * bkv;
        p += __shfl_xor(p, 1);
        p += __shfl_xor(p, 2);
        p += __shfl_xor(p, 4);
        p += __shfl_xor(p, 8);
        int bi = b0 + row;
        if ((c & 15) == 0 && bi < NB) qbg[bi * 8 + h] = p;
    }
}

__global__ void k_count(const int* __restrict__ etgt, int* __restrict__ cnt, int E) {
    int e = blockIdx.x * blockDim.x + threadIdx.x;
    if (e < E) atomicAdd(&cnt[etgt[e]], 1);
}

__global__ void __launch_bounds__(1024) k_scan(const int* __restrict__ cnt,
                                               int* __restrict__ offs, int NB) {
    __shared__ int part[1024];
    int t = threadIdx.x;
    int CH = (NB + 1023) >> 10;
    int base = t * CH;
    int s = 0;
    for (int i = 0; i < CH; ++i) {
        int idx = base + i;
        if (idx < NB) s += cnt[idx];
    }
    part[t] = s;
    __syncthreads();
    for (int off = 1; off < 1024; off <<= 1) {
        int v = (t >= off) ? part[t - off] : 0;
        __syncthreads();
        part[t] += v;
        __syncthreads();
    }
    int run = part[t] - s;
    for (int i = 0; i < CH; ++i) {
        int idx = base + i;
        if (idx < NB) {
            offs[idx] = run;
            run += cnt[idx];
        }
    }
    if (t == 1023) offs[NB] = part[1023];
}

__global__ void k_scatter(const int* __restrict__ etgt, const int* __restrict__ esrc,
                          const float* __restrict__ coords, const float* __restrict__ rbp,
                          const int* __restrict__ offs, int* __restrict__ cursor,
                          int* __restrict__ ssrc, float* __restrict__ sdist, int E) {
    int e = blockIdx.x * blockDim.x + threadIdx.x;
    if (e < E) {
        int t = etgt[e];
        int pos = atomicAdd(&cursor[t], 1);
        int idx = offs[t] + pos;
        int src = esrc[e];
        ssrc[idx] = src;
        float dx = coords[src * 3 + 0] - rbp[t * 3 + 0];
        float dy = coords[src * 3 + 1] - rbp[t * 3 + 1];
        float dz = coords[src * 3 + 2] - rbp[t * 3 + 2];
        sdist[idx] = sqrtf(dx * dx + dy * dy + dz * dz);
    }
}

// one wave per 2 bonds; fp16 K/V + fdot2 scores; writes macc/wde/dn (V-proj B deferred)
__global__ void __launch_bounds__(64) k_attn(
    const float* __restrict__ qv, const float* __restrict__ tkg,
    const float* __restrict__ qbg, const _Float16* __restrict__ ka,
    const _Float16* __restrict__ va, const int* __restrict__ ssrc,
    const float* __restrict__ sdist, const int* __restrict__ offs,
    float* __restrict__ macc, float* __restrict__ wdeg,
    float* __restrict__ dnb, int NB) {
    __shared__ __align__(16) _Float16 qh[2][128];
    __shared__ __align__(16) _Float16 tkh[2][256];
    __shared__ float qb_s[2][8];
    __shared__ int   src_s[2][32];
    __shared__ __align__(16) _Float16 de_s[2][32 * 40];
    __shared__ float w_s[2][32 * 9];

    int l = threadIdx.x;
    int half = l >> 5;
    int j = l & 31;
    int bb = blockIdx.x * 2 + half;
    bool vb = bb < NB;

    if (vb) {
#pragma unroll
        for (int i = 0; i < 4; ++i)
            qh[half][j + 32 * i] = (_Float16)qv[(size_t)bb * D + j + 32 * i];
#pragma unroll
        for (int i = 0; i < 8; ++i)
            tkh[half][j + 32 * i] = (_Float16)tkg[(size_t)bb * 256 + j + 32 * i];
        if (j < 8) qb_s[half][j] = qbg[bb * 8 + j];
    }
    int base = 0, ne = 0;
    if (vb) { base = offs[bb]; ne = offs[bb + 1] - base; }
    int mych = (ne + 31) >> 5;
    int och = __shfl_xor(mych, 32);
    int nch = mych > och ? mych : och;
    __syncthreads();

    const float step = 5.0f / 31.0f;
    const float coeff = -0.5f / (step * step);

    float dnp[8];
#pragma unroll
    for (int h = 0; h < 8; ++h) dnp[h] = 0.f;
    f4 acc = make_float4(0.f, 0.f, 0.f, 0.f);
    f4 wa  = make_float4(0.f, 0.f, 0.f, 0.f);
    f4 wb  = make_float4(0.f, 0.f, 0.f, 0.f);
    f4 acc2 = acc, wa2 = acc, wb2 = acc;

    int h4 = j >> 2;
    int dq8 = 8 * (j & 3);

    for (int cb = 0; cb < nch; ++cb) {
        int ebase = cb * 32;
        int nec = ne - ebase;
        nec = nec < 0 ? 0 : (nec > 32 ? 32 : nec);
        if (j < nec) {
            int eg = base + ebase + j;
            int src = ssrc[eg];
            float dist = sdist[eg];
            src_s[half][j] = src;
            h8v dh[4];
#pragma unroll
            for (int k2 = 0; k2 < 4; ++k2) {
#pragma unroll
                for (int m = 0; m < 8; ++m) {
                    float t = dist - step * (float)(8 * k2 + m);
                    dh[k2][m] = (_Float16)__expf(coeff * t * t);
                }
                *(h8v*)&de_s[half][j * 40 + 8 * k2] = dh[k2];
            }
            float sc[8];
#pragma unroll
            for (int h = 0; h < 8; ++h) sc[h] = qb_s[half][h];
            const _Float16* kap = ka + (size_t)src * 128;
#pragma unroll
            for (int f = 0; f < 16; ++f) {
                h8v kv = *(const h8v*)(kap + 8 * f);
                h8v qq = *(const h8v*)&qh[half][8 * f];
                int hh = f >> 1;
#pragma unroll
                for (int m = 0; m < 4; ++m) {
                    h2v a = {qq[2 * m], qq[2 * m + 1]};
                    h2v bq2 = {kv[2 * m], kv[2 * m + 1]};
                    sc[hh] = fdot2_acc(a, bq2, sc[hh]);
                }
            }
            const h2v* dh2 = (const h2v*)dh;
#pragma unroll
            for (int h = 0; h < 8; ++h) {
                float s = 0.f;
                h8v t0 = *(const h8v*)&tkh[half][h * 32];
                h8v t1 = *(const h8v*)&tkh[half][h * 32 + 8];
                h8v t2 = *(const h8v*)&tkh[half][h * 32 + 16];
                h8v t3 = *(const h8v*)&tkh[half][h * 32 + 24];
#pragma unroll
                for (int m = 0; m < 4; ++m) {
                    h2v ta = {t0[2 * m], t0[2 * m + 1]};
                    h2v tb = {t1[2 * m], t1[2 * m + 1]};
                    h2v tc = {t2[2 * m], t2[2 * m + 1]};
                    h2v td = {t3[2 * m], t3[2 * m + 1]};
                    s = fdot2_acc(dh2[m], ta, s);
                    s = fdot2_acc(dh2[4 + m], tb, s);
                    s = fdot2_acc(dh2[8 + m], tc, s);
                    s = fdot2_acc(dh2[12 + m], td, s);
                }
                float wv_ = __expf(sc[h] + s);
                dnp[h] += wv_;
                w_s[half][j * 9 + h] = wv_;
            }
        }
        __syncthreads();
        int e = 0;
        for (; e + 2 <= nec; e += 2) {
            int s0 = src_s[half][e];
            int s1 = src_s[half][e + 1];
            float ww0 = w_s[half][e * 9 + h4];
            float ww1 = w_s[half][(e + 1) * 9 + h4];
            h4v v0 = *(const h4v*)(va + (size_t)s0 * 128 + 4 * j);
            h4v v1 = *(const h4v*)(va + (size_t)s1 * 128 + 4 * j);
            h8v d0 = *(const h8v*)&de_s[half][e * 40 + dq8];
            h8v d1 = *(const h8v*)&de_s[half][(e + 1) * 40 + dq8];
            acc.x += ww0 * (float)v0[0]; acc.y += ww0 * (float)v0[1];
            acc.z += ww0 * (float)v0[2]; acc.w += ww0 * (float)v0[3];
            wa.x += ww0 * (float)d0[0]; wa.y += ww0 * (float)d0[1];
            wa.z += ww0 * (float)d0[2]; wa.w += ww0 * (float)d0[3];
            wb.x += ww0 * (float)d0[4]; wb.y += ww0 * (float)d0[5];
            wb.z += ww0 * (float)d0[6]; wb.w += ww0 * (float)d0[7];
            acc2.x += ww1 * (float)v1[0]; acc2.y += ww1 * (float)v1[1];
            acc2.z += ww1 * (float)v1[2]; acc2.w += ww1 * (float)v1[3];
            wa2.x += ww1 * (float)d1[0]; wa2.y += ww1 * (float)d1[1];
            wa2.z += ww1 * (float)d1[2]; wa2.w += ww1 * (float)d1[3];
            wb2.x += ww1 * (float)d1[4]; wb2.y += ww1 * (float)d1[5];
            wb2.z += ww1 * (float)d1[6]; wb2.w += ww1 * (float)d1[7];
        }
        if (e < nec) {
            int s0 = src_s[half][e];
            float ww0 = w_s[half][e * 9 + h4];
            h4v v0 = *(const h4v*)(va + (size_t)s0 * 128 + 4 * j);
            h8v d0 = *(const h8v*)&de_s[half][e * 40 + dq8];
            acc.x += ww0 * (float)v0[0]; acc.y += ww0 * (float)v0[1];
            acc.z += ww0 * (float)v0[2]; acc.w += ww0 * (float)v0[3];
            wa.x += ww0 * (float)d0[0]; wa.y += ww0 * (float)d0[1];
            wa.z += ww0 * (float)d0[2]; wa.w += ww0 * (float)d0[3];
            wb.x += ww0 * (float)d0[4]; wb.y += ww0 * (float)d0[5];
            wb.z += ww0 * (float)d0[6]; wb.w += ww0 * (float)d0[7];
        }
        __syncthreads();
    }
    acc.x += acc2.x; acc.y += acc2.y; acc.z += acc2.z; acc.w += acc2.w;
    wa.x += wa2.x; wa.y += wa2.y; wa.z += wa2.z; wa.w += wa2.w;
    wb.x += wb2.x; wb.y += wb2.y; wb.z += wb2.z; wb.w += wb2.w;
#pragma unroll
    for (int h = 0; h < 8; ++h) {
        float v = dnp[h];
        v += __shfl_xor(v, 1);
        v += __shfl_xor(v, 2);
        v += __shfl_xor(v, 4);
        v += __shfl_xor(v, 8);
        v += __shfl_xor(v, 16);
        dnp[h] = v;
    }
    if (vb) {
        ((f4*)macc)[(size_t)bb * 32 + j] = acc;
        f4* wp = (f4*)&wdeg[(size_t)bb * 256 + h4 * 32 + dq8];
        wp[0] = wa;
        wp[1] = wb;
        if (j < 8) dnb[bb * 8 + j] = dnp[j];
    }
}

__device__ __forceinline__ float gelu_exact(float x) {
    return 0.5f * x * (1.0f + erff(x * 0.70710678118654752f));
}

// v_in = (macc + wde@WvB + dn*bv)/dn -> Wout -> gelu(Wt1) -> Wt2
__global__ void __launch_bounds__(128) k_mlp(
    const float* __restrict__ macc, const float* __restrict__ wdeg,
    const float* __restrict__ dnb, const float* __restrict__ Wv,
    const float* __restrict__ bv, const float* __restrict__ Wout,
    const float* __restrict__ bout, const float* __restrict__ Wt1,
    const float* __restrict__ bt1, const float* __restrict__ Wt2,
    const float* __restrict__ bt2, float* __restrict__ y, int NB) {
    __shared__ __align__(16) float s[8][D], x1[8][D], wdl[8][256];
    __shared__ float dnl[8][8];
    int b0 = blockIdx.x * 8;
    int c = threadIdx.x;
#pragma unroll
    for (int b = 0; b < 8; ++b) {
        int bi = b0 + b;
        s[b][c] = (bi < NB) ? macc[(size_t)bi * D + c] : 0.f;
    }
#pragma unroll
    for (int i = 0; i < 16; ++i) {
        int idx = c + 128 * i;
        int b = idx >> 8, r = idx & 255;
        wdl[b][r] = (b0 + b < NB) ? wdeg[(size_t)(b0 + b) * 256 + r] : 0.f;
    }
    if (c < 64) {
        int b = c >> 3, h = c & 7;
        dnl[b][h] = (b0 + b < NB) ? dnb[(b0 + b) * 8 + h] : 0.f;
    }
    __syncthreads();
    int hh = c >> 4;
    float acc[8];
#pragma unroll
    for (int b = 0; b < 8; ++b) acc[b] = 0.f;
    for (int tq = 0; tq < 8; ++tq) {
        float w0 = Wv[(128 + 4 * tq + 0) * D + c];
        float w1 = Wv[(128 + 4 * tq + 1) * D + c];
        float w2 = Wv[(128 + 4 * tq + 2) * D + c];
        float w3 = Wv[(128 + 4 * tq + 3) * D + c];
#pragma unroll
        for (int b = 0; b < 8; ++b) {
            f4 v = *(const f4*)&wdl[b][hh * 32 + 4 * tq];
            acc[b] += v.x * w0 + v.y * w1 + v.z * w2 + v.w * w3;
        }
    }
    float bvc = bv[c];
#pragma unroll
    for (int b = 0; b < 8; ++b) {
        float dn = dnl[b][hh];
        float inv = 1.0f / (dn + 1e-16f);
        x1[b][c] = (s[b][c] + acc[b] + bvc * dn) * inv;
    }
    __syncthreads();
    float bo = bout[c];
#pragma unroll
    for (int b = 0; b < 8; ++b) acc[b] = bo;
    for (int dq = 0; dq < 32; ++dq) {
        float w0 = Wout[(4 * dq + 0) * D + c];
        float w1 = Wout[(4 * dq + 1) * D + c];
        float w2 = Wout[(4 * dq + 2) * D + c];
        float w3 = Wout[(4 * dq + 3) * D + c];
#pragma unroll
        for (int b = 0; b < 8; ++b) {
            f4 v = *(const f4*)&x1[b][4 * dq];
            acc[b] += v.x * w0 + v.y * w1 + v.z * w2 + v.w * w3;
        }
    }
    __syncthreads();
#pragma unroll
    for (int b = 0; b < 8; ++b) s[b][c] = acc[b];
    __syncthreads();
    float bt = bt1[c];
#pragma unroll
    for (int b = 0; b < 8; ++b) acc[b] = bt;
    for (int dq = 0; dq < 32; ++dq) {
        float w0 = Wt1[(4 * dq + 0) * D + c];
        float w1 = Wt1[(4 * dq + 1) * D + c];
        float w2 = Wt1[(4 * dq + 2) * D + c];
        float w3 = Wt1[(4 * dq + 3) * D + c];
#pragma unroll
        for (int b = 0; b < 8; ++b) {
            f4 v = *(const f4*)&s[b][4 * dq];
            acc[b] += v.x * w0 + v.y * w1 + v.z * w2 + v.w * w3;
        }
    }
    __syncthreads();
#pragma unroll
    for (int b = 0; b < 8; ++b) x1[b][c] = gelu_exact(acc[b]);
    __syncthreads();
    int b2 = c >> 4;
    int l16 = c & 15;
    float p0 = 0.f, p1 = 0.f;
#pragma unroll
    for (int k = 0; k < 8; ++k) {
        int d = l16 + 16 * k;
        float hv = x1[b2][d];
        p0 += hv * Wt2[d * 2 + 0];
        p1 += hv * Wt2[d * 2 + 1];
    }
    p0 += __shfl_xor(p0, 1); p1 += __shfl_xor(p1, 1);
    p0 += __shfl_xor(p0, 2); p1 += __shfl_xor(p1, 2);
    p0 += __shfl_xor(p0, 4); p1 += __shfl_xor(p1, 4);
    p0 += __shfl_xor(p0, 8); p1 += __shfl_xor(p1, 8);
    int bi = b0 + b2;
    if (l16 == 0 && bi < NB) {
        y[bi * 2 + 0] = p0 + bt2[0];
        y[bi * 2 + 1] = p1 + bt2[1];
    }
}

extern "C" void kernel_launch(void* const* d_in, const int* in_sizes, int n_in,
                              void* d_out, int out_size, void* d_ws, size_t ws_size,
                              hipStream_t stream) {
    const float* af     = (const float*)d_in[0];
    const float* coords = (const float*)d_in[1];
    const int*   rbi    = (const int*)d_in[2];
    const int*   etgt   = (const int*)d_in[3];
    const int*   esrc   = (const int*)d_in[4];
    const int*   tt     = (const int*)d_in[5];
    const float* W_dih  = (const float*)d_in[6];
    const float* b_dih  = (const float*)d_in[7];
    const float* Wq     = (const float*)d_in[8];
    const float* bq     = (const float*)d_in[9];
    const float* Wk     = (const float*)d_in[10];
    const float* bk     = (const float*)d_in[11];
    const float* Wv     = (const float*)d_in[12];
    const float* bv     = (const float*)d_in[13];
    const float* Wout   = (const float*)d_in[14];
    const float* bout   = (const float*)d_in[15];
    const float* Wt1    = (const float*)d_in[16];
    const float* bt1    = (const float*)d_in[17];
    const float* Wt2    = (const float*)d_in[18];
    const float* bt2    = (const float*)d_in[19];

    int N  = in_sizes[0] / D;
    int NB = in_sizes[2] / 2;
    int E  = in_sizes[3];

    char* ws = (char*)d_ws;
    size_t off = 0;
    auto alloc = [&](size_t bytes) -> char* {
        char* p = ws + off;
        off = (off + bytes + 255) & ~(size_t)255;
        return p;
    };
    _Float16* ka  = (_Float16*)alloc((size_t)N * D * 2);
    _Float16* va  = (_Float16*)alloc((size_t)N * D * 2);
    float* qv     = (float*)alloc((size_t)NB * D * 4);
    float* rbp    = (float*)alloc((size_t)NB * 3 * 4);
    float* tkg    = (float*)alloc((size_t)NB * 256 * 4);
    float* qbg    = (float*)alloc((size_t)NB * 8 * 4);
    float* maccb  = (float*)alloc((size_t)NB * D * 4);
    float* wdeg   = (float*)alloc((size_t)NB * 256 * 4);
    float* dnb    = (float*)alloc((size_t)NB * 8 * 4);
    int*   cnt2   = (int*)alloc((size_t)2 * NB * 4);
    int*   cnt    = cnt2;
    int*   cursor = cnt2 + NB;
    int*   offs   = (int*)alloc((size_t)(NB + 1) * 4);
    int*   ssrc   = (int*)alloc((size_t)E * 4);
    float* sdist  = (float*)alloc((size_t)E * 4);
    unsigned short* Wth  = (unsigned short*)alloc((size_t)256 * 128 * 2);
    unsigned short* Wtl  = (unsigned short*)alloc((size_t)256 * 128 * 2);
    unsigned short* Wabh = (unsigned short*)alloc((size_t)128 * 256 * 2);
    unsigned short* Wabl = (unsigned short*)alloc((size_t)128 * 256 * 2);
    unsigned short* Wqh  = (unsigned short*)alloc((size_t)128 * 128 * 2);
    unsigned short* Wql  = (unsigned short*)alloc((size_t)128 * 128 * 2);

    k_zero<<<(2 * NB + 255) / 256, 256, 0, stream>>>(cnt2, 2 * NB);
    k_wprep<<<128, 256, 0, stream>>>(Wk, Wv, Wth, Wtl);
    k_wprep2<<<192, 256, 0, stream>>>(W_dih, Wq, Wabh, Wabl, Wqh, Wql);
    k_atomproj<<<(N + 63) / 64, 256, 0, stream>>>(af, Wth, Wtl, ka, va, N);
    k_bondfeats<<<(NB + 31) / 32, 256, 0, stream>>>(af, coords, rbi, tt, b_dih,
                                                    bq, Wabh, Wabl, Wqh, Wql,
                                                    Wk, bk, qv, rbp, tkg, qbg, NB);
    k_count<<<(E + 255) / 256, 256, 0, stream>>>(etgt, cnt, E);
    k_scan<<<1, 1024, 0, stream>>>(cnt, offs, NB);
    k_scatter<<<(E + 255) / 256, 256, 0, stream>>>(etgt, esrc, coords, rbp,
                                                   offs, cursor, ssrc, sdist, E);
    k_attn<<<(NB + 1) / 2, 64, 0, stream>>>(qv, tkg, qbg, ka, va, ssrc, sdist,
                                            offs, maccb, wdeg, dnb, NB);
    k_mlp<<<(NB + 7) / 8, 128, 0, stream>>>(maccb, wdeg, dnb, Wv, bv, Wout,
                                            bout, Wt1, bt1, Wt2, bt2,
                                            (float*)d_out, NB);
}

// Round 9
// 277.452 us; speedup vs baseline: 1.5199x; 1.0557x over previous
//
#include <hip/hip_runtime.h>
#include <math.h>

#define D 128
#define DDIM 32
#define NHEAD 8

typedef float4 f4;
typedef __attribute__((ext_vector_type(8))) short short8;
typedef __attribute__((ext_vector_type(4))) float f32x4;
typedef _Float16 h2v __attribute__((ext_vector_type(2)));
typedef _Float16 h4v __attribute__((ext_vector_type(4)));
typedef _Float16 h8v __attribute__((ext_vector_type(8)));

#if defined(__has_builtin)
#if __has_builtin(__builtin_amdgcn_fdot2)
#define HAVE_FDOT2 1
#endif
#endif

__device__ __forceinline__ float fdot2_acc(h2v a, h2v b, float c) {
#ifdef HAVE_FDOT2
    return __builtin_amdgcn_fdot2(a, b, c, false);
#else
    return c + (float)a[0] * (float)b[0] + (float)a[1] * (float)b[1];
#endif
}

__device__ __forceinline__ unsigned short bf16_rne(float x) {
    unsigned u = __float_as_uint(x);
    return (unsigned short)((u + 0x7fff + ((u >> 16) & 1)) >> 16);
}
__device__ __forceinline__ float bf16_to_f(unsigned short h) {
    return __uint_as_float(((unsigned)h) << 16);
}

// Unified prep: bf16 hi/lo transposed weights for Wk|Wv, Wab, Wq, Wout, Wt1 + zero cnt
__global__ void __launch_bounds__(256) k_prep(
    const float* __restrict__ Wk, const float* __restrict__ Wv,
    const float* __restrict__ W_dih, const float* __restrict__ Wq,
    const float* __restrict__ Wout, const float* __restrict__ Wt1,
    unsigned short* __restrict__ Wth, unsigned short* __restrict__ Wtl,
    unsigned short* __restrict__ Wabh, unsigned short* __restrict__ Wabl,
    unsigned short* __restrict__ Wqh, unsigned short* __restrict__ Wql,
    unsigned short* __restrict__ Wouth, unsigned short* __restrict__ Woutl,
    unsigned short* __restrict__ Wt1h, unsigned short* __restrict__ Wt1l,
    int* __restrict__ cnt2, int nzero) {
    int idx = blockIdx.x * 256 + threadIdx.x;
    if (idx < 32768) {
        int col = idx >> 7, k = idx & 127;
        float w = (col < 128) ? Wk[k * 128 + col] : Wv[k * 128 + (col - 128)];
        unsigned short h = bf16_rne(w);
        Wth[idx] = h;
        Wtl[idx] = bf16_rne(w - bf16_to_f(h));
    } else if (idx < 65536) {
        int j = idx - 32768;
        int col = j >> 8, k = j & 255;
        float w;
        if (k < 128) w = W_dih[k * 128 + col] + W_dih[(384 + k) * 128 + col];
        else {
            int kk = k - 128;
            w = W_dih[(128 + kk) * 128 + col] + W_dih[(256 + kk) * 128 + col];
        }
        unsigned short h = bf16_rne(w);
        Wabh[j] = h;
        Wabl[j] = bf16_rne(w - bf16_to_f(h));
    } else if (idx < 81920) {
        int j = idx - 65536;
        int col = j >> 7, k = j & 127;
        float w = Wq[k * 128 + col];
        unsigned short h = bf16_rne(w);
        Wqh[j] = h;
        Wql[j] = bf16_rne(w - bf16_to_f(h));
    } else if (idx < 98304) {
        int j = idx - 81920;
        int col = j >> 7, k = j & 127;
        float w = Wout[k * 128 + col];
        unsigned short h = bf16_rne(w);
        Wouth[j] = h;
        Woutl[j] = bf16_rne(w - bf16_to_f(h));
    } else if (idx < 114688) {
        int j = idx - 98304;
        int col = j >> 7, k = j & 127;
        float w = Wt1[k * 128 + col];
        unsigned short h = bf16_rne(w);
        Wt1h[j] = h;
        Wt1l[j] = bf16_rne(w - bf16_to_f(h));
    } else {
        int j = idx - 114688;
        if (j < nzero) cnt2[j] = 0;
    }
}

// MFMA: [ka|va] = af @ [WkA|WvA], 3-pass bf16 hi/lo split; fp16 output
__global__ void __launch_bounds__(256) k_atomproj(
    const float* __restrict__ af, const unsigned short* __restrict__ Wth,
    const unsigned short* __restrict__ Wtl, _Float16* __restrict__ ka,
    _Float16* __restrict__ va, int N) {
    __shared__ __align__(16) unsigned short Ahi[64 * 128];
    __shared__ __align__(16) unsigned short Alo[64 * 128];
    int t = threadIdx.x;
    int a0 = blockIdx.x * 64;
    const f4* af4 = (const f4*)af;
#pragma unroll
    for (int i = 0; i < 8; ++i) {
        int idx = t + 256 * i;
        int row = idx >> 5, q4 = idx & 31;
        f4 v = make_float4(0.f, 0.f, 0.f, 0.f);
        if (a0 + row < N) v = af4[(size_t)(a0 + row) * 32 + q4];
        float xs[4] = {v.x, v.y, v.z, v.w};
        unsigned hp0, hp1, lp0, lp1;
        {
            unsigned short h0 = bf16_rne(xs[0]), h1 = bf16_rne(xs[1]);
            unsigned short h2 = bf16_rne(xs[2]), h3 = bf16_rne(xs[3]);
            unsigned short l0 = bf16_rne(xs[0] - bf16_to_f(h0));
            unsigned short l1 = bf16_rne(xs[1] - bf16_to_f(h1));
            unsigned short l2 = bf16_rne(xs[2] - bf16_to_f(h2));
            unsigned short l3 = bf16_rne(xs[3] - bf16_to_f(h3));
            hp0 = (unsigned)h0 | ((unsigned)h1 << 16);
            hp1 = (unsigned)h2 | ((unsigned)h3 << 16);
            lp0 = (unsigned)l0 | ((unsigned)l1 << 16);
            lp1 = (unsigned)l2 | ((unsigned)l3 << 16);
        }
        int byteoff = (q4 * 8) ^ ((row & 7) << 4);
        *(uint2*)((char*)Ahi + row * 256 + byteoff) = make_uint2(hp0, hp1);
        *(uint2*)((char*)Alo + row * 256 + byteoff) = make_uint2(lp0, lp1);
    }
    __syncthreads();

    int w = t >> 6;
    int l = t & 63;
    int lr = l & 15;
    int lg = l >> 4;
    _Float16* outbase = (w < 2) ? ka : va;
    int colbase = (w & 1) * 64;

    f32x4 acc[4][4];
#pragma unroll
    for (int mf = 0; mf < 4; ++mf)
#pragma unroll
        for (int nf = 0; nf < 4; ++nf)
            acc[mf][nf] = (f32x4){0.f, 0.f, 0.f, 0.f};

    for (int ks = 0; ks < 4; ++ks) {
        short8 Bh[4], Bl[4];
#pragma unroll
        for (int nf = 0; nf < 4; ++nf) {
            size_t o = (size_t)(w * 64 + nf * 16 + lr) * 128 + ks * 32 + lg * 8;
            Bh[nf] = *(const short8*)(Wth + o);
            Bl[nf] = *(const short8*)(Wtl + o);
        }
#pragma unroll
        for (int mf = 0; mf < 4; ++mf) {
            int row = mf * 16 + lr;
            int kbyte = (ks * 64 + lg * 16) ^ ((row & 7) << 4);
            short8 Ah = *(const short8*)((const char*)Ahi + row * 256 + kbyte);
            short8 Al = *(const short8*)((const char*)Alo + row * 256 + kbyte);
#pragma unroll
            for (int nf = 0; nf < 4; ++nf) {
                acc[mf][nf] = __builtin_amdgcn_mfma_f32_16x16x32_bf16(Ah, Bh[nf], acc[mf][nf], 0, 0, 0);
                acc[mf][nf] = __builtin_amdgcn_mfma_f32_16x16x32_bf16(Al, Bh[nf], acc[mf][nf], 0, 0, 0);
                acc[mf][nf] = __builtin_amdgcn_mfma_f32_16x16x32_bf16(Ah, Bl[nf], acc[mf][nf], 0, 0, 0);
            }
        }
    }
#pragma unroll
    for (int mf = 0; mf < 4; ++mf) {
        int atom0 = a0 + mf * 16 + lg * 4;
#pragma unroll
        for (int r = 0; r < 4; ++r) {
            int atom = atom0 + r;
            if (atom < N) {
#pragma unroll
                for (int nf = 0; nf < 4; ++nf)
                    outbase[(size_t)atom * 128 + colbase + nf * 16 + lr] = (_Float16)acc[mf][nf][r];
            }
        }
    }
}

// MFMA bondfeats: rf = [s1|s2]@Wab + 2*b_dih; q = (rf@Wq + bq)*0.25; tk; qb; rbp
__global__ void __launch_bounds__(256) k_bondfeats(
    const float* __restrict__ af, const float* __restrict__ coords,
    const int* __restrict__ rbi, const int* __restrict__ tt,
    const float* __restrict__ b_dih, const float* __restrict__ bq,
    const unsigned short* __restrict__ Wabh, const unsigned short* __restrict__ Wabl,
    const unsigned short* __restrict__ Wqh, const unsigned short* __restrict__ Wql,
    const float* __restrict__ Wk, const float* __restrict__ bk,
    float* __restrict__ qv, float* __restrict__ rbp,
    float* __restrict__ tkg, float* __restrict__ qbg, int NB) {
    __shared__ __align__(16) char lds[32768];
    unsigned short* Ahi = (unsigned short*)lds;
    unsigned short* Alo = (unsigned short*)(lds + 16384);
    int t = threadIdx.x;
    int b0 = blockIdx.x * 32;
    const f4* af4 = (const f4*)af;
#pragma unroll
    for (int i = 0; i < 8; ++i) {
        int idx = t + 256 * i;
        int bond = idx >> 6, rem = idx & 63;
        int halfm = rem >> 5, q4 = rem & 31;
        int bi = b0 + bond;
        f4 v = make_float4(0.f, 0.f, 0.f, 0.f);
        if (bi < NB) {
            int ia, ib_;
            if (halfm == 0) { ia = tt[bi * 4 + 0]; ib_ = tt[bi * 4 + 3]; }
            else            { ia = tt[bi * 4 + 1]; ib_ = tt[bi * 4 + 2]; }
            f4 va_ = af4[(size_t)ia * 32 + q4];
            f4 vb_ = af4[(size_t)ib_ * 32 + q4];
            v = make_float4(va_.x + vb_.x, va_.y + vb_.y, va_.z + vb_.z, va_.w + vb_.w);
        }
        float xs[4] = {v.x, v.y, v.z, v.w};
        unsigned short h0 = bf16_rne(xs[0]), h1 = bf16_rne(xs[1]);
        unsigned short h2 = bf16_rne(xs[2]), h3 = bf16_rne(xs[3]);
        unsigned short l0 = bf16_rne(xs[0] - bf16_to_f(h0));
        unsigned short l1 = bf16_rne(xs[1] - bf16_to_f(h1));
        unsigned short l2 = bf16_rne(xs[2] - bf16_to_f(h2));
        unsigned short l3 = bf16_rne(xs[3] - bf16_to_f(h3));
        uint2 hp = make_uint2((unsigned)h0 | ((unsigned)h1 << 16),
                              (unsigned)h2 | ((unsigned)h3 << 16));
        uint2 lp = make_uint2((unsigned)l0 | ((unsigned)l1 << 16),
                              (unsigned)l2 | ((unsigned)l3 << 16));
        int byteoff = (halfm * 256 + q4 * 8) ^ ((bond & 7) << 4);
        *(uint2*)((char*)Ahi + bond * 512 + byteoff) = hp;
        *(uint2*)((char*)Alo + bond * 512 + byteoff) = lp;
    }
    if (t < 96) {
        int b = t / 3, x = t % 3;
        int bi = b0 + b;
        if (bi < NB) {
            int a0i = rbi[bi], a1i = rbi[NB + bi];
            rbp[bi * 3 + x] = 0.5f * (coords[a0i * 3 + x] + coords[a1i * 3 + x]);
        }
    }
    __syncthreads();
    int w = t >> 6, l = t & 63, lr = l & 15, lg = l >> 4;
    int colbase = w * 32;
    f32x4 acc[2][2];
#pragma unroll
    for (int mf = 0; mf < 2; ++mf)
#pragma unroll
        for (int nf = 0; nf < 2; ++nf)
            acc[mf][nf] = (f32x4){0.f, 0.f, 0.f, 0.f};
    for (int ks = 0; ks < 8; ++ks) {
        short8 Bh[2], Bl[2];
#pragma unroll
        for (int nf = 0; nf < 2; ++nf) {
            size_t o = (size_t)(colbase + nf * 16 + lr) * 256 + ks * 32 + lg * 8;
            Bh[nf] = *(const short8*)(Wabh + o);
            Bl[nf] = *(const short8*)(Wabl + o);
        }
#pragma unroll
        for (int mf = 0; mf < 2; ++mf) {
            int row = mf * 16 + lr;
            int kbyte = (ks * 64 + lg * 16) ^ ((row & 7) << 4);
            short8 Ah = *(const short8*)((const char*)Ahi + row * 512 + kbyte);
            short8 Al = *(const short8*)((const char*)Alo + row * 512 + kbyte);
#pragma unroll
            for (int nf = 0; nf < 2; ++nf) {
                acc[mf][nf] = __builtin_amdgcn_mfma_f32_16x16x32_bf16(Ah, Bh[nf], acc[mf][nf], 0, 0, 0);
                acc[mf][nf] = __builtin_amdgcn_mfma_f32_16x16x32_bf16(Al, Bh[nf], acc[mf][nf], 0, 0, 0);
                acc[mf][nf] = __builtin_amdgcn_mfma_f32_16x16x32_bf16(Ah, Bl[nf], acc[mf][nf], 0, 0, 0);
            }
        }
    }
    float bd[2];
#pragma unroll
    for (int nf = 0; nf < 2; ++nf) bd[nf] = 2.f * b_dih[colbase + nf * 16 + lr];
    __syncthreads();
    {
        char* rfh = lds;
        char* rfl = lds + 8192;
#pragma unroll
        for (int mf = 0; mf < 2; ++mf) {
#pragma unroll
            for (int nf = 0; nf < 2; ++nf) {
#pragma unroll
                for (int r = 0; r < 4; ++r) {
                    int row = mf * 16 + lg * 4 + r;
                    int col = colbase + nf * 16 + lr;
                    float vv_ = acc[mf][nf][r] + bd[nf];
                    unsigned short hh = bf16_rne(vv_);
                    unsigned short ll = bf16_rne(vv_ - bf16_to_f(hh));
                    int byteo = row * 256 + ((col * 2) ^ ((row & 7) << 4));
                    *(unsigned short*)(rfh + byteo) = hh;
                    *(unsigned short*)(rfl + byteo) = ll;
                }
            }
        }
    }
    __syncthreads();
    f32x4 acc2[2][2];
#pragma unroll
    for (int mf = 0; mf < 2; ++mf)
#pragma unroll
        for (int nf = 0; nf < 2; ++nf)
            acc2[mf][nf] = (f32x4){0.f, 0.f, 0.f, 0.f};
    for (int ks = 0; ks < 4; ++ks) {
        short8 Bh[2], Bl[2];
#pragma unroll
        for (int nf = 0; nf < 2; ++nf) {
            size_t o = (size_t)(colbase + nf * 16 + lr) * 128 + ks * 32 + lg * 8;
            Bh[nf] = *(const short8*)(Wqh + o);
            Bl[nf] = *(const short8*)(Wql + o);
        }
#pragma unroll
        for (int mf = 0; mf < 2; ++mf) {
            int row = mf * 16 + lr;
            int kbyte = (ks * 64 + lg * 16) ^ ((row & 7) << 4);
            short8 Ah = *(const short8*)((const char*)lds + row * 256 + kbyte);
            short8 Al = *(const short8*)((const char*)lds + 8192 + row * 256 + kbyte);
#pragma unroll
            for (int nf = 0; nf < 2; ++nf) {
                acc2[mf][nf] = __builtin_amdgcn_mfma_f32_16x16x32_bf16(Ah, Bh[nf], acc2[mf][nf], 0, 0, 0);
                acc2[mf][nf] = __builtin_amdgcn_mfma_f32_16x16x32_bf16(Al, Bh[nf], acc2[mf][nf], 0, 0, 0);
                acc2[mf][nf] = __builtin_amdgcn_mfma_f32_16x16x32_bf16(Ah, Bl[nf], acc2[mf][nf], 0, 0, 0);
            }
        }
    }
    float* qs = (float*)(lds + 16384);
    {
        float bqv[2];
#pragma unroll
        for (int nf = 0; nf < 2; ++nf) bqv[nf] = bq[colbase + nf * 16 + lr];
#pragma unroll
        for (int mf = 0; mf < 2; ++mf) {
#pragma unroll
            for (int nf = 0; nf < 2; ++nf) {
#pragma unroll
                for (int r = 0; r < 4; ++r) {
                    int row = mf * 16 + lg * 4 + r;
                    int col = colbase + nf * 16 + lr;
                    float qq = (acc2[mf][nf][r] + bqv[nf]) * 0.25f;
                    qs[row * 128 + col] = qq;
                    int bi = b0 + row;
                    if (bi < NB) qv[(size_t)bi * 128 + col] = qq;
                }
            }
        }
    }
    __syncthreads();
    int g = t >> 7, c = t & 127;
    int h = c >> 4, dx = (c & 15) * 2;
    float w0[16], w1[16];
#pragma unroll
    for (int cc = 0; cc < 16; ++cc) {
        w0[cc] = Wk[(128 + dx) * 128 + h * 16 + cc];
        w1[cc] = Wk[(129 + dx) * 128 + h * 16 + cc];
    }
#pragma unroll
    for (int b = 0; b < 16; ++b) {
        int row = g * 16 + b;
        float t0 = 0.f, t1 = 0.f;
#pragma unroll
        for (int k = 0; k < 4; ++k) {
            f4 qq = *(const f4*)&qs[row * 128 + h * 16 + 4 * k];
            t0 += w0[4 * k] * qq.x + w0[4 * k + 1] * qq.y + w0[4 * k + 2] * qq.z + w0[4 * k + 3] * qq.w;
            t1 += w1[4 * k] * qq.x + w1[4 * k + 1] * qq.y + w1[4 * k + 2] * qq.z + w1[4 * k + 3] * qq.w;
        }
        int bi = b0 + row;
        if (bi < NB) {
            tkg[(size_t)bi * 256 + h * 32 + dx]     = t0;
            tkg[(size_t)bi * 256 + h * 32 + dx + 1] = t1;
        }
    }
    float bkv = bk[h * 16 + (c & 15)];
#pragma unroll
    for (int b = 0; b < 16; ++b) {
        int row = g * 16 + b;
        float p = qs[row * 128 + h * 16 + (c & 15)] * bkv;
        p += __shfl_xor(p, 1);
        p += __shfl_xor(p, 2);
        p += __shfl_xor(p, 4);
        p += __shfl_xor(p, 8);
        int bi = b0 + row;
        if ((c & 15) == 0 && bi < NB) qbg[bi * 8 + h] = p;
    }
}

__global__ void k_count(const int* __restrict__ etgt, int* __restrict__ cnt, int E) {
    int e = blockIdx.x * blockDim.x + threadIdx.x;
    if (e < E) atomicAdd(&cnt[etgt[e]], 1);
}

__global__ void __launch_bounds__(1024) k_scan(const int* __restrict__ cnt,
                                               int* __restrict__ offs, int NB) {
    __shared__ int part[1024];
    int t = threadIdx.x;
    int CH = (NB + 1023) >> 10;
    int base = t * CH;
    int s = 0;
    for (int i = 0; i < CH; ++i) {
        int idx = base + i;
        if (idx < NB) s += cnt[idx];
    }
    part[t] = s;
    __syncthreads();
    for (int off = 1; off < 1024; off <<= 1) {
        int v = (t >= off) ? part[t - off] : 0;
        __syncthreads();
        part[t] += v;
        __syncthreads();
    }
    int run = part[t] - s;
    for (int i = 0; i < CH; ++i) {
        int idx = base + i;
        if (idx < NB) {
            offs[idx] = run;
            run += cnt[idx];
        }
    }
    if (t == 1023) offs[NB] = part[1023];
}

__global__ void k_scatter(const int* __restrict__ etgt, const int* __restrict__ esrc,
                          const float* __restrict__ coords, const float* __restrict__ rbp,
                          const int* __restrict__ offs, int* __restrict__ cursor,
                          int* __restrict__ ssrc, float* __restrict__ sdist, int E) {
    int e = blockIdx.x * blockDim.x + threadIdx.x;
    if (e < E) {
        int t = etgt[e];
        int pos = atomicAdd(&cursor[t], 1);
        int idx = offs[t] + pos;
        int src = esrc[e];
        ssrc[idx] = src;
        float dx = coords[src * 3 + 0] - rbp[t * 3 + 0];
        float dy = coords[src * 3 + 1] - rbp[t * 3 + 1];
        float dz = coords[src * 3 + 2] - rbp[t * 3 + 2];
        sdist[idx] = sqrtf(dx * dx + dy * dy + dz * dz);
    }
}

// one wave per 2 bonds; fp16 K/V + fdot2 scores; w packed into de rows
__global__ void __launch_bounds__(64) k_attn(
    const float* __restrict__ qv, const float* __restrict__ tkg,
    const float* __restrict__ qbg, const _Float16* __restrict__ ka,
    const _Float16* __restrict__ va, const int* __restrict__ ssrc,
    const float* __restrict__ sdist, const int* __restrict__ offs,
    float* __restrict__ macc, float* __restrict__ wdeg,
    float* __restrict__ dnb, int NB) {
    __shared__ __align__(16) _Float16 qh[2][128];
    __shared__ __align__(16) _Float16 tkh[2][256];
    __shared__ float qb_s[2][8];
    __shared__ int   src_s[2][32];
    __shared__ __align__(16) _Float16 de_s[2][32 * 40];  // [0..31]=de, [32..39]=w fp16

    int l = threadIdx.x;
    int half = l >> 5;
    int j = l & 31;
    int bb = blockIdx.x * 2 + half;
    bool vb = bb < NB;

    if (vb) {
#pragma unroll
        for (int i = 0; i < 4; ++i)
            qh[half][j + 32 * i] = (_Float16)qv[(size_t)bb * D + j + 32 * i];
#pragma unroll
        for (int i = 0; i < 8; ++i)
            tkh[half][j + 32 * i] = (_Float16)tkg[(size_t)bb * 256 + j + 32 * i];
        if (j < 8) qb_s[half][j] = qbg[bb * 8 + j];
    }
    int base = 0, ne = 0;
    if (vb) { base = offs[bb]; ne = offs[bb + 1] - base; }
    int mych = (ne + 31) >> 5;
    int och = __shfl_xor(mych, 32);
    int nch = mych > och ? mych : och;
    __syncthreads();

    const float step = 5.0f / 31.0f;
    const float coeff = -0.5f / (step * step);

    float dnp[8];
#pragma unroll
    for (int h = 0; h < 8; ++h) dnp[h] = 0.f;
    f4 acc = make_float4(0.f, 0.f, 0.f, 0.f);
    f4 wa  = make_float4(0.f, 0.f, 0.f, 0.f);
    f4 wb  = make_float4(0.f, 0.f, 0.f, 0.f);
    f4 acc2 = acc, wa2 = acc, wb2 = acc;

    int h4 = j >> 2;
    int dq8 = 8 * (j & 3);

    for (int cb = 0; cb < nch; ++cb) {
        int ebase = cb * 32;
        int nec = ne - ebase;
        nec = nec < 0 ? 0 : (nec > 32 ? 32 : nec);
        if (j < nec) {
            int eg = base + ebase + j;
            int src = ssrc[eg];
            float dist = sdist[eg];
            src_s[half][j] = src;
            h8v dh[4];
#pragma unroll
            for (int k2 = 0; k2 < 4; ++k2) {
#pragma unroll
                for (int m = 0; m < 8; ++m) {
                    float t = dist - step * (float)(8 * k2 + m);
                    dh[k2][m] = (_Float16)__expf(coeff * t * t);
                }
                *(h8v*)&de_s[half][j * 40 + 8 * k2] = dh[k2];
            }
            float sc[8];
#pragma unroll
            for (int h = 0; h < 8; ++h) sc[h] = qb_s[half][h];
            const _Float16* kap = ka + (size_t)src * 128;
#pragma unroll
            for (int f = 0; f < 16; ++f) {
                h8v kv = *(const h8v*)(kap + 8 * f);
                h8v qq = *(const h8v*)&qh[half][8 * f];
                int hh = f >> 1;
#pragma unroll
                for (int m = 0; m < 4; ++m) {
                    h2v a = {qq[2 * m], qq[2 * m + 1]};
                    h2v bq2 = {kv[2 * m], kv[2 * m + 1]};
                    sc[hh] = fdot2_acc(a, bq2, sc[hh]);
                }
            }
            const h2v* dh2 = (const h2v*)dh;
#pragma unroll
            for (int h = 0; h < 8; ++h) {
                float s = 0.f;
                h8v t0 = *(const h8v*)&tkh[half][h * 32];
                h8v t1 = *(const h8v*)&tkh[half][h * 32 + 8];
                h8v t2 = *(const h8v*)&tkh[half][h * 32 + 16];
                h8v t3 = *(const h8v*)&tkh[half][h * 32 + 24];
#pragma unroll
                for (int m = 0; m < 4; ++m) {
                    h2v ta = {t0[2 * m], t0[2 * m + 1]};
                    h2v tb = {t1[2 * m], t1[2 * m + 1]};
                    h2v tc = {t2[2 * m], t2[2 * m + 1]};
                    h2v td = {t3[2 * m], t3[2 * m + 1]};
                    s = fdot2_acc(dh2[m], ta, s);
                    s = fdot2_acc(dh2[4 + m], tb, s);
                    s = fdot2_acc(dh2[8 + m], tc, s);
                    s = fdot2_acc(dh2[12 + m], td, s);
                }
                float wv_ = __expf(sc[h] + s);
                dnp[h] += wv_;
                de_s[half][j * 40 + 32 + h] = (_Float16)wv_;
            }
        }
        __syncthreads();
        int e = 0;
        for (; e + 2 <= nec; e += 2) {
            int s0 = src_s[half][e];
            int s1 = src_s[half][e + 1];
            float ww0 = (float)de_s[half][e * 40 + 32 + h4];
            float ww1 = (float)de_s[half][(e + 1) * 40 + 32 + h4];
            h4v v0 = *(const h4v*)(va + (size_t)s0 * 128 + 4 * j);
            h4v v1 = *(const h4v*)(va + (size_t)s1 * 128 + 4 * j);
            h8v d0 = *(const h8v*)&de_s[half][e * 40 + dq8];
            h8v d1 = *(const h8v*)&de_s[half][(e + 1) * 40 + dq8];
            acc.x += ww0 * (float)v0[0]; acc.y += ww0 * (float)v0[1];
            acc.z += ww0 * (float)v0[2]; acc.w += ww0 * (float)v0[3];
            wa.x += ww0 * (float)d0[0]; wa.y += ww0 * (float)d0[1];
            wa.z += ww0 * (float)d0[2]; wa.w += ww0 * (float)d0[3];
            wb.x += ww0 * (float)d0[4]; wb.y += ww0 * (float)d0[5];
            wb.z += ww0 * (float)d0[6]; wb.w += ww0 * (float)d0[7];
            acc2.x += ww1 * (float)v1[0]; acc2.y += ww1 * (float)v1[1];
            acc2.z += ww1 * (float)v1[2]; acc2.w += ww1 * (float)v1[3];
            wa2.x += ww1 * (float)d1[0]; wa2.y += ww1 * (float)d1[1];
            wa2.z += ww1 * (float)d1[2]; wa2.w += ww1 * (float)d1[3];
            wb2.x += ww1 * (float)d1[4]; wb2.y += ww1 * (float)d1[5];
            wb2.z += ww1 * (float)d1[6]; wb2.w += ww1 * (float)d1[7];
        }
        if (e < nec) {
            int s0 = src_s[half][e];
            float ww0 = (float)de_s[half][e * 40 + 32 + h4];
            h4v v0 = *(const h4v*)(va + (size_t)s0 * 128 + 4 * j);
            h8v d0 = *(const h8v*)&de_s[half][e * 40 + dq8];
            acc.x += ww0 * (float)v0[0]; acc.y += ww0 * (float)v0[1];
            acc.z += ww0 * (float)v0[2]; acc.w += ww0 * (float)v0[3];
            wa.x += ww0 * (float)d0[0]; wa.y += ww0 * (float)d0[1];
            wa.z += ww0 * (float)d0[2]; wa.w += ww0 * (float)d0[3];
            wb.x += ww0 * (float)d0[4]; wb.y += ww0 * (float)d0[5];
            wb.z += ww0 * (float)d0[6]; wb.w += ww0 * (float)d0[7];
        }
        __syncthreads();
    }
    acc.x += acc2.x; acc.y += acc2.y; acc.z += acc2.z; acc.w += acc2.w;
    wa.x += wa2.x; wa.y += wa2.y; wa.z += wa2.z; wa.w += wa2.w;
    wb.x += wb2.x; wb.y += wb2.y; wb.z += wb2.z; wb.w += wb2.w;
#pragma unroll
    for (int h = 0; h < 8; ++h) {
        float v = dnp[h];
        v += __shfl_xor(v, 1);
        v += __shfl_xor(v, 2);
        v += __shfl_xor(v, 4);
        v += __shfl_xor(v, 8);
        v += __shfl_xor(v, 16);
        dnp[h] = v;
    }
    if (vb) {
        ((f4*)macc)[(size_t)bb * 32 + j] = acc;
        f4* wp = (f4*)&wdeg[(size_t)bb * 256 + h4 * 32 + dq8];
        wp[0] = wa;
        wp[1] = wb;
        if (j < 8) dnb[bb * 8 + j] = dnp[j];
    }
}

__device__ __forceinline__ float gelu_exact(float x) {
    return 0.5f * x * (1.0f + erff(x * 0.70710678118654752f));
}

// MFMA mlp: v_in (VALU) -> Wout (MFMA) -> gelu(Wt1) (MFMA) -> Wt2 (reduce)
__global__ void __launch_bounds__(256) k_mlp(
    const float* __restrict__ macc, const float* __restrict__ wdeg,
    const float* __restrict__ dnb, const float* __restrict__ Wv,
    const float* __restrict__ bv,
    const unsigned short* __restrict__ Wouth, const unsigned short* __restrict__ Woutl,
    const unsigned short* __restrict__ Wt1h, const unsigned short* __restrict__ Wt1l,
    const float* __restrict__ bout, const float* __restrict__ bt1,
    const float* __restrict__ Wt2, const float* __restrict__ bt2,
    float* __restrict__ y, int NB) {
    __shared__ __align__(16) char lds[32768];
    int t = threadIdx.x;
    int b0 = blockIdx.x * 32;
    // ---- phase 0: v_in = (macc + wde@WvB + bv*dn)/dn, bf16 hi/lo into A buffers ----
    {
        int c = t & 127, g = t >> 7;
        int h = c >> 4;
        float wvb[32];
#pragma unroll
        for (int d = 0; d < 32; ++d) wvb[d] = Wv[(128 + d) * 128 + c];
        float bvc = bv[c];
        char* vh = lds;
        char* vl = lds + 8192;
#pragma unroll
        for (int bl = 0; bl < 16; ++bl) {
            int row = g * 16 + bl;
            int bi = b0 + row;
            float v = 0.f;
            if (bi < NB) {
                float dn = dnb[bi * 8 + h];
                const f4* wr = (const f4*)(wdeg + (size_t)bi * 256 + h * 32);
                float sum = 0.f;
#pragma unroll
                for (int k = 0; k < 8; ++k) {
                    f4 wv4 = wr[k];
                    sum += wv4.x * wvb[4 * k] + wv4.y * wvb[4 * k + 1]
                         + wv4.z * wvb[4 * k + 2] + wv4.w * wvb[4 * k + 3];
                }
                float mval = macc[(size_t)bi * 128 + c];
                v = (mval + sum + bvc * dn) * (1.0f / (dn + 1e-16f));
            }
            unsigned short hh = bf16_rne(v);
            unsigned short ll = bf16_rne(v - bf16_to_f(hh));
            int byteo = row * 256 + ((c * 2) ^ ((row & 7) << 4));
            *(unsigned short*)(vh + byteo) = hh;
            *(unsigned short*)(vl + byteo) = ll;
        }
    }
    __syncthreads();
    int w = t >> 6, l = t & 63, lr = l & 15, lg = l >> 4;
    int colbase = w * 32;
    // ---- GEMM1: x1 = v_in @ Wout + bout ----
    f32x4 acc[2][2];
#pragma unroll
    for (int mf = 0; mf < 2; ++mf)
#pragma unroll
        for (int nf = 0; nf < 2; ++nf)
            acc[mf][nf] = (f32x4){0.f, 0.f, 0.f, 0.f};
    for (int ks = 0; ks < 4; ++ks) {
        short8 Bh[2], Bl[2];
#pragma unroll
        for (int nf = 0; nf < 2; ++nf) {
            size_t o = (size_t)(colbase + nf * 16 + lr) * 128 + ks * 32 + lg * 8;
            Bh[nf] = *(const short8*)(Wouth + o);
            Bl[nf] = *(const short8*)(Woutl + o);
        }
#pragma unroll
        for (int mf = 0; mf < 2; ++mf) {
            int row = mf * 16 + lr;
            int kbyte = (ks * 64 + lg * 16) ^ ((row & 7) << 4);
            short8 Ah = *(const short8*)((const char*)lds + row * 256 + kbyte);
            short8 Al = *(const short8*)((const char*)lds + 8192 + row * 256 + kbyte);
#pragma unroll
            for (int nf = 0; nf < 2; ++nf) {
                acc[mf][nf] = __builtin_amdgcn_mfma_f32_16x16x32_bf16(Ah, Bh[nf], acc[mf][nf], 0, 0, 0);
                acc[mf][nf] = __builtin_amdgcn_mfma_f32_16x16x32_bf16(Al, Bh[nf], acc[mf][nf], 0, 0, 0);
                acc[mf][nf] = __builtin_amdgcn_mfma_f32_16x16x32_bf16(Ah, Bl[nf], acc[mf][nf], 0, 0, 0);
            }
        }
    }
    float bo[2];
#pragma unroll
    for (int nf = 0; nf < 2; ++nf) bo[nf] = bout[colbase + nf * 16 + lr];
    __syncthreads();
    {
        char* rfh = lds;
        char* rfl = lds + 8192;
#pragma unroll
        for (int mf = 0; mf < 2; ++mf) {
#pragma unroll
            for (int nf = 0; nf < 2; ++nf) {
#pragma unroll
                for (int r = 0; r < 4; ++r) {
                    int row = mf * 16 + lg * 4 + r;
                    int col = colbase + nf * 16 + lr;
                    float vv_ = acc[mf][nf][r] + bo[nf];
                    unsigned short hh = bf16_rne(vv_);
                    unsigned short ll = bf16_rne(vv_ - bf16_to_f(hh));
                    int byteo = row * 256 + ((col * 2) ^ ((row & 7) << 4));
                    *(unsigned short*)(rfh + byteo) = hh;
                    *(unsigned short*)(rfl + byteo) = ll;
                }
            }
        }
    }
    __syncthreads();
    // ---- GEMM2: h = gelu(x1 @ Wt1 + bt1) ----
    f32x4 acc2[2][2];
#pragma unroll
    for (int mf = 0; mf < 2; ++mf)
#pragma unroll
        for (int nf = 0; nf < 2; ++nf)
            acc2[mf][nf] = (f32x4){0.f, 0.f, 0.f, 0.f};
    for (int ks = 0; ks < 4; ++ks) {
        short8 Bh[2], Bl[2];
#pragma unroll
        for (int nf = 0; nf < 2; ++nf) {
            size_t o = (size_t)(colbase + nf * 16 + lr) * 128 + ks * 32 + lg * 8;
            Bh[nf] = *(const short8*)(Wt1h + o);
            Bl[nf] = *(const short8*)(Wt1l + o);
        }
#pragma unroll
        for (int mf = 0; mf < 2; ++mf) {
            int row = mf * 16 + lr;
            int kbyte = (ks * 64 + lg * 16) ^ ((row & 7) << 4);
            short8 Ah = *(const short8*)((const char*)lds + row * 256 + kbyte);
            short8 Al = *(const short8*)((const char*)lds + 8192 + row * 256 + kbyte);
#pragma unroll
            for (int nf = 0; nf < 2; ++nf) {
                acc2[mf][nf] = __builtin_amdgcn_mfma_f32_16x16x32_bf16(Ah, Bh[nf], acc2[mf][nf], 0, 0, 0);
                acc2[mf][nf] = __builtin_amdgcn_mfma_f32_16x16x32_bf16(Al, Bh[nf], acc2[mf][nf], 0, 0, 0);
                acc2[mf][nf] = __builtin_amdgcn_mfma_f32_16x16x32_bf16(Ah, Bl[nf], acc2[mf][nf], 0, 0, 0);
            }
        }
    }
    float* hs = (float*)(lds + 16384);
    {
        float bt[2];
#pragma unroll
        for (int nf = 0; nf < 2; ++nf) bt[nf] = bt1[colbase + nf * 16 + lr];
#pragma unroll
        for (int mf = 0; mf < 2; ++mf) {
#pragma unroll
            for (int nf = 0; nf < 2; ++nf) {
#pragma unroll
                for (int r = 0; r < 4; ++r) {
                    int row = mf * 16 + lg * 4 + r;
                    int col = colbase + nf * 16 + lr;
                    hs[row * 128 + col] = gelu_exact(acc2[mf][nf][r] + bt[nf]);
                }
            }
        }
    }
    __syncthreads();
    // ---- final 128 -> 2 ----
    int g8 = t >> 3, l8 = t & 7;
    float p0 = 0.f, p1 = 0.f;
#pragma unroll
    for (int k = 0; k < 16; ++k) {
        int d = l8 + 8 * k;
        float hv = hs[g8 * 128 + d];
        p0 += hv * Wt2[d * 2 + 0];
        p1 += hv * Wt2[d * 2 + 1];
    }
    p0 += __shfl_xor(p0, 1); p1 += __shfl_xor(p1, 1);
    p0 += __shfl_xor(p0, 2); p1 += __shfl_xor(p1, 2);
    p0 += __shfl_xor(p0, 4); p1 += __shfl_xor(p1, 4);
    int bi = b0 + g8;
    if (l8 == 0 && bi < NB) {
        y[bi * 2 + 0] = p0 + bt2[0];
        y[bi * 2 + 1] = p1 + bt2[1];
    }
}

extern "C" void kernel_launch(void* const* d_in, const int* in_sizes, int n_in,
                              void* d_out, int out_size, void* d_ws, size_t ws_size,
                              hipStream_t stream) {
    const float* af     = (const float*)d_in[0];
    const float* coords = (const float*)d_in[1];
    const int*   rbi    = (const int*)d_in[2];
    const int*   etgt   = (const int*)d_in[3];
    const int*   esrc   = (const int*)d_in[4];
    const int*   tt     = (const int*)d_in[5];
    const float* W_dih  = (const float*)d_in[6];
    const float* b_dih  = (const float*)d_in[7];
    const float* Wq     = (const float*)d_in[8];
    const float* bq     = (const float*)d_in[9];
    const float* Wk     = (const float*)d_in[10];
    const float* bk     = (const float*)d_in[11];
    const float* Wv     = (const float*)d_in[12];
    const float* bv     = (const float*)d_in[13];
    const float* Wout   = (const float*)d_in[14];
    const float* bout   = (const float*)d_in[15];
    const float* Wt1    = (const float*)d_in[16];
    const float* bt1    = (const float*)d_in[17];
    const float* Wt2    = (const float*)d_in[18];
    const float* bt2    = (const float*)d_in[19];

    int N  = in_sizes[0] / D;
    int NB = in_sizes[2] / 2;
    int E  = in_sizes[3];

    char* ws = (char*)d_ws;
    size_t off = 0;
    auto alloc = [&](size_t bytes) -> char* {
        char* p = ws + off;
        off = (off + bytes + 255) & ~(size_t)255;
        return p;
    };
    _Float16* ka  = (_Float16*)alloc((size_t)N * D * 2);
    _Float16* va  = (_Float16*)alloc((size_t)N * D * 2);
    float* qv     = (float*)alloc((size_t)NB * D * 4);
    float* rbp    = (float*)alloc((size_t)NB * 3 * 4);
    float* tkg    = (float*)alloc((size_t)NB * 256 * 4);
    float* qbg    = (float*)alloc((size_t)NB * 8 * 4);
    float* maccb  = (float*)alloc((size_t)NB * D * 4);
    float* wdeg   = (float*)alloc((size_t)NB * 256 * 4);
    float* dnb    = (float*)alloc((size_t)NB * 8 * 4);
    int*   cnt2   = (int*)alloc((size_t)2 * NB * 4);
    int*   cnt    = cnt2;
    int*   cursor = cnt2 + NB;
    int*   offs   = (int*)alloc((size_t)(NB + 1) * 4);
    int*   ssrc   = (int*)alloc((size_t)E * 4);
    float* sdist  = (float*)alloc((size_t)E * 4);
    unsigned short* Wth   = (unsigned short*)alloc((size_t)256 * 128 * 2);
    unsigned short* Wtl   = (unsigned short*)alloc((size_t)256 * 128 * 2);
    unsigned short* Wabh  = (unsigned short*)alloc((size_t)128 * 256 * 2);
    unsigned short* Wabl  = (unsigned short*)alloc((size_t)128 * 256 * 2);
    unsigned short* Wqh   = (unsigned short*)alloc((size_t)128 * 128 * 2);
    unsigned short* Wql   = (unsigned short*)alloc((size_t)128 * 128 * 2);
    unsigned short* Wouth = (unsigned short*)alloc((size_t)128 * 128 * 2);
    unsigned short* Woutl = (unsigned short*)alloc((size_t)128 * 128 * 2);
    unsigned short* Wt1h  = (unsigned short*)alloc((size_t)128 * 128 * 2);
    unsigned short* Wt1l  = (unsigned short*)alloc((size_t)128 * 128 * 2);

    int prep_items = 114688 + 2 * NB;
    k_prep<<<(prep_items + 255) / 256, 256, 0, stream>>>(
        Wk, Wv, W_dih, Wq, Wout, Wt1, Wth, Wtl, Wabh, Wabl, Wqh, Wql,
        Wouth, Woutl, Wt1h, Wt1l, cnt2, 2 * NB);
    k_atomproj<<<(N + 63) / 64, 256, 0, stream>>>(af, Wth, Wtl, ka, va, N);
    k_bondfeats<<<(NB + 31) / 32, 256, 0, stream>>>(af, coords, rbi, tt, b_dih,
                                                    bq, Wabh, Wabl, Wqh, Wql,
                                                    Wk, bk, qv, rbp, tkg, qbg, NB);
    k_count<<<(E + 255) / 256, 256, 0, stream>>>(etgt, cnt, E);
    k_scan<<<1, 1024, 0, stream>>>(cnt, offs, NB);
    k_scatter<<<(E + 255) / 256, 256, 0, stream>>>(etgt, esrc, coords, rbp,
                                                   offs, cursor, ssrc, sdist, E);
    k_attn<<<(NB + 1) / 2, 64, 0, stream>>>(qv, tkg, qbg, ka, va, ssrc, sdist,
                                            offs, maccb, wdeg, dnb, NB);
    k_mlp<<<(NB + 31) / 32, 256, 0, stream>>>(maccb, wdeg, dnb, Wv, bv,
                                              Wouth, Woutl, Wt1h, Wt1l,
                                              bout, bt1, Wt2, bt2,
                                              (float*)d_out, NB);
}